// Round 14
// baseline (670.617 us; speedup 1.0000x reference)
//
#include <hip/hip_runtime.h>
#include <hip/hip_bf16.h>

#define N_NODESC 100000
#define N_EDGESC 1600000
#define N_GRAPHSC 200
#define IN_DIMC 25
#define HIDC 256
#define OUT_DIMC 128
#define SCAN_BLK 1024
#define SCAN_NBLK ((N_NODESC + SCAN_BLK - 1) / SCAN_BLK)
#define NRB128 ((N_NODESC + 127) / 128)  // 782 row-blocks
#define NBKT ((N_NODESC + 255) / 256)  // 391 dst-buckets (256 nodes each)
#define NCH 400                        // edge chunks
#define CHSZ (N_EDGESC / NCH)          // 4000 edges/chunk (exact)

typedef __attribute__((ext_vector_type(8))) short bf16x8;
typedef __attribute__((ext_vector_type(4))) float f32x4;

// ---------- bf16 helpers (raw ushort storage) ----------
__device__ inline float bf2f(unsigned short u) {
    union { float f; unsigned u32; } c;
    c.u32 = ((unsigned)u) << 16;
    return c.f;
}
__device__ inline unsigned short f2bf(float f) {
    union { float f; unsigned u; } c;
    c.f = f;
    unsigned r = (c.u + 0x7FFFu + ((c.u >> 16) & 1u)) >> 16;  // RNE
    return (unsigned short)r;
}
__device__ inline float u2f(unsigned u) {
    union { unsigned u; float f; } c;
    c.u = u;
    return c.f;
}

// ---------- utility fills ----------
__global__ void fill_u32(unsigned* __restrict__ p, unsigned v, int n) {
    int i = blockIdx.x * 256 + threadIdx.x;
    if (i < n) p[i] = v;
}

__global__ void inv_kernel(const int* __restrict__ cnt, float* __restrict__ inv, int n) {
    int i = blockIdx.x * 256 + threadIdx.x;
    if (i < n) inv[i] = 1.0f / (float)max(cnt[i], 1);
}

// ---------- bucketed CSR build ----------
__global__ __launch_bounds__(256) void hist_kernel(const int* __restrict__ dst,
                                                   int* __restrict__ hist) {
    __shared__ int h[NBKT];
    const int c = blockIdx.x, tid = threadIdx.x;
    for (int t = tid; t < NBKT; t += 256) h[t] = 0;
    __syncthreads();
    const int e0 = c * CHSZ;
    for (int e = e0 + tid; e < e0 + CHSZ; e += 256) atomicAdd(&h[dst[e] >> 8], 1);
    __syncthreads();
    for (int t = tid; t < NBKT; t += 256) hist[c * NBKT + t] = h[t];
}

__global__ __launch_bounds__(512) void col_scan(int* __restrict__ hist,
                                                int* __restrict__ colsum) {
    __shared__ int sm[512];
    const int b = blockIdx.x, t = threadIdx.x;
    int v = (t < NCH) ? hist[t * NBKT + b] : 0;
    sm[t] = v;
    __syncthreads();
    for (int off = 1; off < 512; off <<= 1) {
        int u = (t >= off) ? sm[t - off] : 0;
        __syncthreads();
        sm[t] += u;
        __syncthreads();
    }
    if (t < NCH) hist[t * NBKT + b] = sm[t] - v;  // chunk-prefix within bucket
    if (t == 511) colsum[b] = sm[511];            // bucket total
}

__global__ __launch_bounds__(512) void bucket_base_scan(const int* __restrict__ colsum,
                                                        int* __restrict__ base) {
    __shared__ int sm[512];
    const int t = threadIdx.x;
    int v = (t < NBKT) ? colsum[t] : 0;
    sm[t] = v;
    __syncthreads();
    for (int off = 1; off < 512; off <<= 1) {
        int u = (t >= off) ? sm[t - off] : 0;
        __syncthreads();
        sm[t] += u;
        __syncthreads();
    }
    if (t <= NBKT) base[t] = sm[t] - v;
}

__global__ __launch_bounds__(256) void bucket_scatter(const int* __restrict__ src,
                                                      const int* __restrict__ dst,
                                                      const int* __restrict__ chpre,
                                                      const int* __restrict__ base,
                                                      int2* __restrict__ pairs) {
    __shared__ int cur[NBKT];
    __shared__ int o2[NBKT];
    const int c = blockIdx.x, tid = threadIdx.x;
    for (int t = tid; t < NBKT; t += 256) {
        cur[t] = 0;
        o2[t] = base[t] + chpre[c * NBKT + t];
    }
    __syncthreads();
    const int e0 = c * CHSZ;
    for (int e = e0 + tid; e < e0 + CHSZ; e += 256) {
        int s = src[e], d = dst[e];
        int b = d >> 8;
        int p = atomicAdd(&cur[b], 1);
        pairs[o2[b] + p] = make_int2(s, d);
    }
}

__global__ __launch_bounds__(256) void bucket_deg(const int2* __restrict__ pairs,
                                                  const int* __restrict__ base,
                                                  int* __restrict__ cnt) {
    __shared__ int h[256];
    const int b = blockIdx.x, tid = threadIdx.x;
    h[tid] = 0;
    __syncthreads();
    for (int i = base[b] + tid; i < base[b + 1]; i += 256)
        atomicAdd(&h[pairs[i].y & 255], 1);
    __syncthreads();
    int node = b * 256 + tid;
    if (node < N_NODESC) cnt[node] = h[tid];
}

__global__ __launch_bounds__(256) void bucket_csrfill(const int2* __restrict__ pairs,
                                                      const int* __restrict__ base,
                                                      const int* __restrict__ row_ofs,
                                                      int* __restrict__ csr) {
    __shared__ int cur[256];
    __shared__ int ob[256];
    const int b = blockIdx.x, tid = threadIdx.x;
    int node = b * 256 + tid;
    ob[tid] = (node < N_NODESC) ? row_ofs[node] : 0;
    cur[tid] = 0;
    __syncthreads();
    for (int i = base[b] + tid; i < base[b + 1]; i += 256) {
        int2 pr = pairs[i];
        int loc = pr.y & 255;
        int p = atomicAdd(&cur[loc], 1);
        csr[ob[loc] + p] = pr.x;
    }
}

// ---------- hierarchical exclusive scan over cnt[N] -> ofs[N+1] ----------
__global__ __launch_bounds__(SCAN_BLK) void scan_partial(const int* __restrict__ cnt,
                                                         int* __restrict__ ofs,
                                                         int* __restrict__ bsum) {
    __shared__ int sm[SCAN_BLK];
    int i = blockIdx.x * SCAN_BLK + threadIdx.x;
    int v = (i < N_NODESC) ? cnt[i] : 0;
    sm[threadIdx.x] = v;
    __syncthreads();
    for (int off = 1; off < SCAN_BLK; off <<= 1) {
        int t = (threadIdx.x >= off) ? sm[threadIdx.x - off] : 0;
        __syncthreads();
        sm[threadIdx.x] += t;
        __syncthreads();
    }
    if (i < N_NODESC) ofs[i] = sm[threadIdx.x] - v;  // exclusive within block
    if (threadIdx.x == SCAN_BLK - 1) bsum[blockIdx.x] = sm[SCAN_BLK - 1];
}

__global__ __launch_bounds__(128) void scan_bsums(int* __restrict__ bsum) {
    __shared__ int sm[SCAN_NBLK];
    if (threadIdx.x == 0) {
        int run = 0;
        for (int b = 0; b < SCAN_NBLK; ++b) {
            int t = bsum[b];
            sm[b] = run;
            run += t;
        }
        for (int b = 0; b < SCAN_NBLK; ++b) bsum[b] = sm[b];
    }
}

__global__ __launch_bounds__(SCAN_BLK) void scan_add(int* __restrict__ ofs,
                                                     const int* __restrict__ bsum) {
    int i = blockIdx.x * SCAN_BLK + threadIdx.x;
    if (i < N_NODESC) ofs[i] += bsum[blockIdx.x];
    if (i == 0) ofs[N_NODESC] = N_EDGESC;
}

// ---------- graph ranges: boundary scan (batch sorted; no atomics) ----------
__global__ void ranges_bounds(const int* __restrict__ batch, int* __restrict__ gstart,
                              int* __restrict__ gend, int n) {
    int i = blockIdx.x * 256 + threadIdx.x;
    if (i >= n) return;
    int g = batch[i];
    if (i == 0 || batch[i - 1] != g) gstart[g] = i;
    if (i == n - 1 || batch[i + 1] != g) gend[g] = i + 1;
}

// ---------- weight transpose f32[256][256] -> bf16 WT[n][k] ----------
__global__ void wtransT(const float* __restrict__ W, unsigned short* __restrict__ WT) {
    __shared__ float t[16][17];
    int bx = blockIdx.x, by = blockIdx.y;
    int tx = threadIdx.x & 15, ty = threadIdx.x >> 4;
    t[ty][tx] = W[(by * 16 + ty) * HIDC + bx * 16 + tx];
    __syncthreads();
    WT[(size_t)(bx * 16 + ty) * HIDC + by * 16 + tx] = f2bf(t[tx][ty]);
}

// ---------- layer-1 mean gather (f32, 25 channels) ----------
__global__ void gather25(const float* __restrict__ x, const int* __restrict__ ofs,
                         const int* __restrict__ csr, const float* __restrict__ inv,
                         float* __restrict__ agg) {
    int idx = blockIdx.x * 256 + threadIdx.x;
    int node = idx >> 5, c = idx & 31;
    if (node >= N_NODESC || c >= IN_DIMC) return;
    float acc = 0.0f;
    int s = ofs[node], e = ofs[node + 1];
    for (int j = s; j < e; ++j) acc += x[(size_t)csr[j] * IN_DIMC + c];
    agg[(size_t)node * IN_DIMC + c] = acc * inv[node];
}

// ---------- hidden mean gather: one wave/node, half-wave/edge, 8 rows in flight ----------
__global__ void gather256(const unsigned short* __restrict__ h, const int* __restrict__ ofs,
                          const int* __restrict__ csr, const float* __restrict__ inv,
                          unsigned short* __restrict__ agg) {
    long long gtid = (long long)blockIdx.x * 256 + threadIdx.x;
    int node = (int)(gtid >> 6);
    if (node >= N_NODESC) return;
    const int lane = threadIdx.x & 63;
    const int half = lane >> 5;
    const int l = lane & 31;
    const int s = ofs[node], e = ofs[node + 1];

    float a0 = 0, a1 = 0, a2 = 0, a3 = 0, a4 = 0, a5 = 0, a6 = 0, a7 = 0;
    const size_t coff = (size_t)l * 8;

#define ACC8(v)                                                             \
    a0 += u2f(((unsigned)(v).x) << 16); a1 += u2f(((unsigned)(v).x) & 0xffff0000u); \
    a2 += u2f(((unsigned)(v).y) << 16); a3 += u2f(((unsigned)(v).y) & 0xffff0000u); \
    a4 += u2f(((unsigned)(v).z) << 16); a5 += u2f(((unsigned)(v).z) & 0xffff0000u); \
    a6 += u2f(((unsigned)(v).w) << 16); a7 += u2f(((unsigned)(v).w) & 0xffff0000u);

    int j = s + half;
    for (; j + 6 < e; j += 8) {
        int sn0 = csr[j];
        int sn1 = csr[j + 2];
        int sn2 = csr[j + 4];
        int sn3 = csr[j + 6];
        int4 v0 = *reinterpret_cast<const int4*>(h + (size_t)sn0 * HIDC + coff);
        int4 v1 = *reinterpret_cast<const int4*>(h + (size_t)sn1 * HIDC + coff);
        int4 v2 = *reinterpret_cast<const int4*>(h + (size_t)sn2 * HIDC + coff);
        int4 v3 = *reinterpret_cast<const int4*>(h + (size_t)sn3 * HIDC + coff);
        ACC8(v0) ACC8(v1) ACC8(v2) ACC8(v3)
    }
    for (; j < e; j += 2) {
        int sn0 = csr[j];
        int4 v0 = *reinterpret_cast<const int4*>(h + (size_t)sn0 * HIDC + coff);
        ACC8(v0)
    }
#undef ACC8

    a0 += __shfl_xor(a0, 32, 64); a1 += __shfl_xor(a1, 32, 64);
    a2 += __shfl_xor(a2, 32, 64); a3 += __shfl_xor(a3, 32, 64);
    a4 += __shfl_xor(a4, 32, 64); a5 += __shfl_xor(a5, 32, 64);
    a6 += __shfl_xor(a6, 32, 64); a7 += __shfl_xor(a7, 32, 64);

    if (half == 0) {
        float sc = inv[node];
        int4 p;
        p.x = (int)((unsigned)f2bf(a0 * sc) | ((unsigned)f2bf(a1 * sc) << 16));
        p.y = (int)((unsigned)f2bf(a2 * sc) | ((unsigned)f2bf(a3 * sc) << 16));
        p.z = (int)((unsigned)f2bf(a4 * sc) | ((unsigned)f2bf(a5 * sc) << 16));
        p.w = (int)((unsigned)f2bf(a6 * sc) | ((unsigned)f2bf(a7 * sc) << 16));
        *reinterpret_cast<int4*>(agg + (size_t)node * HIDC + coff) = p;
    }
}

// ---------- layer-1 f32 SAGE GEMM (K=25) ----------
template <int K>
__global__ __launch_bounds__(256) void sage_gemm_f32(
    const float* __restrict__ agg, const float* __restrict__ h,
    const float* __restrict__ Wl, const float* __restrict__ Wr,
    const float* __restrict__ bias,
    unsigned short* __restrict__ out, int nrows) {
    constexpr int BM = 64, BN = 64, BK = 16;
    __shared__ float sA[BK][BM + 4];
    __shared__ float sB[BK][BN + 4];
    const int tid = threadIdx.x;
    const int tx = tid & 15, ty = tid >> 4;
    const int rowbase = blockIdx.x * BM;
    const int colbase = blockIdx.y * BN;
    float acc[4][4] = {};
    const int lrow = tid >> 2, lkq = (tid & 3) * 4;
    const int lkB = tid >> 4, lnB = (tid & 15) * 4;

    for (int pass = 0; pass < 2; ++pass) {
        const float* __restrict__ A = pass ? h : agg;
        const float* __restrict__ W = pass ? Wr : Wl;
        const int grow = rowbase + lrow;
        for (int kb = 0; kb < K; kb += BK) {
#pragma unroll
            for (int j = 0; j < 4; ++j) {
                int k = kb + lkq + j;
                float v = 0.0f;
                if (grow < nrows && k < K) v = A[(size_t)grow * K + k];
                sA[lkq + j][lrow] = v;
            }
#pragma unroll
            for (int j = 0; j < 4; ++j) {
                int k = kb + lkB;
                int n = colbase + lnB + j;
                sB[lkB][lnB + j] = (k < K) ? W[(size_t)k * HIDC + n] : 0.0f;
            }
            __syncthreads();
#pragma unroll
            for (int kk = 0; kk < BK; ++kk) {
                float a[4], b[4];
#pragma unroll
                for (int i = 0; i < 4; ++i) a[i] = sA[kk][ty * 4 + i];
#pragma unroll
                for (int j = 0; j < 4; ++j) b[j] = sB[kk][tx * 4 + j];
#pragma unroll
                for (int i = 0; i < 4; ++i)
#pragma unroll
                    for (int j = 0; j < 4; ++j) acc[i][j] += a[i] * b[j];
            }
            __syncthreads();
        }
    }
#pragma unroll
    for (int i = 0; i < 4; ++i) {
        int r = rowbase + ty * 4 + i;
        if (r >= nrows) continue;
#pragma unroll
        for (int j = 0; j < 4; ++j) {
            int c = colbase + tx * 4 + j;
            out[(size_t)r * HIDC + c] = f2bf(fmaxf(acc[i][j] + bias[c], 0.0f));
        }
    }
}

// ---------- MFMA bf16 SAGE GEMM, m97-style, 128-row full-width tile ----------
// out = relu(A0@B0 + A1@B1 + b). A: [M][256] bf16. BnT: [256 n][256 k] bf16.
// 512 threads = 8 waves (2 row-halves x 4 col-quarters); tile 128 x 256.
// Per BK=64 step: DMA A(128x64, 16KB) + B(256x64, 32KB) via global_load_lds
// (linear dest, inverse-XOR-swizzled source), 2 barriers, 32 MFMA/wave.
// OOB A rows read in-workspace garbage; their C rows are discarded at epilogue.
__global__ __launch_bounds__(512) void sage_gemm_mfma(
    const unsigned short* __restrict__ A0, const unsigned short* __restrict__ A1,
    const unsigned short* __restrict__ B0T, const unsigned short* __restrict__ B1T,
    const float* __restrict__ bias, unsigned short* __restrict__ out, int M) {
    constexpr int KD = 256;
    __shared__ unsigned short sA[128 * 64];  // [128 r][64 k] 16KB
    __shared__ unsigned short sB[256 * 64];  // [256 c][64 k] 32KB
    const int rowbase = blockIdx.x * 128;
    const int tid = threadIdx.x;
    const int lane = tid & 63;
    const int wid = tid >> 6;      // 0..7
    const int wm = wid >> 2;       // 0..1 row half
    const int wn = wid & 3;        // 0..3 col quarter
    const int fr = lane & 15;
    const int kq8 = (lane >> 4) << 3;  // 0,8,16,24 elems

    const int srow = lane >> 3;            // row within 8-row stripe
    const int schunk = (lane & 7) ^ srow;  // inverse-swizzled source 16B chunk

    f32x4 acc[4][4] = {};

    for (int pass = 0; pass < 2; ++pass) {
        const unsigned short* __restrict__ A = pass ? A1 : A0;
        const unsigned short* __restrict__ BT = pass ? B1T : B0T;
        for (int ks = 0; ks < 4; ++ks) {
            const int kb = ks * 64;
            __syncthreads();  // prior k-step frag reads done before overwrite
            // stage A: 16 stripes of 8 rows; wave wid covers stripes 2*wid, 2*wid+1
#pragma unroll
            for (int c = 0; c < 2; ++c) {
                int ar = wid * 16 + c * 8 + srow;
                const unsigned short* g = A + (size_t)(rowbase + ar) * KD + kb + (schunk << 3);
                __builtin_amdgcn_global_load_lds(
                    (const __attribute__((address_space(1))) void*)g,
                    (__attribute__((address_space(3))) void*)(sA + (wid * 16 + c * 8) * 64),
                    16, 0, 0);
            }
            // stage B: 32 stripes of 8 cols; wave wid covers 4
#pragma unroll
            for (int c = 0; c < 4; ++c) {
                int br = wid * 32 + c * 8 + srow;
                const unsigned short* g = BT + (size_t)br * KD + kb + (schunk << 3);
                __builtin_amdgcn_global_load_lds(
                    (const __attribute__((address_space(1))) void*)g,
                    (__attribute__((address_space(3))) void*)(sB + (wid * 32 + c * 8) * 64),
                    16, 0, 0);
            }
            __syncthreads();  // vmcnt drained -> LDS ready
#pragma unroll
            for (int kg = 0; kg < 2; ++kg) {
                bf16x8 af[4], bfr[4];
#pragma unroll
                for (int t = 0; t < 4; ++t) {
                    int ra = wm * 64 + t * 16 + fr;
                    int ba = ra * 128 + ((kg * 64 + kq8 * 2) ^ ((ra & 7) << 4));
                    af[t] = *reinterpret_cast<const bf16x8*>(
                        reinterpret_cast<const char*>(sA) + ba);
                    int rb = wn * 64 + t * 16 + fr;
                    int bb2 = rb * 128 + ((kg * 64 + kq8 * 2) ^ ((rb & 7) << 4));
                    bfr[t] = *reinterpret_cast<const bf16x8*>(
                        reinterpret_cast<const char*>(sB) + bb2);
                }
#pragma unroll
                for (int i = 0; i < 4; ++i)
#pragma unroll
                    for (int j = 0; j < 4; ++j)
                        acc[i][j] = __builtin_amdgcn_mfma_f32_16x16x32_bf16(
                            af[i], bfr[j], acc[i][j], 0, 0, 0);
            }
        }
    }

    // epilogue: C/D layout col=lane&15, row=4*(lane>>4)+r
    const int crow0 = (lane >> 4) << 2;
#pragma unroll
    for (int i = 0; i < 4; ++i) {
#pragma unroll
        for (int j = 0; j < 4; ++j) {
            int col = wn * 64 + j * 16 + fr;
            float bb = bias[col];
#pragma unroll
            for (int r = 0; r < 4; ++r) {
                int row = rowbase + wm * 64 + i * 16 + crow0 + r;
                if (row < M)
                    out[(size_t)row * HIDC + col] = f2bf(fmaxf(acc[i][j][r] + bb, 0.0f));
            }
        }
    }
}

// ---------- segment-max pool: 8-way parallel per graph, atomicMax (values >= 0) ----------
__global__ void pool_max(const unsigned short* __restrict__ h, const int* __restrict__ gstart,
                         const int* __restrict__ gend, float* __restrict__ xc, int col_off) {
    int g = blockIdx.x;
    int chunk = blockIdx.y;  // 0..7
    int c = threadIdx.x;
    int s = gstart[g], e = gend[g];
    int len = e - s;
    if (len <= 0) return;
    int per = (len + 7) >> 3;
    int cs = s + chunk * per;
    int ce = min(cs + per, e);
    if (cs >= ce) return;
    float m = 0.0f;  // relu outputs >= 0
    for (int i = cs; i < ce; ++i) m = fmaxf(m, bf2f(h[(size_t)i * HIDC + c]));
    atomicMax(reinterpret_cast<int*>(&xc[(size_t)g * (3 * HIDC) + col_off + c]),
              __float_as_int(m));
}

// ---------- head MLPs ----------
__global__ void mlp1(const float* __restrict__ xc, const float* __restrict__ W,
                     const float* __restrict__ b, float* __restrict__ hmid) {
    __shared__ float row[3 * HIDC];
    int g = blockIdx.x;
    for (int i = threadIdx.x; i < 3 * HIDC; i += 256) row[i] = xc[(size_t)g * (3 * HIDC) + i];
    __syncthreads();
    float acc = b[threadIdx.x];
    for (int k = 0; k < 3 * HIDC; ++k) acc += row[k] * W[(size_t)k * HIDC + threadIdx.x];
    hmid[(size_t)g * HIDC + threadIdx.x] = fmaxf(acc, 0.0f);
}

__global__ void mlp2(const float* __restrict__ hmid, const float* __restrict__ W,
                     const float* __restrict__ b, float* __restrict__ out) {
    __shared__ float row[HIDC];
    int g = blockIdx.x;
    for (int i = threadIdx.x; i < HIDC; i += 128) row[i] = hmid[(size_t)g * HIDC + i];
    __syncthreads();
    float acc = b[threadIdx.x];
    for (int k = 0; k < HIDC; ++k) acc += row[k] * W[(size_t)k * OUT_DIMC + threadIdx.x];
    out[(size_t)g * OUT_DIMC + threadIdx.x] = acc;
}

static inline char* align_up(char* p, size_t a) {
    return (char*)(((uintptr_t)p + a - 1) & ~(uintptr_t)(a - 1));
}

extern "C" void kernel_launch(void* const* d_in, const int* in_sizes, int n_in,
                              void* d_out, int out_size, void* d_ws, size_t ws_size,
                              hipStream_t stream) {
    const float* x = (const float*)d_in[0];
    const int* edge_index = (const int*)d_in[1];
    const int* batch = (const int*)d_in[2];
    const float* W1l = (const float*)d_in[3];
    const float* W1r = (const float*)d_in[4];
    const float* b1 = (const float*)d_in[5];
    const float* W2l = (const float*)d_in[6];
    const float* W2r = (const float*)d_in[7];
    const float* b2 = (const float*)d_in[8];
    const float* W3l = (const float*)d_in[9];
    const float* W3r = (const float*)d_in[10];
    const float* b3 = (const float*)d_in[11];
    const float* Wlin1 = (const float*)d_in[12];
    const float* blin1 = (const float*)d_in[13];
    const float* Wlin2 = (const float*)d_in[14];
    const float* blin2 = (const float*)d_in[15];
    float* out = (float*)d_out;

    const int N = N_NODESC, E = N_EDGESC;
    const int* src = edge_index;
    const int* dst = edge_index + E;

    // ---- workspace carve-up ----
    char* w0 = (char*)d_ws;
    char* w = w0;
    int* cnt = (int*)w;        w = align_up(w + (size_t)N * 4, 256);
    float* invc = (float*)w;   w = align_up(w + (size_t)N * 4, 256);
    int* row_ofs = (int*)w;    w = align_up(w + (size_t)(N + 1) * 4, 256);
    int* bsum = (int*)w;       w = align_up(w + (size_t)SCAN_NBLK * 4, 256);
    int* bbase = (int*)w;      w = align_up(w + (size_t)(NBKT + 1) * 4, 256);
    int* colsum = (int*)w;     w = align_up(w + (size_t)NBKT * 4, 256);
    int* csr = (int*)w;        w = align_up(w + (size_t)E * 4, 256);
    int* gstart = (int*)w;     w = align_up(w + (size_t)N_GRAPHSC * 4, 256);
    int* gend = (int*)w;       w = align_up(w + (size_t)N_GRAPHSC * 4, 256);
    float* xc = (float*)w;     w = align_up(w + (size_t)N_GRAPHSC * 3 * HIDC * 4, 256);
    float* hmid = (float*)w;   w = align_up(w + (size_t)N_GRAPHSC * HIDC * 4, 256);
    unsigned short* W2lT = (unsigned short*)w; w = align_up(w + (size_t)HIDC * HIDC * 2, 256);
    unsigned short* W2rT = (unsigned short*)w; w = align_up(w + (size_t)HIDC * HIDC * 2, 256);
    unsigned short* W3lT = (unsigned short*)w; w = align_up(w + (size_t)HIDC * HIDC * 2, 256);
    unsigned short* W3rT = (unsigned short*)w; w = align_up(w + (size_t)HIDC * HIDC * 2, 256);
    char* aggU = w;            w = align_up(w + (size_t)N * HIDC * 2, 256);
    unsigned short* h1 = (unsigned short*)w;  w = align_up(w + (size_t)N * HIDC * 2, 256);
    unsigned short* h2 = (unsigned short*)w;  w = align_up(w + (size_t)N * HIDC * 2 + 65536, 256);
    size_t required = (size_t)(w - w0);
    if (ws_size < required) return;

    float* agg25 = (float*)aggU;
    unsigned short* aggH = (unsigned short*)aggU;
    // transient aliases (dead before their host buffers are first written):
    int* hist = (int*)aggU;   // NCH*NBKT ints = 625 KB, dead after bucket_scatter
    int2* pairs = (int2*)h2;  // E*8B = 12.8 MB, dead after bucket_csrfill

    const int nbN = (N + 255) / 256;
    const dim3 gemm_grid_f32((N + 63) / 64, HIDC / 64);
    const dim3 tgrid(16, 16);
    const dim3 pgrid(N_GRAPHSC, 8);

    // weight transposes
    wtransT<<<tgrid, 256, 0, stream>>>(W2l, W2lT);
    wtransT<<<tgrid, 256, 0, stream>>>(W2r, W2rT);
    wtransT<<<tgrid, 256, 0, stream>>>(W3l, W3lT);
    wtransT<<<tgrid, 256, 0, stream>>>(W3r, W3rT);

    // ---- bucketed CSR build ----
    hist_kernel<<<NCH, 256, 0, stream>>>(dst, hist);
    col_scan<<<NBKT, 512, 0, stream>>>(hist, colsum);
    bucket_base_scan<<<1, 512, 0, stream>>>(colsum, bbase);
    bucket_scatter<<<NCH, 256, 0, stream>>>(src, dst, hist, bbase, pairs);
    bucket_deg<<<NBKT, 256, 0, stream>>>(pairs, bbase, cnt);
    inv_kernel<<<nbN, 256, 0, stream>>>(cnt, invc, N);
    scan_partial<<<SCAN_NBLK, SCAN_BLK, 0, stream>>>(cnt, row_ofs, bsum);
    scan_bsums<<<1, 128, 0, stream>>>(bsum);
    scan_add<<<SCAN_NBLK, SCAN_BLK, 0, stream>>>(row_ofs, bsum);
    bucket_csrfill<<<NBKT, 256, 0, stream>>>(pairs, bbase, row_ofs, csr);

    // graph ranges + zero xc (pool uses atomicMax over non-negative floats)
    fill_u32<<<1, 256, 0, stream>>>((unsigned*)gstart, (unsigned)N, N_GRAPHSC);
    fill_u32<<<1, 256, 0, stream>>>((unsigned*)gend, 0u, N_GRAPHSC);
    ranges_bounds<<<nbN, 256, 0, stream>>>(batch, gstart, gend, N);
    fill_u32<<<(N_GRAPHSC * 3 * HIDC + 255) / 256, 256, 0, stream>>>((unsigned*)xc, 0u,
                                                                     N_GRAPHSC * 3 * HIDC);

    // ---- layer 1 (K=25, f32) ----
    gather25<<<(N * 32 + 255) / 256, 256, 0, stream>>>(x, row_ofs, csr, invc, agg25);
    sage_gemm_f32<IN_DIMC><<<gemm_grid_f32, 256, 0, stream>>>(agg25, x, W1l, W1r, b1, h1, N);
    pool_max<<<pgrid, 256, 0, stream>>>(h1, gstart, gend, xc, 0);

    // ---- layer 2 (MFMA, gload_lds, 128-row tile) ----
    gather256<<<(N * 64 + 255) / 256, 256, 0, stream>>>(h1, row_ofs, csr, invc, aggH);
    sage_gemm_mfma<<<NRB128, 512, 0, stream>>>(aggH, h1, W2lT, W2rT, b2, h2, N);
    pool_max<<<pgrid, 256, 0, stream>>>(h2, gstart, gend, xc, HIDC);

    // ---- layer 3 (MFMA, gload_lds, 128-row tile) ----
    gather256<<<(N * 64 + 255) / 256, 256, 0, stream>>>(h2, row_ofs, csr, invc, aggH);
    sage_gemm_mfma<<<NRB128, 512, 0, stream>>>(aggH, h2, W3lT, W3rT, b3, h1, N);
    pool_max<<<pgrid, 256, 0, stream>>>(h1, gstart, gend, xc, 2 * HIDC);

    // ---- head ----
    mlp1<<<N_GRAPHSC, 256, 0, stream>>>(xc, Wlin1, blin1, hmid);
    mlp2<<<N_GRAPHSC, 128, 0, stream>>>(hmid, Wlin2, blin2, out);
}

// Round 15
// 644.227 us; speedup vs baseline: 1.0410x; 1.0410x over previous
//
#include <hip/hip_runtime.h>
#include <hip/hip_bf16.h>

#define N_NODESC 100000
#define N_EDGESC 1600000
#define N_GRAPHSC 200
#define IN_DIMC 25
#define HIDC 256
#define OUT_DIMC 128
#define NRB64 ((N_NODESC + 63) / 64)   // 1563 row-blocks
#define NBKT ((N_NODESC + 255) / 256)  // 391 dst-buckets (256 nodes each)
#define NCH 400                        // edge chunks
#define CHSZ (N_EDGESC / NCH)          // 4000 edges/chunk (exact)

typedef __attribute__((ext_vector_type(8))) short bf16x8;
typedef __attribute__((ext_vector_type(4))) float f32x4;

// ---------- bf16 helpers (raw ushort storage) ----------
__device__ inline float bf2f(unsigned short u) {
    union { float f; unsigned u32; } c;
    c.u32 = ((unsigned)u) << 16;
    return c.f;
}
__device__ inline unsigned short f2bf(float f) {
    union { float f; unsigned u; } c;
    c.f = f;
    unsigned r = (c.u + 0x7FFFu + ((c.u >> 16) & 1u)) >> 16;  // RNE
    return (unsigned short)r;
}
__device__ inline float u2f(unsigned u) {
    union { unsigned u; float f; } c;
    c.u = u;
    return c.f;
}

// ---------- utility fills ----------
__global__ void fill_u32(unsigned* __restrict__ p, unsigned v, int n) {
    int i = blockIdx.x * 256 + threadIdx.x;
    if (i < n) p[i] = v;
}

__global__ void inv_kernel(const int* __restrict__ cnt, float* __restrict__ inv, int n) {
    int i = blockIdx.x * 256 + threadIdx.x;
    if (i < n) inv[i] = 1.0f / (float)max(cnt[i], 1);
}

// ---------- bucketed CSR build ----------
__global__ __launch_bounds__(256) void hist_kernel(const int* __restrict__ dst,
                                                   int* __restrict__ hist) {
    __shared__ int h[NBKT];
    const int c = blockIdx.x, tid = threadIdx.x;
    for (int t = tid; t < NBKT; t += 256) h[t] = 0;
    __syncthreads();
    const int e0 = c * CHSZ;
    for (int e = e0 + tid; e < e0 + CHSZ; e += 256) atomicAdd(&h[dst[e] >> 8], 1);
    __syncthreads();
    for (int t = tid; t < NBKT; t += 256) hist[c * NBKT + t] = h[t];
}

__global__ __launch_bounds__(512) void col_scan(int* __restrict__ hist,
                                                int* __restrict__ colsum) {
    __shared__ int sm[512];
    const int b = blockIdx.x, t = threadIdx.x;
    int v = (t < NCH) ? hist[t * NBKT + b] : 0;
    sm[t] = v;
    __syncthreads();
    for (int off = 1; off < 512; off <<= 1) {
        int u = (t >= off) ? sm[t - off] : 0;
        __syncthreads();
        sm[t] += u;
        __syncthreads();
    }
    if (t < NCH) hist[t * NBKT + b] = sm[t] - v;  // chunk-prefix within bucket
    if (t == 511) colsum[b] = sm[511];            // bucket total
}

__global__ __launch_bounds__(512) void bucket_base_scan(const int* __restrict__ colsum,
                                                        int* __restrict__ base) {
    __shared__ int sm[512];
    const int t = threadIdx.x;
    int v = (t < NBKT) ? colsum[t] : 0;
    sm[t] = v;
    __syncthreads();
    for (int off = 1; off < 512; off <<= 1) {
        int u = (t >= off) ? sm[t - off] : 0;
        __syncthreads();
        sm[t] += u;
        __syncthreads();
    }
    if (t <= NBKT) base[t] = sm[t] - v;
}

__global__ __launch_bounds__(256) void bucket_scatter(const int* __restrict__ src,
                                                      const int* __restrict__ dst,
                                                      const int* __restrict__ chpre,
                                                      const int* __restrict__ base,
                                                      int2* __restrict__ pairs) {
    __shared__ int cur[NBKT];
    __shared__ int o2[NBKT];
    const int c = blockIdx.x, tid = threadIdx.x;
    for (int t = tid; t < NBKT; t += 256) {
        cur[t] = 0;
        o2[t] = base[t] + chpre[c * NBKT + t];
    }
    __syncthreads();
    const int e0 = c * CHSZ;
    for (int e = e0 + tid; e < e0 + CHSZ; e += 256) {
        int s = src[e], d = dst[e];
        int b = d >> 8;
        int p = atomicAdd(&cur[b], 1);
        pairs[o2[b] + p] = make_int2(s, d);
    }
}

// degrees + row_ofs directly (buckets are contiguous node ranges:
// row_ofs[node] = base[b] + local exclusive prefix of degrees)
__global__ __launch_bounds__(256) void bucket_deg(const int2* __restrict__ pairs,
                                                  const int* __restrict__ base,
                                                  int* __restrict__ cnt,
                                                  int* __restrict__ row_ofs) {
    __shared__ int h[256];
    __shared__ int sc[256];
    const int b = blockIdx.x, tid = threadIdx.x;
    h[tid] = 0;
    __syncthreads();
    for (int i = base[b] + tid; i < base[b + 1]; i += 256)
        atomicAdd(&h[pairs[i].y & 255], 1);
    __syncthreads();
    int v = h[tid];
    sc[tid] = v;
    __syncthreads();
    for (int off = 1; off < 256; off <<= 1) {
        int t = (tid >= off) ? sc[tid - off] : 0;
        __syncthreads();
        sc[tid] += t;
        __syncthreads();
    }
    int node = b * 256 + tid;
    if (node < N_NODESC) {
        cnt[node] = v;
        row_ofs[node] = base[b] + sc[tid] - v;
    }
    if (node == N_NODESC) row_ofs[N_NODESC] = N_EDGESC;
}

__global__ __launch_bounds__(256) void bucket_csrfill(const int2* __restrict__ pairs,
                                                      const int* __restrict__ base,
                                                      const int* __restrict__ row_ofs,
                                                      int* __restrict__ csr) {
    __shared__ int cur[256];
    __shared__ int ob[256];
    const int b = blockIdx.x, tid = threadIdx.x;
    int node = b * 256 + tid;
    ob[tid] = (node < N_NODESC) ? row_ofs[node] : 0;
    cur[tid] = 0;
    __syncthreads();
    for (int i = base[b] + tid; i < base[b + 1]; i += 256) {
        int2 pr = pairs[i];
        int loc = pr.y & 255;
        int p = atomicAdd(&cur[loc], 1);
        csr[ob[loc] + p] = pr.x;
    }
}

// ---------- graph ranges: boundary scan (batch sorted; no atomics) ----------
__global__ void ranges_bounds(const int* __restrict__ batch, int* __restrict__ gstart,
                              int* __restrict__ gend, int n) {
    int i = blockIdx.x * 256 + threadIdx.x;
    if (i >= n) return;
    int g = batch[i];
    if (i == 0 || batch[i - 1] != g) gstart[g] = i;
    if (i == n - 1 || batch[i + 1] != g) gend[g] = i + 1;
}

// ---------- weight transpose f32[256][256] -> bf16 WT[n][k] ----------
__global__ void wtransT(const float* __restrict__ W, unsigned short* __restrict__ WT) {
    __shared__ float t[16][17];
    int bx = blockIdx.x, by = blockIdx.y;
    int tx = threadIdx.x & 15, ty = threadIdx.x >> 4;
    t[ty][tx] = W[(by * 16 + ty) * HIDC + bx * 16 + tx];
    __syncthreads();
    WT[(size_t)(bx * 16 + ty) * HIDC + by * 16 + tx] = f2bf(t[tx][ty]);
}

// ---------- layer-1 mean gather (f32, 25 channels) ----------
__global__ void gather25(const float* __restrict__ x, const int* __restrict__ ofs,
                         const int* __restrict__ csr, const float* __restrict__ inv,
                         float* __restrict__ agg) {
    int idx = blockIdx.x * 256 + threadIdx.x;
    int node = idx >> 5, c = idx & 31;
    if (node >= N_NODESC || c >= IN_DIMC) return;
    float acc = 0.0f;
    int s = ofs[node], e = ofs[node + 1];
    for (int j = s; j < e; ++j) acc += x[(size_t)csr[j] * IN_DIMC + c];
    agg[(size_t)node * IN_DIMC + c] = acc * inv[node];
}

// ---------- hidden mean gather: one wave/node, half-wave/edge, 8 rows in flight ----------
__global__ void gather256(const unsigned short* __restrict__ h, const int* __restrict__ ofs,
                          const int* __restrict__ csr, const float* __restrict__ inv,
                          unsigned short* __restrict__ agg) {
    long long gtid = (long long)blockIdx.x * 256 + threadIdx.x;
    int node = (int)(gtid >> 6);
    if (node >= N_NODESC) return;
    const int lane = threadIdx.x & 63;
    const int half = lane >> 5;
    const int l = lane & 31;
    const int s = ofs[node], e = ofs[node + 1];

    float a0 = 0, a1 = 0, a2 = 0, a3 = 0, a4 = 0, a5 = 0, a6 = 0, a7 = 0;
    const size_t coff = (size_t)l * 8;

#define ACC8(v)                                                             \
    a0 += u2f(((unsigned)(v).x) << 16); a1 += u2f(((unsigned)(v).x) & 0xffff0000u); \
    a2 += u2f(((unsigned)(v).y) << 16); a3 += u2f(((unsigned)(v).y) & 0xffff0000u); \
    a4 += u2f(((unsigned)(v).z) << 16); a5 += u2f(((unsigned)(v).z) & 0xffff0000u); \
    a6 += u2f(((unsigned)(v).w) << 16); a7 += u2f(((unsigned)(v).w) & 0xffff0000u);

    int j = s + half;
    for (; j + 6 < e; j += 8) {
        int sn0 = csr[j];
        int sn1 = csr[j + 2];
        int sn2 = csr[j + 4];
        int sn3 = csr[j + 6];
        int4 v0 = *reinterpret_cast<const int4*>(h + (size_t)sn0 * HIDC + coff);
        int4 v1 = *reinterpret_cast<const int4*>(h + (size_t)sn1 * HIDC + coff);
        int4 v2 = *reinterpret_cast<const int4*>(h + (size_t)sn2 * HIDC + coff);
        int4 v3 = *reinterpret_cast<const int4*>(h + (size_t)sn3 * HIDC + coff);
        ACC8(v0) ACC8(v1) ACC8(v2) ACC8(v3)
    }
    for (; j < e; j += 2) {
        int sn0 = csr[j];
        int4 v0 = *reinterpret_cast<const int4*>(h + (size_t)sn0 * HIDC + coff);
        ACC8(v0)
    }
#undef ACC8

    a0 += __shfl_xor(a0, 32, 64); a1 += __shfl_xor(a1, 32, 64);
    a2 += __shfl_xor(a2, 32, 64); a3 += __shfl_xor(a3, 32, 64);
    a4 += __shfl_xor(a4, 32, 64); a5 += __shfl_xor(a5, 32, 64);
    a6 += __shfl_xor(a6, 32, 64); a7 += __shfl_xor(a7, 32, 64);

    if (half == 0) {
        float sc = inv[node];
        int4 p;
        p.x = (int)((unsigned)f2bf(a0 * sc) | ((unsigned)f2bf(a1 * sc) << 16));
        p.y = (int)((unsigned)f2bf(a2 * sc) | ((unsigned)f2bf(a3 * sc) << 16));
        p.z = (int)((unsigned)f2bf(a4 * sc) | ((unsigned)f2bf(a5 * sc) << 16));
        p.w = (int)((unsigned)f2bf(a6 * sc) | ((unsigned)f2bf(a7 * sc) << 16));
        *reinterpret_cast<int4*>(agg + (size_t)node * HIDC + coff) = p;
    }
}

// ---------- layer-1 f32 SAGE GEMM (K=25) ----------
template <int K>
__global__ __launch_bounds__(256) void sage_gemm_f32(
    const float* __restrict__ agg, const float* __restrict__ h,
    const float* __restrict__ Wl, const float* __restrict__ Wr,
    const float* __restrict__ bias,
    unsigned short* __restrict__ out, int nrows) {
    constexpr int BM = 64, BN = 64, BK = 16;
    __shared__ float sA[BK][BM + 4];
    __shared__ float sB[BK][BN + 4];
    const int tid = threadIdx.x;
    const int tx = tid & 15, ty = tid >> 4;
    const int rowbase = blockIdx.x * BM;
    const int colbase = blockIdx.y * BN;
    float acc[4][4] = {};
    const int lrow = tid >> 2, lkq = (tid & 3) * 4;
    const int lkB = tid >> 4, lnB = (tid & 15) * 4;

    for (int pass = 0; pass < 2; ++pass) {
        const float* __restrict__ A = pass ? h : agg;
        const float* __restrict__ W = pass ? Wr : Wl;
        const int grow = rowbase + lrow;
        for (int kb = 0; kb < K; kb += BK) {
#pragma unroll
            for (int j = 0; j < 4; ++j) {
                int k = kb + lkq + j;
                float v = 0.0f;
                if (grow < nrows && k < K) v = A[(size_t)grow * K + k];
                sA[lkq + j][lrow] = v;
            }
#pragma unroll
            for (int j = 0; j < 4; ++j) {
                int k = kb + lkB;
                int n = colbase + lnB + j;
                sB[lkB][lnB + j] = (k < K) ? W[(size_t)k * HIDC + n] : 0.0f;
            }
            __syncthreads();
#pragma unroll
            for (int kk = 0; kk < BK; ++kk) {
                float a[4], b[4];
#pragma unroll
                for (int i = 0; i < 4; ++i) a[i] = sA[kk][ty * 4 + i];
#pragma unroll
                for (int j = 0; j < 4; ++j) b[j] = sB[kk][tx * 4 + j];
#pragma unroll
                for (int i = 0; i < 4; ++i)
#pragma unroll
                    for (int j = 0; j < 4; ++j) acc[i][j] += a[i] * b[j];
            }
            __syncthreads();
        }
    }
#pragma unroll
    for (int i = 0; i < 4; ++i) {
        int r = rowbase + ty * 4 + i;
        if (r >= nrows) continue;
#pragma unroll
        for (int j = 0; j < 4; ++j) {
            int c = colbase + tx * 4 + j;
            out[(size_t)r * HIDC + c] = f2bf(fmaxf(acc[i][j] + bias[c], 0.0f));
        }
    }
}

// ---------- MFMA bf16 SAGE GEMM, m97-style 64-row tile (best measured) ----------
__global__ __launch_bounds__(256) void sage_gemm_mfma(
    const unsigned short* __restrict__ A0, const unsigned short* __restrict__ A1,
    const unsigned short* __restrict__ B0T, const unsigned short* __restrict__ B1T,
    const float* __restrict__ bias, unsigned short* __restrict__ out, int M) {
    constexpr int KD = 256;
    __shared__ unsigned short sA[64 * 64];   // [64 r][64 k] 8KB
    __shared__ unsigned short sB[256 * 64];  // [256 c][64 k] 32KB
    const int rowbase = blockIdx.x * 64;
    const int tid = threadIdx.x;
    const int lane = tid & 63;
    const int w = tid >> 6;  // wave 0..3 = col stripe
    const int fr = lane & 15;
    const int kq8 = (lane >> 4) << 3;  // 0,8,16,24 elems

    const int srow = lane >> 3;            // row within 8-row stripe
    const int schunk = (lane & 7) ^ srow;  // inverse-swizzled source 16B chunk

    f32x4 acc[4][4] = {};

    for (int pass = 0; pass < 2; ++pass) {
        const unsigned short* __restrict__ A = pass ? A1 : A0;
        const unsigned short* __restrict__ BT = pass ? B1T : B0T;
        for (int ks = 0; ks < 4; ++ks) {
            const int kb = ks * 64;
            __syncthreads();  // prior k-step frag reads done before overwrite
#pragma unroll
            for (int c = 0; c < 2; ++c) {
                int ar = w * 16 + c * 8 + srow;
                const unsigned short* g = A + (size_t)(rowbase + ar) * KD + kb + (schunk << 3);
                __builtin_amdgcn_global_load_lds(
                    (const __attribute__((address_space(1))) void*)g,
                    (__attribute__((address_space(3))) void*)(sA + (w * 16 + c * 8) * 64),
                    16, 0, 0);
            }
#pragma unroll
            for (int c = 0; c < 8; ++c) {
                int br = w * 64 + c * 8 + srow;
                const unsigned short* g = BT + (size_t)br * KD + kb + (schunk << 3);
                __builtin_amdgcn_global_load_lds(
                    (const __attribute__((address_space(1))) void*)g,
                    (__attribute__((address_space(3))) void*)(sB + (w * 64 + c * 8) * 64),
                    16, 0, 0);
            }
            __syncthreads();  // vmcnt drained here -> LDS ready
#pragma unroll
            for (int kg = 0; kg < 2; ++kg) {
                bf16x8 af[4], bfr[4];
#pragma unroll
                for (int t = 0; t < 4; ++t) {
                    int ra = t * 16 + fr;
                    int ba = ra * 128 + ((kg * 64 + kq8 * 2) ^ ((ra & 7) << 4));
                    af[t] = *reinterpret_cast<const bf16x8*>(
                        reinterpret_cast<const char*>(sA) + ba);
                    int rb = w * 64 + t * 16 + fr;
                    int bb2 = rb * 128 + ((kg * 64 + kq8 * 2) ^ ((rb & 7) << 4));
                    bfr[t] = *reinterpret_cast<const bf16x8*>(
                        reinterpret_cast<const char*>(sB) + bb2);
                }
#pragma unroll
                for (int i = 0; i < 4; ++i)
#pragma unroll
                    for (int j = 0; j < 4; ++j)
                        acc[i][j] = __builtin_amdgcn_mfma_f32_16x16x32_bf16(
                            af[i], bfr[j], acc[i][j], 0, 0, 0);
            }
        }
    }

    const int crow0 = (lane >> 4) << 2;
#pragma unroll
    for (int i = 0; i < 4; ++i) {
#pragma unroll
        for (int j = 0; j < 4; ++j) {
            int col = w * 64 + j * 16 + fr;
            float bb = bias[col];
#pragma unroll
            for (int r = 0; r < 4; ++r) {
                int row = rowbase + i * 16 + crow0 + r;
                if (row < M)
                    out[(size_t)row * HIDC + col] = f2bf(fmaxf(acc[i][j][r] + bb, 0.0f));
            }
        }
    }
}

// ---------- segment-max pool: 8-way parallel per graph, atomicMax (values >= 0) ----------
__global__ void pool_max(const unsigned short* __restrict__ h, const int* __restrict__ gstart,
                         const int* __restrict__ gend, float* __restrict__ xc, int col_off) {
    int g = blockIdx.x;
    int chunk = blockIdx.y;  // 0..7
    int c = threadIdx.x;
    int s = gstart[g], e = gend[g];
    int len = e - s;
    if (len <= 0) return;
    int per = (len + 7) >> 3;
    int cs = s + chunk * per;
    int ce = min(cs + per, e);
    if (cs >= ce) return;
    float m = 0.0f;  // relu outputs >= 0
    for (int i = cs; i < ce; ++i) m = fmaxf(m, bf2f(h[(size_t)i * HIDC + c]));
    atomicMax(reinterpret_cast<int*>(&xc[(size_t)g * (3 * HIDC) + col_off + c]),
              __float_as_int(m));
}

// ---------- head MLPs ----------
__global__ void mlp1(const float* __restrict__ xc, const float* __restrict__ W,
                     const float* __restrict__ b, float* __restrict__ hmid) {
    __shared__ float row[3 * HIDC];
    int g = blockIdx.x;
    for (int i = threadIdx.x; i < 3 * HIDC; i += 256) row[i] = xc[(size_t)g * (3 * HIDC) + i];
    __syncthreads();
    float acc = b[threadIdx.x];
    for (int k = 0; k < 3 * HIDC; ++k) acc += row[k] * W[(size_t)k * HIDC + threadIdx.x];
    hmid[(size_t)g * HIDC + threadIdx.x] = fmaxf(acc, 0.0f);
}

__global__ void mlp2(const float* __restrict__ hmid, const float* __restrict__ W,
                     const float* __restrict__ b, float* __restrict__ out) {
    __shared__ float row[HIDC];
    int g = blockIdx.x;
    for (int i = threadIdx.x; i < HIDC; i += 128) row[i] = hmid[(size_t)g * HIDC + i];
    __syncthreads();
    float acc = b[threadIdx.x];
    for (int k = 0; k < HIDC; ++k) acc += row[k] * W[(size_t)k * OUT_DIMC + threadIdx.x];
    out[(size_t)g * OUT_DIMC + threadIdx.x] = acc;
}

static inline char* align_up(char* p, size_t a) {
    return (char*)(((uintptr_t)p + a - 1) & ~(uintptr_t)(a - 1));
}

extern "C" void kernel_launch(void* const* d_in, const int* in_sizes, int n_in,
                              void* d_out, int out_size, void* d_ws, size_t ws_size,
                              hipStream_t stream) {
    const float* x = (const float*)d_in[0];
    const int* edge_index = (const int*)d_in[1];
    const int* batch = (const int*)d_in[2];
    const float* W1l = (const float*)d_in[3];
    const float* W1r = (const float*)d_in[4];
    const float* b1 = (const float*)d_in[5];
    const float* W2l = (const float*)d_in[6];
    const float* W2r = (const float*)d_in[7];
    const float* b2 = (const float*)d_in[8];
    const float* W3l = (const float*)d_in[9];
    const float* W3r = (const float*)d_in[10];
    const float* b3 = (const float*)d_in[11];
    const float* Wlin1 = (const float*)d_in[12];
    const float* blin1 = (const float*)d_in[13];
    const float* Wlin2 = (const float*)d_in[14];
    const float* blin2 = (const float*)d_in[15];
    float* out = (float*)d_out;

    const int N = N_NODESC, E = N_EDGESC;
    const int* src = edge_index;
    const int* dst = edge_index + E;

    // ---- workspace carve-up ----
    char* w0 = (char*)d_ws;
    char* w = w0;
    int* cnt = (int*)w;        w = align_up(w + (size_t)N * 4, 256);
    float* invc = (float*)w;   w = align_up(w + (size_t)N * 4, 256);
    int* row_ofs = (int*)w;    w = align_up(w + (size_t)(N + 1) * 4, 256);
    int* bbase = (int*)w;      w = align_up(w + (size_t)(NBKT + 1) * 4, 256);
    int* colsum = (int*)w;     w = align_up(w + (size_t)NBKT * 4, 256);
    int* csr = (int*)w;        w = align_up(w + (size_t)E * 4, 256);
    int* gstart = (int*)w;     w = align_up(w + (size_t)N_GRAPHSC * 4, 256);
    int* gend = (int*)w;       w = align_up(w + (size_t)N_GRAPHSC * 4, 256);
    float* xc = (float*)w;     w = align_up(w + (size_t)N_GRAPHSC * 3 * HIDC * 4, 256);
    float* hmid = (float*)w;   w = align_up(w + (size_t)N_GRAPHSC * HIDC * 4, 256);
    unsigned short* W2lT = (unsigned short*)w; w = align_up(w + (size_t)HIDC * HIDC * 2, 256);
    unsigned short* W2rT = (unsigned short*)w; w = align_up(w + (size_t)HIDC * HIDC * 2, 256);
    unsigned short* W3lT = (unsigned short*)w; w = align_up(w + (size_t)HIDC * HIDC * 2, 256);
    unsigned short* W3rT = (unsigned short*)w; w = align_up(w + (size_t)HIDC * HIDC * 2, 256);
    char* aggU = w;            w = align_up(w + (size_t)N * HIDC * 2, 256);
    unsigned short* h1 = (unsigned short*)w;  w = align_up(w + (size_t)N * HIDC * 2, 256);
    unsigned short* h2 = (unsigned short*)w;  w = align_up(w + (size_t)N * HIDC * 2 + 65536, 256);
    size_t required = (size_t)(w - w0);
    if (ws_size < required) return;

    float* agg25 = (float*)aggU;
    unsigned short* aggH = (unsigned short*)aggU;
    // transient aliases (dead before their host buffers are first written):
    int* hist = (int*)aggU;   // NCH*NBKT ints = 625 KB, dead after bucket_scatter
    int2* pairs = (int2*)h2;  // E*8B = 12.8 MB, dead after bucket_csrfill

    const int nbN = (N + 255) / 256;
    const dim3 gemm_grid_f32((N + 63) / 64, HIDC / 64);
    const dim3 tgrid(16, 16);
    const dim3 pgrid(N_GRAPHSC, 8);

    // weight transposes
    wtransT<<<tgrid, 256, 0, stream>>>(W2l, W2lT);
    wtransT<<<tgrid, 256, 0, stream>>>(W2r, W2rT);
    wtransT<<<tgrid, 256, 0, stream>>>(W3l, W3lT);
    wtransT<<<tgrid, 256, 0, stream>>>(W3r, W3rT);

    // ---- bucketed CSR build (row_ofs fused into bucket_deg) ----
    hist_kernel<<<NCH, 256, 0, stream>>>(dst, hist);
    col_scan<<<NBKT, 512, 0, stream>>>(hist, colsum);
    bucket_base_scan<<<1, 512, 0, stream>>>(colsum, bbase);
    bucket_scatter<<<NCH, 256, 0, stream>>>(src, dst, hist, bbase, pairs);
    bucket_deg<<<NBKT, 256, 0, stream>>>(pairs, bbase, cnt, row_ofs);
    inv_kernel<<<nbN, 256, 0, stream>>>(cnt, invc, N);
    bucket_csrfill<<<NBKT, 256, 0, stream>>>(pairs, bbase, row_ofs, csr);

    // graph ranges + zero xc (pool uses atomicMax over non-negative floats)
    fill_u32<<<1, 256, 0, stream>>>((unsigned*)gstart, (unsigned)N, N_GRAPHSC);
    fill_u32<<<1, 256, 0, stream>>>((unsigned*)gend, 0u, N_GRAPHSC);
    ranges_bounds<<<nbN, 256, 0, stream>>>(batch, gstart, gend, N);
    fill_u32<<<(N_GRAPHSC * 3 * HIDC + 255) / 256, 256, 0, stream>>>((unsigned*)xc, 0u,
                                                                     N_GRAPHSC * 3 * HIDC);

    // ---- layer 1 (K=25, f32) ----
    gather25<<<(N * 32 + 255) / 256, 256, 0, stream>>>(x, row_ofs, csr, invc, agg25);
    sage_gemm_f32<IN_DIMC><<<gemm_grid_f32, 256, 0, stream>>>(agg25, x, W1l, W1r, b1, h1, N);
    pool_max<<<pgrid, 256, 0, stream>>>(h1, gstart, gend, xc, 0);

    // ---- layer 2 (MFMA, gload_lds, 64-row tile) ----
    gather256<<<(N * 64 + 255) / 256, 256, 0, stream>>>(h1, row_ofs, csr, invc, aggH);
    sage_gemm_mfma<<<NRB64, 256, 0, stream>>>(aggH, h1, W2lT, W2rT, b2, h2, N);
    pool_max<<<pgrid, 256, 0, stream>>>(h2, gstart, gend, xc, HIDC);

    // ---- layer 3 (MFMA, gload_lds, 64-row tile) ----
    gather256<<<(N * 64 + 255) / 256, 256, 0, stream>>>(h2, row_ofs, csr, invc, aggH);
    sage_gemm_mfma<<<NRB64, 256, 0, stream>>>(aggH, h2, W3lT, W3rT, b3, h1, N);
    pool_max<<<pgrid, 256, 0, stream>>>(h1, gstart, gend, xc, 2 * HIDC);

    // ---- head ----
    mlp1<<<N_GRAPHSC, 256, 0, stream>>>(xc, Wlin1, blin1, hmid);
    mlp2<<<N_GRAPHSC, 128, 0, stream>>>(hmid, Wlin2, blin2, out);
}

// Round 16
// 538.027 us; speedup vs baseline: 1.2464x; 1.1974x over previous
//
#include <hip/hip_runtime.h>
#include <hip/hip_bf16.h>

#define N_NODESC 100000
#define N_EDGESC 1600000
#define N_GRAPHSC 200
#define IN_DIMC 25
#define HIDC 256
#define OUT_DIMC 128
#define NRB64 ((N_NODESC + 63) / 64)   // 1563 row-blocks
#define NBKT ((N_NODESC + 255) / 256)  // 391 dst-buckets (256 nodes each)
#define NCH 400                        // edge chunks
#define CHSZ (N_EDGESC / NCH)          // 4000 edges/chunk (exact)

typedef __attribute__((ext_vector_type(8))) short bf16x8;
typedef __attribute__((ext_vector_type(4))) float f32x4;
typedef __attribute__((ext_vector_type(2))) float f32x2;

#if defined(__has_builtin)
#if __has_builtin(__builtin_amdgcn_cvt_pk_f32_fp8) && __has_builtin(__builtin_amdgcn_cvt_pk_fp8_f32)
#define HAVE_FP8_CVT 1
#endif
#endif

// ---------- bf16 helpers (raw ushort storage) ----------
__device__ inline float bf2f(unsigned short u) {
    union { float f; unsigned u32; } c;
    c.u32 = ((unsigned)u) << 16;
    return c.f;
}
__device__ inline unsigned short f2bf(float f) {
    union { float f; unsigned u; } c;
    c.f = f;
    unsigned r = (c.u + 0x7FFFu + ((c.u >> 16) & 1u)) >> 16;  // RNE
    return (unsigned short)r;
}
__device__ inline float u2f(unsigned u) {
    union { unsigned u; float f; } c;
    c.u = u;
    return c.f;
}

// ---------- fp8 e4m3 helpers (values >= 0 only) ----------
__device__ inline unsigned fp8enc_sw(float v) {
    v = fminf(v, 448.0f);
    union { float f; unsigned u; } c;
    c.f = v;
    unsigned bits = c.u + 0x7FFFFu + ((c.u >> 20) & 1u);  // RNE to 3 mantissa bits
    int e8 = (int)((bits >> 23) & 0xFF) - 120;
    if (e8 <= 0) return (unsigned)(v * 512.0f + 0.5f);  // denormal / small
    return ((unsigned)e8 << 3) | ((bits >> 20) & 7u);
}
__device__ inline float fp8dec_sw(unsigned u) {
    unsigned e = (u >> 3) & 15u, m = u & 7u;
    float fn = u2f(((e + 120u) << 23) | (m << 20));
    float fd = (float)m * 0.001953125f;  // 2^-9
    return e ? fn : fd;
}
__device__ inline unsigned pack4_fp8(float v0, float v1, float v2, float v3) {
#ifdef HAVE_FP8_CVT
    int r = __builtin_amdgcn_cvt_pk_fp8_f32(v0, v1, 0, false);
    r = __builtin_amdgcn_cvt_pk_fp8_f32(v2, v3, r, true);
    return (unsigned)r;
#else
    return fp8enc_sw(v0) | (fp8enc_sw(v1) << 8) | (fp8enc_sw(v2) << 16) | (fp8enc_sw(v3) << 24);
#endif
}

// ---------- utility fills ----------
__global__ void fill_u32(unsigned* __restrict__ p, unsigned v, int n) {
    int i = blockIdx.x * 256 + threadIdx.x;
    if (i < n) p[i] = v;
}

__global__ void inv_kernel(const int* __restrict__ cnt, float* __restrict__ inv, int n) {
    int i = blockIdx.x * 256 + threadIdx.x;
    if (i < n) inv[i] = 1.0f / (float)max(cnt[i], 1);
}

// ---------- bucketed CSR build ----------
__global__ __launch_bounds__(256) void hist_kernel(const int* __restrict__ dst,
                                                   int* __restrict__ hist) {
    __shared__ int h[NBKT];
    const int c = blockIdx.x, tid = threadIdx.x;
    for (int t = tid; t < NBKT; t += 256) h[t] = 0;
    __syncthreads();
    const int e0 = c * CHSZ;
    for (int e = e0 + tid; e < e0 + CHSZ; e += 256) atomicAdd(&h[dst[e] >> 8], 1);
    __syncthreads();
    for (int t = tid; t < NBKT; t += 256) hist[c * NBKT + t] = h[t];
}

__global__ __launch_bounds__(512) void col_scan(int* __restrict__ hist,
                                                int* __restrict__ colsum) {
    __shared__ int sm[512];
    const int b = blockIdx.x, t = threadIdx.x;
    int v = (t < NCH) ? hist[t * NBKT + b] : 0;
    sm[t] = v;
    __syncthreads();
    for (int off = 1; off < 512; off <<= 1) {
        int u = (t >= off) ? sm[t - off] : 0;
        __syncthreads();
        sm[t] += u;
        __syncthreads();
    }
    if (t < NCH) hist[t * NBKT + b] = sm[t] - v;  // chunk-prefix within bucket
    if (t == 511) colsum[b] = sm[511];            // bucket total
}

__global__ __launch_bounds__(512) void bucket_base_scan(const int* __restrict__ colsum,
                                                        int* __restrict__ base) {
    __shared__ int sm[512];
    const int t = threadIdx.x;
    int v = (t < NBKT) ? colsum[t] : 0;
    sm[t] = v;
    __syncthreads();
    for (int off = 1; off < 512; off <<= 1) {
        int u = (t >= off) ? sm[t - off] : 0;
        __syncthreads();
        sm[t] += u;
        __syncthreads();
    }
    if (t <= NBKT) base[t] = sm[t] - v;
}

__global__ __launch_bounds__(256) void bucket_scatter(const int* __restrict__ src,
                                                      const int* __restrict__ dst,
                                                      const int* __restrict__ chpre,
                                                      const int* __restrict__ base,
                                                      int2* __restrict__ pairs) {
    __shared__ int cur[NBKT];
    __shared__ int o2[NBKT];
    const int c = blockIdx.x, tid = threadIdx.x;
    for (int t = tid; t < NBKT; t += 256) {
        cur[t] = 0;
        o2[t] = base[t] + chpre[c * NBKT + t];
    }
    __syncthreads();
    const int e0 = c * CHSZ;
    for (int e = e0 + tid; e < e0 + CHSZ; e += 256) {
        int s = src[e], d = dst[e];
        int b = d >> 8;
        int p = atomicAdd(&cur[b], 1);
        pairs[o2[b] + p] = make_int2(s, d);
    }
}

// degrees + row_ofs (buckets are contiguous node ranges)
__global__ __launch_bounds__(256) void bucket_deg(const int2* __restrict__ pairs,
                                                  const int* __restrict__ base,
                                                  int* __restrict__ cnt,
                                                  int* __restrict__ row_ofs) {
    __shared__ int h[256];
    __shared__ int sc[256];
    const int b = blockIdx.x, tid = threadIdx.x;
    h[tid] = 0;
    __syncthreads();
    for (int i = base[b] + tid; i < base[b + 1]; i += 256)
        atomicAdd(&h[pairs[i].y & 255], 1);
    __syncthreads();
    int v = h[tid];
    sc[tid] = v;
    __syncthreads();
    for (int off = 1; off < 256; off <<= 1) {
        int t = (tid >= off) ? sc[tid - off] : 0;
        __syncthreads();
        sc[tid] += t;
        __syncthreads();
    }
    int node = b * 256 + tid;
    if (node < N_NODESC) {
        cnt[node] = v;
        row_ofs[node] = base[b] + sc[tid] - v;
    }
    if (node == N_NODESC) row_ofs[N_NODESC] = N_EDGESC;
}

__global__ __launch_bounds__(256) void bucket_csrfill(const int2* __restrict__ pairs,
                                                      const int* __restrict__ base,
                                                      const int* __restrict__ row_ofs,
                                                      int* __restrict__ csr) {
    __shared__ int cur[256];
    __shared__ int ob[256];
    const int b = blockIdx.x, tid = threadIdx.x;
    int node = b * 256 + tid;
    ob[tid] = (node < N_NODESC) ? row_ofs[node] : 0;
    cur[tid] = 0;
    __syncthreads();
    for (int i = base[b] + tid; i < base[b + 1]; i += 256) {
        int2 pr = pairs[i];
        int loc = pr.y & 255;
        int p = atomicAdd(&cur[loc], 1);
        csr[ob[loc] + p] = pr.x;
    }
}

// ---------- graph ranges ----------
__global__ void ranges_bounds(const int* __restrict__ batch, int* __restrict__ gstart,
                              int* __restrict__ gend, int n) {
    int i = blockIdx.x * 256 + threadIdx.x;
    if (i >= n) return;
    int g = batch[i];
    if (i == 0 || batch[i - 1] != g) gstart[g] = i;
    if (i == n - 1 || batch[i + 1] != g) gend[g] = i + 1;
}

// ---------- weight transpose f32[256][256] -> bf16 WT[n][k] ----------
__global__ void wtransT(const float* __restrict__ W, unsigned short* __restrict__ WT) {
    __shared__ float t[16][17];
    int bx = blockIdx.x, by = blockIdx.y;
    int tx = threadIdx.x & 15, ty = threadIdx.x >> 4;
    t[ty][tx] = W[(by * 16 + ty) * HIDC + bx * 16 + tx];
    __syncthreads();
    WT[(size_t)(bx * 16 + ty) * HIDC + by * 16 + tx] = f2bf(t[tx][ty]);
}

// permuted-K transpose: WT[n][p] = W[c(p)][n], c(p) = (p&0xC0) + (p&3)*16 + ((p>>2)&15)
// matches the mfma epilogue's fp8 byte permutation.
__global__ void wtransT_perm(const float* __restrict__ W, unsigned short* __restrict__ WT) {
    int n = blockIdx.x;
    int p = threadIdx.x;
    int c = (p & 0xC0) + ((p & 3) << 4) + ((p >> 2) & 15);
    WT[(size_t)n * HIDC + p] = f2bf(W[(size_t)c * HIDC + n]);
}

// ---------- layer-1 mean gather (f32, 25 channels) ----------
__global__ void gather25(const float* __restrict__ x, const int* __restrict__ ofs,
                         const int* __restrict__ csr, const float* __restrict__ inv,
                         float* __restrict__ agg) {
    int idx = blockIdx.x * 256 + threadIdx.x;
    int node = idx >> 5, c = idx & 31;
    if (node >= N_NODESC || c >= IN_DIMC) return;
    float acc = 0.0f;
    int s = ofs[node], e = ofs[node + 1];
    for (int j = s; j < e; ++j) acc += x[(size_t)csr[j] * IN_DIMC + c];
    agg[(size_t)node * IN_DIMC + c] = acc * inv[node];
}

// ---------- hidden mean gather over fp8 rows: one wave/node, half-wave/edge ----------
// hq rows are 256 bytes; positions may be col-permuted (compensated via W perm).
__global__ void gather256_fp8(const unsigned char* __restrict__ hq, const int* __restrict__ ofs,
                              const int* __restrict__ csr, const float* __restrict__ inv,
                              unsigned short* __restrict__ agg) {
    long long gtid = (long long)blockIdx.x * 256 + threadIdx.x;
    int node = (int)(gtid >> 6);
    if (node >= N_NODESC) return;
    const int lane = threadIdx.x & 63;
    const int half = lane >> 5;
    const int l = lane & 31;
    const int s = ofs[node], e = ofs[node + 1];

    float a0 = 0, a1 = 0, a2 = 0, a3 = 0, a4 = 0, a5 = 0, a6 = 0, a7 = 0;
    const size_t boff = (size_t)l * 8;  // byte offset of this lane's 8 fp8

#ifdef HAVE_FP8_CVT
#define DEC8(q)                                                             \
    {                                                                       \
        f32x2 d0 = __builtin_amdgcn_cvt_pk_f32_fp8((int)(q).x, false);      \
        f32x2 d1 = __builtin_amdgcn_cvt_pk_f32_fp8((int)(q).x, true);       \
        f32x2 d2 = __builtin_amdgcn_cvt_pk_f32_fp8((int)(q).y, false);      \
        f32x2 d3 = __builtin_amdgcn_cvt_pk_f32_fp8((int)(q).y, true);       \
        a0 += d0.x; a1 += d0.y; a2 += d1.x; a3 += d1.y;                     \
        a4 += d2.x; a5 += d2.y; a6 += d3.x; a7 += d3.y;                     \
    }
#else
#define DEC8(q)                                                             \
    {                                                                       \
        unsigned lo = (unsigned)(q).x, hi = (unsigned)(q).y;                \
        a0 += fp8dec_sw(lo & 255); a1 += fp8dec_sw((lo >> 8) & 255);        \
        a2 += fp8dec_sw((lo >> 16) & 255); a3 += fp8dec_sw(lo >> 24);       \
        a4 += fp8dec_sw(hi & 255); a5 += fp8dec_sw((hi >> 8) & 255);        \
        a6 += fp8dec_sw((hi >> 16) & 255); a7 += fp8dec_sw(hi >> 24);       \
    }
#endif

    int j = s + half;
    for (; j + 6 < e; j += 8) {
        int sn0 = csr[j];
        int sn1 = csr[j + 2];
        int sn2 = csr[j + 4];
        int sn3 = csr[j + 6];
        uint2 q0 = *reinterpret_cast<const uint2*>(hq + (size_t)sn0 * 256 + boff);
        uint2 q1 = *reinterpret_cast<const uint2*>(hq + (size_t)sn1 * 256 + boff);
        uint2 q2 = *reinterpret_cast<const uint2*>(hq + (size_t)sn2 * 256 + boff);
        uint2 q3 = *reinterpret_cast<const uint2*>(hq + (size_t)sn3 * 256 + boff);
        DEC8(q0) DEC8(q1) DEC8(q2) DEC8(q3)
    }
    for (; j < e; j += 2) {
        int sn0 = csr[j];
        uint2 q0 = *reinterpret_cast<const uint2*>(hq + (size_t)sn0 * 256 + boff);
        DEC8(q0)
    }
#undef DEC8

    a0 += __shfl_xor(a0, 32, 64); a1 += __shfl_xor(a1, 32, 64);
    a2 += __shfl_xor(a2, 32, 64); a3 += __shfl_xor(a3, 32, 64);
    a4 += __shfl_xor(a4, 32, 64); a5 += __shfl_xor(a5, 32, 64);
    a6 += __shfl_xor(a6, 32, 64); a7 += __shfl_xor(a7, 32, 64);

    if (half == 0) {
        float sc = inv[node];
        int4 p;
        p.x = (int)((unsigned)f2bf(a0 * sc) | ((unsigned)f2bf(a1 * sc) << 16));
        p.y = (int)((unsigned)f2bf(a2 * sc) | ((unsigned)f2bf(a3 * sc) << 16));
        p.z = (int)((unsigned)f2bf(a4 * sc) | ((unsigned)f2bf(a5 * sc) << 16));
        p.w = (int)((unsigned)f2bf(a6 * sc) | ((unsigned)f2bf(a7 * sc) << 16));
        *reinterpret_cast<int4*>(agg + (size_t)node * HIDC + (size_t)l * 8) = p;
    }
}

// ---------- layer-1 f32 SAGE GEMM (K=25), writes bf16 h + identity-packed fp8 copy ----------
template <int K>
__global__ __launch_bounds__(256) void sage_gemm_f32(
    const float* __restrict__ agg, const float* __restrict__ h,
    const float* __restrict__ Wl, const float* __restrict__ Wr,
    const float* __restrict__ bias,
    unsigned short* __restrict__ out, unsigned char* __restrict__ outq, int nrows) {
    constexpr int BM = 64, BN = 64, BK = 16;
    __shared__ float sA[BK][BM + 4];
    __shared__ float sB[BK][BN + 4];
    const int tid = threadIdx.x;
    const int tx = tid & 15, ty = tid >> 4;
    const int rowbase = blockIdx.x * BM;
    const int colbase = blockIdx.y * BN;
    float acc[4][4] = {};
    const int lrow = tid >> 2, lkq = (tid & 3) * 4;
    const int lkB = tid >> 4, lnB = (tid & 15) * 4;

    for (int pass = 0; pass < 2; ++pass) {
        const float* __restrict__ A = pass ? h : agg;
        const float* __restrict__ W = pass ? Wr : Wl;
        const int grow = rowbase + lrow;
        for (int kb = 0; kb < K; kb += BK) {
#pragma unroll
            for (int j = 0; j < 4; ++j) {
                int k = kb + lkq + j;
                float v = 0.0f;
                if (grow < nrows && k < K) v = A[(size_t)grow * K + k];
                sA[lkq + j][lrow] = v;
            }
#pragma unroll
            for (int j = 0; j < 4; ++j) {
                int k = kb + lkB;
                int n = colbase + lnB + j;
                sB[lkB][lnB + j] = (k < K) ? W[(size_t)k * HIDC + n] : 0.0f;
            }
            __syncthreads();
#pragma unroll
            for (int kk = 0; kk < BK; ++kk) {
                float a[4], b[4];
#pragma unroll
                for (int i = 0; i < 4; ++i) a[i] = sA[kk][ty * 4 + i];
#pragma unroll
                for (int j = 0; j < 4; ++j) b[j] = sB[kk][tx * 4 + j];
#pragma unroll
                for (int i = 0; i < 4; ++i)
#pragma unroll
                    for (int j = 0; j < 4; ++j) acc[i][j] += a[i] * b[j];
            }
            __syncthreads();
        }
    }
#pragma unroll
    for (int i = 0; i < 4; ++i) {
        int r = rowbase + ty * 4 + i;
        if (r >= nrows) continue;
        float v[4];
#pragma unroll
        for (int j = 0; j < 4; ++j) {
            int c = colbase + tx * 4 + j;
            v[j] = fmaxf(acc[i][j] + bias[c], 0.0f);
            out[(size_t)r * HIDC + c] = f2bf(v[j]);
        }
        *reinterpret_cast<unsigned*>(outq + (size_t)r * 256 + colbase + tx * 4) =
            pack4_fp8(v[0], v[1], v[2], v[3]);
    }
}

// ---------- MFMA bf16 SAGE GEMM, m97-style 64-row tile ----------
// Optionally writes col-permuted fp8 copy (outq != nullptr).
__global__ __launch_bounds__(256) void sage_gemm_mfma(
    const unsigned short* __restrict__ A0, const unsigned short* __restrict__ A1,
    const unsigned short* __restrict__ B0T, const unsigned short* __restrict__ B1T,
    const float* __restrict__ bias, unsigned short* __restrict__ out,
    unsigned char* __restrict__ outq, int M) {
    constexpr int KD = 256;
    __shared__ unsigned short sA[64 * 64];   // [64 r][64 k] 8KB
    __shared__ unsigned short sB[256 * 64];  // [256 c][64 k] 32KB
    const int rowbase = blockIdx.x * 64;
    const int tid = threadIdx.x;
    const int lane = tid & 63;
    const int w = tid >> 6;  // wave 0..3 = col stripe
    const int fr = lane & 15;
    const int kq8 = (lane >> 4) << 3;  // 0,8,16,24 elems

    const int srow = lane >> 3;            // row within 8-row stripe
    const int schunk = (lane & 7) ^ srow;  // inverse-swizzled source 16B chunk

    f32x4 acc[4][4] = {};

    for (int pass = 0; pass < 2; ++pass) {
        const unsigned short* __restrict__ A = pass ? A1 : A0;
        const unsigned short* __restrict__ BT = pass ? B1T : B0T;
        for (int ks = 0; ks < 4; ++ks) {
            const int kb = ks * 64;
            __syncthreads();  // prior k-step frag reads done before overwrite
#pragma unroll
            for (int c = 0; c < 2; ++c) {
                int ar = w * 16 + c * 8 + srow;
                const unsigned short* g = A + (size_t)(rowbase + ar) * KD + kb + (schunk << 3);
                __builtin_amdgcn_global_load_lds(
                    (const __attribute__((address_space(1))) void*)g,
                    (__attribute__((address_space(3))) void*)(sA + (w * 16 + c * 8) * 64),
                    16, 0, 0);
            }
#pragma unroll
            for (int c = 0; c < 8; ++c) {
                int br = w * 64 + c * 8 + srow;
                const unsigned short* g = BT + (size_t)br * KD + kb + (schunk << 3);
                __builtin_amdgcn_global_load_lds(
                    (const __attribute__((address_space(1))) void*)g,
                    (__attribute__((address_space(3))) void*)(sB + (w * 64 + c * 8) * 64),
                    16, 0, 0);
            }
            __syncthreads();  // vmcnt drained here -> LDS ready
#pragma unroll
            for (int kg = 0; kg < 2; ++kg) {
                bf16x8 af[4], bfr[4];
#pragma unroll
                for (int t = 0; t < 4; ++t) {
                    int ra = t * 16 + fr;
                    int ba = ra * 128 + ((kg * 64 + kq8 * 2) ^ ((ra & 7) << 4));
                    af[t] = *reinterpret_cast<const bf16x8*>(
                        reinterpret_cast<const char*>(sA) + ba);
                    int rb = w * 64 + t * 16 + fr;
                    int bb2 = rb * 128 + ((kg * 64 + kq8 * 2) ^ ((rb & 7) << 4));
                    bfr[t] = *reinterpret_cast<const bf16x8*>(
                        reinterpret_cast<const char*>(sB) + bb2);
                }
#pragma unroll
                for (int i = 0; i < 4; ++i)
#pragma unroll
                    for (int j = 0; j < 4; ++j)
                        acc[i][j] = __builtin_amdgcn_mfma_f32_16x16x32_bf16(
                            af[i], bfr[j], acc[i][j], 0, 0, 0);
            }
        }
    }

    // epilogue: C/D layout col=lane&15, row=4*(lane>>4)+r
    const int crow0 = (lane >> 4) << 2;
    float bb[4];
#pragma unroll
    for (int j = 0; j < 4; ++j) bb[j] = bias[w * 64 + j * 16 + fr];
#pragma unroll
    for (int i = 0; i < 4; ++i) {
#pragma unroll
        for (int r = 0; r < 4; ++r) {
            int row = rowbase + i * 16 + crow0 + r;
            if (row >= M) continue;
            float v[4];
#pragma unroll
            for (int j = 0; j < 4; ++j) {
                v[j] = fmaxf(acc[i][j][r] + bb[j], 0.0f);
                out[(size_t)row * HIDC + w * 64 + j * 16 + fr] = f2bf(v[j]);
            }
            if (outq)
                *reinterpret_cast<unsigned*>(outq + (size_t)row * 256 + w * 64 + fr * 4) =
                    pack4_fp8(v[0], v[1], v[2], v[3]);
        }
    }
}

// ---------- segment-max pool: 8-way parallel per graph, atomicMax (values >= 0) ----------
__global__ void pool_max(const unsigned short* __restrict__ h, const int* __restrict__ gstart,
                         const int* __restrict__ gend, float* __restrict__ xc, int col_off) {
    int g = blockIdx.x;
    int chunk = blockIdx.y;  // 0..7
    int c = threadIdx.x;
    int s = gstart[g], e = gend[g];
    int len = e - s;
    if (len <= 0) return;
    int per = (len + 7) >> 3;
    int cs = s + chunk * per;
    int ce = min(cs + per, e);
    if (cs >= ce) return;
    float m = 0.0f;  // relu outputs >= 0
    for (int i = cs; i < ce; ++i) m = fmaxf(m, bf2f(h[(size_t)i * HIDC + c]));
    atomicMax(reinterpret_cast<int*>(&xc[(size_t)g * (3 * HIDC) + col_off + c]),
              __float_as_int(m));
}

// ---------- head MLPs ----------
__global__ void mlp1(const float* __restrict__ xc, const float* __restrict__ W,
                     const float* __restrict__ b, float* __restrict__ hmid) {
    __shared__ float row[3 * HIDC];
    int g = blockIdx.x;
    for (int i = threadIdx.x; i < 3 * HIDC; i += 256) row[i] = xc[(size_t)g * (3 * HIDC) + i];
    __syncthreads();
    float acc = b[threadIdx.x];
    for (int k = 0; k < 3 * HIDC; ++k) acc += row[k] * W[(size_t)k * HIDC + threadIdx.x];
    hmid[(size_t)g * HIDC + threadIdx.x] = fmaxf(acc, 0.0f);
}

__global__ void mlp2(const float* __restrict__ hmid, const float* __restrict__ W,
                     const float* __restrict__ b, float* __restrict__ out) {
    __shared__ float row[HIDC];
    int g = blockIdx.x;
    for (int i = threadIdx.x; i < HIDC; i += 128) row[i] = hmid[(size_t)g * HIDC + i];
    __syncthreads();
    float acc = b[threadIdx.x];
    for (int k = 0; k < HIDC; ++k) acc += row[k] * W[(size_t)k * OUT_DIMC + threadIdx.x];
    out[(size_t)g * OUT_DIMC + threadIdx.x] = acc;
}

static inline char* align_up(char* p, size_t a) {
    return (char*)(((uintptr_t)p + a - 1) & ~(uintptr_t)(a - 1));
}

extern "C" void kernel_launch(void* const* d_in, const int* in_sizes, int n_in,
                              void* d_out, int out_size, void* d_ws, size_t ws_size,
                              hipStream_t stream) {
    const float* x = (const float*)d_in[0];
    const int* edge_index = (const int*)d_in[1];
    const int* batch = (const int*)d_in[2];
    const float* W1l = (const float*)d_in[3];
    const float* W1r = (const float*)d_in[4];
    const float* b1 = (const float*)d_in[5];
    const float* W2l = (const float*)d_in[6];
    const float* W2r = (const float*)d_in[7];
    const float* b2 = (const float*)d_in[8];
    const float* W3l = (const float*)d_in[9];
    const float* W3r = (const float*)d_in[10];
    const float* b3 = (const float*)d_in[11];
    const float* Wlin1 = (const float*)d_in[12];
    const float* blin1 = (const float*)d_in[13];
    const float* Wlin2 = (const float*)d_in[14];
    const float* blin2 = (const float*)d_in[15];
    float* out = (float*)d_out;

    const int N = N_NODESC, E = N_EDGESC;
    const int* src = edge_index;
    const int* dst = edge_index + E;

    // ---- workspace carve-up ----
    char* w0 = (char*)d_ws;
    char* w = w0;
    int* cnt = (int*)w;        w = align_up(w + (size_t)N * 4, 256);
    float* invc = (float*)w;   w = align_up(w + (size_t)N * 4, 256);
    int* row_ofs = (int*)w;    w = align_up(w + (size_t)(N + 1) * 4, 256);
    int* bbase = (int*)w;      w = align_up(w + (size_t)(NBKT + 1) * 4, 256);
    int* colsum = (int*)w;     w = align_up(w + (size_t)NBKT * 4, 256);
    int* csr = (int*)w;        w = align_up(w + (size_t)E * 4, 256);
    int* gstart = (int*)w;     w = align_up(w + (size_t)N_GRAPHSC * 4, 256);
    int* gend = (int*)w;       w = align_up(w + (size_t)N_GRAPHSC * 4, 256);
    float* xc = (float*)w;     w = align_up(w + (size_t)N_GRAPHSC * 3 * HIDC * 4, 256);
    float* hmid = (float*)w;   w = align_up(w + (size_t)N_GRAPHSC * HIDC * 4, 256);
    unsigned short* W2lT = (unsigned short*)w; w = align_up(w + (size_t)HIDC * HIDC * 2, 256);
    unsigned short* W2rT = (unsigned short*)w; w = align_up(w + (size_t)HIDC * HIDC * 2, 256);
    unsigned short* W3lT = (unsigned short*)w; w = align_up(w + (size_t)HIDC * HIDC * 2, 256);
    unsigned short* W3rT = (unsigned short*)w; w = align_up(w + (size_t)HIDC * HIDC * 2, 256);
    char* aggU = w;            w = align_up(w + (size_t)N * HIDC * 2, 256);
    unsigned short* h1 = (unsigned short*)w;  w = align_up(w + (size_t)N * HIDC * 2, 256);
    unsigned short* h2 = (unsigned short*)w;  w = align_up(w + (size_t)N * HIDC * 2 + 65536, 256);
    unsigned char* hq = (unsigned char*)w;    w = align_up(w + (size_t)N * 256, 256);
    size_t required = (size_t)(w - w0);
    if (ws_size < required) return;

    float* agg25 = (float*)aggU;
    unsigned short* aggH = (unsigned short*)aggU;
    // transient aliases (dead before their host buffers are first written):
    int* hist = (int*)aggU;   // NCH*NBKT ints = 625 KB, dead after bucket_scatter
    int2* pairs = (int2*)h2;  // E*8B = 12.8 MB, dead after bucket_csrfill

    const int nbN = (N + 255) / 256;
    const dim3 gemm_grid_f32((N + 63) / 64, HIDC / 64);
    const dim3 tgrid(16, 16);
    const dim3 pgrid(N_GRAPHSC, 8);

    // weight transposes (W3lT permuted to match mfma fp8 epilogue layout)
    wtransT<<<tgrid, 256, 0, stream>>>(W2l, W2lT);
    wtransT<<<tgrid, 256, 0, stream>>>(W2r, W2rT);
    wtransT_perm<<<HIDC, 256, 0, stream>>>(W3l, W3lT);
    wtransT<<<tgrid, 256, 0, stream>>>(W3r, W3rT);

    // ---- bucketed CSR build ----
    hist_kernel<<<NCH, 256, 0, stream>>>(dst, hist);
    col_scan<<<NBKT, 512, 0, stream>>>(hist, colsum);
    bucket_base_scan<<<1, 512, 0, stream>>>(colsum, bbase);
    bucket_scatter<<<NCH, 256, 0, stream>>>(src, dst, hist, bbase, pairs);
    bucket_deg<<<NBKT, 256, 0, stream>>>(pairs, bbase, cnt, row_ofs);
    inv_kernel<<<nbN, 256, 0, stream>>>(cnt, invc, N);
    bucket_csrfill<<<NBKT, 256, 0, stream>>>(pairs, bbase, row_ofs, csr);

    // graph ranges + zero xc
    fill_u32<<<1, 256, 0, stream>>>((unsigned*)gstart, (unsigned)N, N_GRAPHSC);
    fill_u32<<<1, 256, 0, stream>>>((unsigned*)gend, 0u, N_GRAPHSC);
    ranges_bounds<<<nbN, 256, 0, stream>>>(batch, gstart, gend, N);
    fill_u32<<<(N_GRAPHSC * 3 * HIDC + 255) / 256, 256, 0, stream>>>((unsigned*)xc, 0u,
                                                                     N_GRAPHSC * 3 * HIDC);

    // ---- layer 1 (K=25, f32) -> h1 bf16 + hq fp8 (identity layout) ----
    gather25<<<(N * 32 + 255) / 256, 256, 0, stream>>>(x, row_ofs, csr, invc, agg25);
    sage_gemm_f32<IN_DIMC><<<gemm_grid_f32, 256, 0, stream>>>(agg25, x, W1l, W1r, b1, h1, hq, N);
    pool_max<<<pgrid, 256, 0, stream>>>(h1, gstart, gend, xc, 0);

    // ---- layer 2: fp8 gather (identity) + MFMA -> h2 bf16 + hq fp8 (perm layout) ----
    gather256_fp8<<<(N * 64 + 255) / 256, 256, 0, stream>>>(hq, row_ofs, csr, invc, aggH);
    sage_gemm_mfma<<<NRB64, 256, 0, stream>>>(aggH, h1, W2lT, W2rT, b2, h2, hq, N);
    pool_max<<<pgrid, 256, 0, stream>>>(h2, gstart, gend, xc, HIDC);

    // ---- layer 3: fp8 gather (perm) + MFMA with perm'd W3lT -> h1 bf16 ----
    gather256_fp8<<<(N * 64 + 255) / 256, 256, 0, stream>>>(hq, row_ofs, csr, invc, aggH);
    sage_gemm_mfma<<<NRB64, 256, 0, stream>>>(aggH, h2, W3lT, W3rT, b3, h1, nullptr, N);
    pool_max<<<pgrid, 256, 0, stream>>>(h1, gstart, gend, xc, 2 * HIDC);

    // ---- head ----
    mlp1<<<N_GRAPHSC, 256, 0, stream>>>(xc, Wlin1, blin1, hmid);
    mlp2<<<N_GRAPHSC, 128, 0, stream>>>(hmid, Wlin2, blin2, out);
}

// Round 17
// 456.450 us; speedup vs baseline: 1.4692x; 1.1787x over previous
//
#include <hip/hip_runtime.h>
#include <hip/hip_bf16.h>

#define N_NODESC 100000
#define N_EDGESC 1600000
#define N_GRAPHSC 200
#define IN_DIMC 25
#define HIDC 256
#define OUT_DIMC 128
#define NRB64 ((N_NODESC + 63) / 64)   // 1563 row-blocks
#define NBKT ((N_NODESC + 255) / 256)  // 391 dst-buckets (256 nodes each)
#define NCH 400                        // edge chunks
#define CHSZ (N_EDGESC / NCH)          // 4000 edges/chunk (exact)

typedef __attribute__((ext_vector_type(8))) short bf16x8;
typedef __attribute__((ext_vector_type(4))) float f32x4;
typedef __attribute__((ext_vector_type(2))) float f32x2;

#if defined(__has_builtin)
#if __has_builtin(__builtin_amdgcn_cvt_pk_f32_fp8) && __has_builtin(__builtin_amdgcn_cvt_pk_fp8_f32)
#define HAVE_FP8_CVT 1
#endif
#endif

// ---------- bf16 helpers ----------
__device__ inline float bf2f(unsigned short u) {
    union { float f; unsigned u32; } c;
    c.u32 = ((unsigned)u) << 16;
    return c.f;
}
__device__ inline unsigned short f2bf(float f) {
    union { float f; unsigned u; } c;
    c.f = f;
    unsigned r = (c.u + 0x7FFFu + ((c.u >> 16) & 1u)) >> 16;  // RNE
    return (unsigned short)r;
}
__device__ inline float u2f(unsigned u) {
    union { unsigned u; float f; } c;
    c.u = u;
    return c.f;
}

// ---------- fp8 e4m3 helpers (values >= 0 only) ----------
__device__ inline unsigned fp8enc_sw(float v) {
    v = fminf(v, 448.0f);
    union { float f; unsigned u; } c;
    c.f = v;
    unsigned bits = c.u + 0x7FFFFu + ((c.u >> 20) & 1u);
    int e8 = (int)((bits >> 23) & 0xFF) - 120;
    if (e8 <= 0) return (unsigned)(v * 512.0f + 0.5f);
    return ((unsigned)e8 << 3) | ((bits >> 20) & 7u);
}
__device__ inline float fp8dec_sw(unsigned u) {
    unsigned e = (u >> 3) & 15u, m = u & 7u;
    float fn = u2f(((e + 120u) << 23) | (m << 20));
    float fd = (float)m * 0.001953125f;
    return e ? fn : fd;
}
__device__ inline unsigned pack4_fp8(float v0, float v1, float v2, float v3) {
#ifdef HAVE_FP8_CVT
    int r = __builtin_amdgcn_cvt_pk_fp8_f32(v0, v1, 0, false);
    r = __builtin_amdgcn_cvt_pk_fp8_f32(v2, v3, r, true);
    return (unsigned)r;
#else
    return fp8enc_sw(v0) | (fp8enc_sw(v1) << 8) | (fp8enc_sw(v2) << 16) | (fp8enc_sw(v3) << 24);
#endif
}

// ---------- utility fills ----------
__global__ void fill_u32(unsigned* __restrict__ p, unsigned v, int n) {
    int i = blockIdx.x * 256 + threadIdx.x;
    if (i < n) p[i] = v;
}

__global__ void inv_kernel(const int* __restrict__ cnt, float* __restrict__ inv, int n) {
    int i = blockIdx.x * 256 + threadIdx.x;
    if (i < n) inv[i] = 1.0f / (float)max(cnt[i], 1);
}

// ---------- bucketed CSR build ----------
__global__ __launch_bounds__(256) void hist_kernel(const int* __restrict__ dst,
                                                   int* __restrict__ hist) {
    __shared__ int h[NBKT];
    const int c = blockIdx.x, tid = threadIdx.x;
    for (int t = tid; t < NBKT; t += 256) h[t] = 0;
    __syncthreads();
    const int e0 = c * CHSZ;
    for (int e = e0 + tid; e < e0 + CHSZ; e += 256) atomicAdd(&h[dst[e] >> 8], 1);
    __syncthreads();
    for (int t = tid; t < NBKT; t += 256) hist[c * NBKT + t] = h[t];
}

__global__ __launch_bounds__(512) void col_scan(int* __restrict__ hist,
                                                int* __restrict__ colsum) {
    __shared__ int sm[512];
    const int b = blockIdx.x, t = threadIdx.x;
    int v = (t < NCH) ? hist[t * NBKT + b] : 0;
    sm[t] = v;
    __syncthreads();
    for (int off = 1; off < 512; off <<= 1) {
        int u = (t >= off) ? sm[t - off] : 0;
        __syncthreads();
        sm[t] += u;
        __syncthreads();
    }
    if (t < NCH) hist[t * NBKT + b] = sm[t] - v;
    if (t == 511) colsum[b] = sm[511];
}

__global__ __launch_bounds__(512) void bucket_base_scan(const int* __restrict__ colsum,
                                                        int* __restrict__ base) {
    __shared__ int sm[512];
    const int t = threadIdx.x;
    int v = (t < NBKT) ? colsum[t] : 0;
    sm[t] = v;
    __syncthreads();
    for (int off = 1; off < 512; off <<= 1) {
        int u = (t >= off) ? sm[t - off] : 0;
        __syncthreads();
        sm[t] += u;
        __syncthreads();
    }
    if (t <= NBKT) base[t] = sm[t] - v;
}

__global__ __launch_bounds__(256) void bucket_scatter(const int* __restrict__ src,
                                                      const int* __restrict__ dst,
                                                      const int* __restrict__ chpre,
                                                      const int* __restrict__ base,
                                                      int2* __restrict__ pairs) {
    __shared__ int cur[NBKT];
    __shared__ int o2[NBKT];
    const int c = blockIdx.x, tid = threadIdx.x;
    for (int t = tid; t < NBKT; t += 256) {
        cur[t] = 0;
        o2[t] = base[t] + chpre[c * NBKT + t];
    }
    __syncthreads();
    const int e0 = c * CHSZ;
    for (int e = e0 + tid; e < e0 + CHSZ; e += 256) {
        int s = src[e], d = dst[e];
        int b = d >> 8;
        int p = atomicAdd(&cur[b], 1);
        pairs[o2[b] + p] = make_int2(s, d);
    }
}

__global__ __launch_bounds__(256) void bucket_deg(const int2* __restrict__ pairs,
                                                  const int* __restrict__ base,
                                                  int* __restrict__ cnt,
                                                  int* __restrict__ row_ofs) {
    __shared__ int h[256];
    __shared__ int sc[256];
    const int b = blockIdx.x, tid = threadIdx.x;
    h[tid] = 0;
    __syncthreads();
    for (int i = base[b] + tid; i < base[b + 1]; i += 256)
        atomicAdd(&h[pairs[i].y & 255], 1);
    __syncthreads();
    int v = h[tid];
    sc[tid] = v;
    __syncthreads();
    for (int off = 1; off < 256; off <<= 1) {
        int t = (tid >= off) ? sc[tid - off] : 0;
        __syncthreads();
        sc[tid] += t;
        __syncthreads();
    }
    int node = b * 256 + tid;
    if (node < N_NODESC) {
        cnt[node] = v;
        row_ofs[node] = base[b] + sc[tid] - v;
    }
    if (node == N_NODESC) row_ofs[N_NODESC] = N_EDGESC;
}

__global__ __launch_bounds__(256) void bucket_csrfill(const int2* __restrict__ pairs,
                                                      const int* __restrict__ base,
                                                      const int* __restrict__ row_ofs,
                                                      int* __restrict__ csr) {
    __shared__ int cur[256];
    __shared__ int ob[256];
    const int b = blockIdx.x, tid = threadIdx.x;
    int node = b * 256 + tid;
    ob[tid] = (node < N_NODESC) ? row_ofs[node] : 0;
    cur[tid] = 0;
    __syncthreads();
    for (int i = base[b] + tid; i < base[b + 1]; i += 256) {
        int2 pr = pairs[i];
        int loc = pr.y & 255;
        int p = atomicAdd(&cur[loc], 1);
        csr[ob[loc] + p] = pr.x;
    }
}

// ---------- graph ranges ----------
__global__ void ranges_bounds(const int* __restrict__ batch, int* __restrict__ gstart,
                              int* __restrict__ gend, int n) {
    int i = blockIdx.x * 256 + threadIdx.x;
    if (i >= n) return;
    int g = batch[i];
    if (i == 0 || batch[i - 1] != g) gstart[g] = i;
    if (i == n - 1 || batch[i + 1] != g) gend[g] = i + 1;
}

// ---------- weight transposes ----------
__global__ void wtransT(const float* __restrict__ W, unsigned short* __restrict__ WT) {
    __shared__ float t[16][17];
    int bx = blockIdx.x, by = blockIdx.y;
    int tx = threadIdx.x & 15, ty = threadIdx.x >> 4;
    t[ty][tx] = W[(by * 16 + ty) * HIDC + bx * 16 + tx];
    __syncthreads();
    WT[(size_t)(bx * 16 + ty) * HIDC + by * 16 + tx] = f2bf(t[tx][ty]);
}

// permuted-K transpose (matches mfma fp8 epilogue byte layout):
// c(p) = (p&0xC0) + (p&3)*16 + ((p>>2)&15)
__global__ void wtransT_perm(const float* __restrict__ W, unsigned short* __restrict__ WT) {
    int n = blockIdx.x;
    int p = threadIdx.x;
    int c = (p & 0xC0) + ((p & 3) << 4) + ((p >> 2) & 15);
    WT[(size_t)n * HIDC + p] = f2bf(W[(size_t)c * HIDC + n]);
}

// combined layer-1 weight: BT1[n][k] = W1l[k][n] (k<25), W1r[k-32][n] (32<=k<57), else 0
__global__ void wtrans1(const float* __restrict__ W1l, const float* __restrict__ W1r,
                        unsigned short* __restrict__ BT1) {
    int n = blockIdx.x;
    int k = threadIdx.x;  // 0..63
    float v = 0.0f;
    if (k < IN_DIMC) v = W1l[(size_t)k * HIDC + n];
    else if (k >= 32 && k < 32 + IN_DIMC) v = W1r[(size_t)(k - 32) * HIDC + n];
    BT1[(size_t)n * 64 + k] = f2bf(v);
}

// ---------- x copy into Acat cols 32..63 (bf16, zero-padded) ----------
__global__ void xcopy(const float* __restrict__ x, unsigned short* __restrict__ Acat) {
    int i = blockIdx.x * 256 + threadIdx.x;
    int node = i >> 5, c = i & 31;
    if (node >= N_NODESC) return;
    Acat[(size_t)node * 64 + 32 + c] =
        (c < IN_DIMC) ? f2bf(x[(size_t)node * IN_DIMC + c]) : (unsigned short)0;
}

// ---------- layer-1 mean gather: wave/node, half-wave/edge, 4x unroll, bf16 out ----------
__global__ void gather25(const float* __restrict__ x, const int* __restrict__ ofs,
                         const int* __restrict__ csr, const float* __restrict__ inv,
                         unsigned short* __restrict__ Acat) {
    long long gtid = (long long)blockIdx.x * 256 + threadIdx.x;
    int node = (int)(gtid >> 6);
    if (node >= N_NODESC) return;
    const int lane = threadIdx.x & 63;
    const int half = lane >> 5;
    const int c = lane & 31;
    const bool act = c < IN_DIMC;
    const int s = ofs[node], e = ofs[node + 1];
    float acc = 0.0f;
    int j = s + half;
    for (; j + 6 < e; j += 8) {
        int sn0 = csr[j], sn1 = csr[j + 2], sn2 = csr[j + 4], sn3 = csr[j + 6];
        float v0 = act ? x[(size_t)sn0 * IN_DIMC + c] : 0.0f;
        float v1 = act ? x[(size_t)sn1 * IN_DIMC + c] : 0.0f;
        float v2 = act ? x[(size_t)sn2 * IN_DIMC + c] : 0.0f;
        float v3 = act ? x[(size_t)sn3 * IN_DIMC + c] : 0.0f;
        acc += (v0 + v1) + (v2 + v3);
    }
    for (; j < e; j += 2) {
        int sn = csr[j];
        acc += act ? x[(size_t)sn * IN_DIMC + c] : 0.0f;
    }
    acc += __shfl_xor(acc, 32, 64);
    if (half == 0) Acat[(size_t)node * 64 + c] = f2bf(acc * inv[node]);
}

// ---------- hidden mean gather over fp8 rows ----------
__global__ void gather256_fp8(const unsigned char* __restrict__ hq, const int* __restrict__ ofs,
                              const int* __restrict__ csr, const float* __restrict__ inv,
                              unsigned short* __restrict__ agg) {
    long long gtid = (long long)blockIdx.x * 256 + threadIdx.x;
    int node = (int)(gtid >> 6);
    if (node >= N_NODESC) return;
    const int lane = threadIdx.x & 63;
    const int half = lane >> 5;
    const int l = lane & 31;
    const int s = ofs[node], e = ofs[node + 1];

    float a0 = 0, a1 = 0, a2 = 0, a3 = 0, a4 = 0, a5 = 0, a6 = 0, a7 = 0;
    const size_t boff = (size_t)l * 8;

#ifdef HAVE_FP8_CVT
#define DEC8(q)                                                             \
    {                                                                       \
        f32x2 d0 = __builtin_amdgcn_cvt_pk_f32_fp8((int)(q).x, false);      \
        f32x2 d1 = __builtin_amdgcn_cvt_pk_f32_fp8((int)(q).x, true);       \
        f32x2 d2 = __builtin_amdgcn_cvt_pk_f32_fp8((int)(q).y, false);      \
        f32x2 d3 = __builtin_amdgcn_cvt_pk_f32_fp8((int)(q).y, true);       \
        a0 += d0.x; a1 += d0.y; a2 += d1.x; a3 += d1.y;                     \
        a4 += d2.x; a5 += d2.y; a6 += d3.x; a7 += d3.y;                     \
    }
#else
#define DEC8(q)                                                             \
    {                                                                       \
        unsigned lo = (unsigned)(q).x, hi = (unsigned)(q).y;                \
        a0 += fp8dec_sw(lo & 255); a1 += fp8dec_sw((lo >> 8) & 255);        \
        a2 += fp8dec_sw((lo >> 16) & 255); a3 += fp8dec_sw(lo >> 24);       \
        a4 += fp8dec_sw(hi & 255); a5 += fp8dec_sw((hi >> 8) & 255);        \
        a6 += fp8dec_sw((hi >> 16) & 255); a7 += fp8dec_sw(hi >> 24);       \
    }
#endif

    int j = s + half;
    for (; j + 6 < e; j += 8) {
        int sn0 = csr[j];
        int sn1 = csr[j + 2];
        int sn2 = csr[j + 4];
        int sn3 = csr[j + 6];
        uint2 q0 = *reinterpret_cast<const uint2*>(hq + (size_t)sn0 * 256 + boff);
        uint2 q1 = *reinterpret_cast<const uint2*>(hq + (size_t)sn1 * 256 + boff);
        uint2 q2 = *reinterpret_cast<const uint2*>(hq + (size_t)sn2 * 256 + boff);
        uint2 q3 = *reinterpret_cast<const uint2*>(hq + (size_t)sn3 * 256 + boff);
        DEC8(q0) DEC8(q1) DEC8(q2) DEC8(q3)
    }
    for (; j < e; j += 2) {
        int sn0 = csr[j];
        uint2 q0 = *reinterpret_cast<const uint2*>(hq + (size_t)sn0 * 256 + boff);
        DEC8(q0)
    }
#undef DEC8

    a0 += __shfl_xor(a0, 32, 64); a1 += __shfl_xor(a1, 32, 64);
    a2 += __shfl_xor(a2, 32, 64); a3 += __shfl_xor(a3, 32, 64);
    a4 += __shfl_xor(a4, 32, 64); a5 += __shfl_xor(a5, 32, 64);
    a6 += __shfl_xor(a6, 32, 64); a7 += __shfl_xor(a7, 32, 64);

    if (half == 0) {
        float sc = inv[node];
        int4 p;
        p.x = (int)((unsigned)f2bf(a0 * sc) | ((unsigned)f2bf(a1 * sc) << 16));
        p.y = (int)((unsigned)f2bf(a2 * sc) | ((unsigned)f2bf(a3 * sc) << 16));
        p.z = (int)((unsigned)f2bf(a4 * sc) | ((unsigned)f2bf(a5 * sc) << 16));
        p.w = (int)((unsigned)f2bf(a6 * sc) | ((unsigned)f2bf(a7 * sc) << 16));
        *reinterpret_cast<int4*>(agg + (size_t)node * HIDC + (size_t)l * 8) = p;
    }
}

// ---------- MFMA bf16 SAGE GEMM, m97-style 64-row tile, templated K-depth ----------
// TWOPASS: out = relu(A0@B0 + A1@B1 + b); else out = relu(A0@B0 + b).
// A: [M][KD] bf16. BT: [256 n][KD k] bf16. Optional fp8 copy (col-permuted).
template <int KD, bool TWOPASS>
__global__ __launch_bounds__(256) void sage_gemm_mfma(
    const unsigned short* __restrict__ A0, const unsigned short* __restrict__ A1,
    const unsigned short* __restrict__ B0T, const unsigned short* __restrict__ B1T,
    const float* __restrict__ bias, unsigned short* __restrict__ out,
    unsigned char* __restrict__ outq, int M) {
    __shared__ unsigned short sA[64 * 64];   // 8KB
    __shared__ unsigned short sB[256 * 64];  // 32KB
    const int rowbase = blockIdx.x * 64;
    const int tid = threadIdx.x;
    const int lane = tid & 63;
    const int w = tid >> 6;
    const int fr = lane & 15;
    const int kq8 = (lane >> 4) << 3;

    const int srow = lane >> 3;
    const int schunk = (lane & 7) ^ srow;

    f32x4 acc[4][4] = {};

#pragma unroll
    for (int pass = 0; pass < (TWOPASS ? 2 : 1); ++pass) {
        const unsigned short* __restrict__ A = (TWOPASS && pass) ? A1 : A0;
        const unsigned short* __restrict__ BT = (TWOPASS && pass) ? B1T : B0T;
#pragma unroll
        for (int ks = 0; ks < KD / 64; ++ks) {
            const int kb = ks * 64;
            __syncthreads();
#pragma unroll
            for (int c = 0; c < 2; ++c) {
                int ar = w * 16 + c * 8 + srow;
                const unsigned short* g = A + (size_t)(rowbase + ar) * KD + kb + (schunk << 3);
                __builtin_amdgcn_global_load_lds(
                    (const __attribute__((address_space(1))) void*)g,
                    (__attribute__((address_space(3))) void*)(sA + (w * 16 + c * 8) * 64),
                    16, 0, 0);
            }
#pragma unroll
            for (int c = 0; c < 8; ++c) {
                int br = w * 64 + c * 8 + srow;
                const unsigned short* g = BT + (size_t)br * KD + kb + (schunk << 3);
                __builtin_amdgcn_global_load_lds(
                    (const __attribute__((address_space(1))) void*)g,
                    (__attribute__((address_space(3))) void*)(sB + (w * 64 + c * 8) * 64),
                    16, 0, 0);
            }
            __syncthreads();
#pragma unroll
            for (int kg = 0; kg < 2; ++kg) {
                bf16x8 af[4], bfr[4];
#pragma unroll
                for (int t = 0; t < 4; ++t) {
                    int ra = t * 16 + fr;
                    int ba = ra * 128 + ((kg * 64 + kq8 * 2) ^ ((ra & 7) << 4));
                    af[t] = *reinterpret_cast<const bf16x8*>(
                        reinterpret_cast<const char*>(sA) + ba);
                    int rb = w * 64 + t * 16 + fr;
                    int bb2 = rb * 128 + ((kg * 64 + kq8 * 2) ^ ((rb & 7) << 4));
                    bfr[t] = *reinterpret_cast<const bf16x8*>(
                        reinterpret_cast<const char*>(sB) + bb2);
                }
#pragma unroll
                for (int i = 0; i < 4; ++i)
#pragma unroll
                    for (int j = 0; j < 4; ++j)
                        acc[i][j] = __builtin_amdgcn_mfma_f32_16x16x32_bf16(
                            af[i], bfr[j], acc[i][j], 0, 0, 0);
            }
        }
    }

    // epilogue: C/D layout col=lane&15, row=4*(lane>>4)+r
    const int crow0 = (lane >> 4) << 2;
    float bb[4];
#pragma unroll
    for (int j = 0; j < 4; ++j) bb[j] = bias[w * 64 + j * 16 + fr];
#pragma unroll
    for (int i = 0; i < 4; ++i) {
#pragma unroll
        for (int r = 0; r < 4; ++r) {
            int row = rowbase + i * 16 + crow0 + r;
            if (row >= M) continue;
            float v[4];
#pragma unroll
            for (int j = 0; j < 4; ++j) {
                v[j] = fmaxf(acc[i][j][r] + bb[j], 0.0f);
                out[(size_t)row * HIDC + w * 64 + j * 16 + fr] = f2bf(v[j]);
            }
            if (outq)
                *reinterpret_cast<unsigned*>(outq + (size_t)row * 256 + w * 64 + fr * 4) =
                    pack4_fp8(v[0], v[1], v[2], v[3]);
        }
    }
}

// ---------- segment-max pool ----------
__global__ void pool_max(const unsigned short* __restrict__ h, const int* __restrict__ gstart,
                         const int* __restrict__ gend, float* __restrict__ xc, int col_off) {
    int g = blockIdx.x;
    int chunk = blockIdx.y;
    int c = threadIdx.x;
    int s = gstart[g], e = gend[g];
    int len = e - s;
    if (len <= 0) return;
    int per = (len + 7) >> 3;
    int cs = s + chunk * per;
    int ce = min(cs + per, e);
    if (cs >= ce) return;
    float m = 0.0f;
    for (int i = cs; i < ce; ++i) m = fmaxf(m, bf2f(h[(size_t)i * HIDC + c]));
    atomicMax(reinterpret_cast<int*>(&xc[(size_t)g * (3 * HIDC) + col_off + c]),
              __float_as_int(m));
}

// ---------- head MLPs ----------
__global__ void mlp1(const float* __restrict__ xc, const float* __restrict__ W,
                     const float* __restrict__ b, float* __restrict__ hmid) {
    __shared__ float row[3 * HIDC];
    int g = blockIdx.x;
    for (int i = threadIdx.x; i < 3 * HIDC; i += 256) row[i] = xc[(size_t)g * (3 * HIDC) + i];
    __syncthreads();
    float acc = b[threadIdx.x];
    for (int k = 0; k < 3 * HIDC; ++k) acc += row[k] * W[(size_t)k * HIDC + threadIdx.x];
    hmid[(size_t)g * HIDC + threadIdx.x] = fmaxf(acc, 0.0f);
}

__global__ void mlp2(const float* __restrict__ hmid, const float* __restrict__ W,
                     const float* __restrict__ b, float* __restrict__ out) {
    __shared__ float row[HIDC];
    int g = blockIdx.x;
    for (int i = threadIdx.x; i < HIDC; i += 128) row[i] = hmid[(size_t)g * HIDC + i];
    __syncthreads();
    float acc = b[threadIdx.x];
    for (int k = 0; k < HIDC; ++k) acc += row[k] * W[(size_t)k * OUT_DIMC + threadIdx.x];
    out[(size_t)g * OUT_DIMC + threadIdx.x] = acc;
}

static inline char* align_up(char* p, size_t a) {
    return (char*)(((uintptr_t)p + a - 1) & ~(uintptr_t)(a - 1));
}

extern "C" void kernel_launch(void* const* d_in, const int* in_sizes, int n_in,
                              void* d_out, int out_size, void* d_ws, size_t ws_size,
                              hipStream_t stream) {
    const float* x = (const float*)d_in[0];
    const int* edge_index = (const int*)d_in[1];
    const int* batch = (const int*)d_in[2];
    const float* W1l = (const float*)d_in[3];
    const float* W1r = (const float*)d_in[4];
    const float* b1 = (const float*)d_in[5];
    const float* W2l = (const float*)d_in[6];
    const float* W2r = (const float*)d_in[7];
    const float* b2 = (const float*)d_in[8];
    const float* W3l = (const float*)d_in[9];
    const float* W3r = (const float*)d_in[10];
    const float* b3 = (const float*)d_in[11];
    const float* Wlin1 = (const float*)d_in[12];
    const float* blin1 = (const float*)d_in[13];
    const float* Wlin2 = (const float*)d_in[14];
    const float* blin2 = (const float*)d_in[15];
    float* out = (float*)d_out;

    const int N = N_NODESC, E = N_EDGESC;
    const int* src = edge_index;
    const int* dst = edge_index + E;

    // ---- workspace carve-up ----
    char* w0 = (char*)d_ws;
    char* w = w0;
    int* cnt = (int*)w;        w = align_up(w + (size_t)N * 4, 256);
    float* invc = (float*)w;   w = align_up(w + (size_t)N * 4, 256);
    int* row_ofs = (int*)w;    w = align_up(w + (size_t)(N + 1) * 4, 256);
    int* bbase = (int*)w;      w = align_up(w + (size_t)(NBKT + 1) * 4, 256);
    int* colsum = (int*)w;     w = align_up(w + (size_t)NBKT * 4, 256);
    int* csr = (int*)w;        w = align_up(w + (size_t)E * 4, 256);
    int* gstart = (int*)w;     w = align_up(w + (size_t)N_GRAPHSC * 4, 256);
    int* gend = (int*)w;       w = align_up(w + (size_t)N_GRAPHSC * 4, 256);
    float* xc = (float*)w;     w = align_up(w + (size_t)N_GRAPHSC * 3 * HIDC * 4, 256);
    float* hmid = (float*)w;   w = align_up(w + (size_t)N_GRAPHSC * HIDC * 4, 256);
    unsigned short* W2lT = (unsigned short*)w; w = align_up(w + (size_t)HIDC * HIDC * 2, 256);
    unsigned short* W2rT = (unsigned short*)w; w = align_up(w + (size_t)HIDC * HIDC * 2, 256);
    unsigned short* W3lT = (unsigned short*)w; w = align_up(w + (size_t)HIDC * HIDC * 2, 256);
    unsigned short* W3rT = (unsigned short*)w; w = align_up(w + (size_t)HIDC * HIDC * 2, 256);
    unsigned short* BT1 = (unsigned short*)w;  w = align_up(w + (size_t)HIDC * 64 * 2, 256);
    char* aggU = w;            w = align_up(w + (size_t)N * HIDC * 2, 256);
    unsigned short* h1 = (unsigned short*)w;  w = align_up(w + (size_t)N * HIDC * 2, 256);
    unsigned short* h2 = (unsigned short*)w;  w = align_up(w + (size_t)N * HIDC * 2 + 65536, 256);
    unsigned char* hq = (unsigned char*)w;    w = align_up(w + (size_t)N * 256, 256);
    size_t required = (size_t)(w - w0);
    if (ws_size < required) return;

    unsigned short* aggH = (unsigned short*)aggU;
    // transient aliases:
    int* hist = (int*)aggU;                  // dead after bucket_scatter
    unsigned short* Acat = (unsigned short*)aggU;  // [N][64] bf16; written by gather25/xcopy
                                                   // after hist dead; dead before aggH use
    int2* pairs = (int2*)h2;                 // dead after bucket_csrfill

    const int nbN = (N + 255) / 256;
    const dim3 tgrid(16, 16);
    const dim3 pgrid(N_GRAPHSC, 8);

    // weight transposes: layer-1 MFMA writes permuted fp8 -> W2lT perm; W3lT perm (layer-2
    // MFMA fp8 also perm); right-weights identity.
    wtransT_perm<<<HIDC, 256, 0, stream>>>(W2l, W2lT);
    wtransT<<<tgrid, 256, 0, stream>>>(W2r, W2rT);
    wtransT_perm<<<HIDC, 256, 0, stream>>>(W3l, W3lT);
    wtransT<<<tgrid, 256, 0, stream>>>(W3r, W3rT);
    wtrans1<<<HIDC, 64, 0, stream>>>(W1l, W1r, BT1);

    // ---- bucketed CSR build ----
    hist_kernel<<<NCH, 256, 0, stream>>>(dst, hist);
    col_scan<<<NBKT, 512, 0, stream>>>(hist, colsum);
    bucket_base_scan<<<1, 512, 0, stream>>>(colsum, bbase);
    bucket_scatter<<<NCH, 256, 0, stream>>>(src, dst, hist, bbase, pairs);
    bucket_deg<<<NBKT, 256, 0, stream>>>(pairs, bbase, cnt, row_ofs);
    inv_kernel<<<nbN, 256, 0, stream>>>(cnt, invc, N);
    bucket_csrfill<<<NBKT, 256, 0, stream>>>(pairs, bbase, row_ofs, csr);

    // graph ranges + zero xc
    fill_u32<<<1, 256, 0, stream>>>((unsigned*)gstart, (unsigned)N, N_GRAPHSC);
    fill_u32<<<1, 256, 0, stream>>>((unsigned*)gend, 0u, N_GRAPHSC);
    ranges_bounds<<<nbN, 256, 0, stream>>>(batch, gstart, gend, N);
    fill_u32<<<(N_GRAPHSC * 3 * HIDC + 255) / 256, 256, 0, stream>>>((unsigned*)xc, 0u,
                                                                     N_GRAPHSC * 3 * HIDC);

    // ---- layer 1 (MFMA KD=64 on [agg25|x]) -> h1 bf16 + hq fp8 (perm layout) ----
    gather25<<<(N * 64 + 255) / 256, 256, 0, stream>>>(x, row_ofs, csr, invc, Acat);
    xcopy<<<(N * 32 + 255) / 256, 256, 0, stream>>>(x, Acat);
    sage_gemm_mfma<64, false><<<NRB64, 256, 0, stream>>>(Acat, nullptr, BT1, nullptr, b1, h1,
                                                         hq, N);
    pool_max<<<pgrid, 256, 0, stream>>>(h1, gstart, gend, xc, 0);

    // ---- layer 2: fp8 gather (perm) + MFMA with perm'd W2lT -> h2 + hq fp8 (perm) ----
    gather256_fp8<<<(N * 64 + 255) / 256, 256, 0, stream>>>(hq, row_ofs, csr, invc, aggH);
    sage_gemm_mfma<256, true><<<NRB64, 256, 0, stream>>>(aggH, h1, W2lT, W2rT, b2, h2, hq, N);
    pool_max<<<pgrid, 256, 0, stream>>>(h2, gstart, gend, xc, HIDC);

    // ---- layer 3: fp8 gather (perm) + MFMA with perm'd W3lT -> h1 ----
    gather256_fp8<<<(N * 64 + 255) / 256, 256, 0, stream>>>(hq, row_ofs, csr, invc, aggH);
    sage_gemm_mfma<256, true><<<NRB64, 256, 0, stream>>>(aggH, h2, W3lT, W3rT, b3, h1, nullptr,
                                                         N);
    pool_max<<<pgrid, 256, 0, stream>>>(h1, gstart, gend, xc, 2 * HIDC);

    // ---- head ----
    mlp1<<<N_GRAPHSC, 256, 0, stream>>>(xc, Wlin1, blin1, hmid);
    mlp2<<<N_GRAPHSC, 128, 0, stream>>>(hmid, Wlin2, blin2, out);
}

// Round 18
// 443.803 us; speedup vs baseline: 1.5111x; 1.0285x over previous
//
#include <hip/hip_runtime.h>
#include <hip/hip_bf16.h>

#define N_NODESC 100000
#define N_EDGESC 1600000
#define N_GRAPHSC 200
#define IN_DIMC 25
#define HIDC 256
#define OUT_DIMC 128
#define NRB64 ((N_NODESC + 63) / 64)   // 1563 row-blocks
#define NBKT ((N_NODESC + 255) / 256)  // 391 dst-buckets (256 nodes each)
#define NCH 400                        // edge chunks
#define CHSZ (N_EDGESC / NCH)          // 4000 edges/chunk (exact)

typedef __attribute__((ext_vector_type(8))) short bf16x8;
typedef __attribute__((ext_vector_type(4))) float f32x4;
typedef __attribute__((ext_vector_type(2))) float f32x2;

#if defined(__has_builtin)
#if __has_builtin(__builtin_amdgcn_cvt_pk_f32_fp8) && __has_builtin(__builtin_amdgcn_cvt_pk_fp8_f32)
#define HAVE_FP8_CVT 1
#endif
#endif

// ---------- bf16 helpers ----------
__device__ inline float bf2f(unsigned short u) {
    union { float f; unsigned u32; } c;
    c.u32 = ((unsigned)u) << 16;
    return c.f;
}
__device__ inline unsigned short f2bf(float f) {
    union { float f; unsigned u; } c;
    c.f = f;
    unsigned r = (c.u + 0x7FFFu + ((c.u >> 16) & 1u)) >> 16;  // RNE
    return (unsigned short)r;
}
__device__ inline float u2f(unsigned u) {
    union { unsigned u; float f; } c;
    c.u = u;
    return c.f;
}

// ---------- fp8 e4m3 helpers (values >= 0 only) ----------
__device__ inline unsigned fp8enc_sw(float v) {
    v = fminf(v, 448.0f);
    union { float f; unsigned u; } c;
    c.f = v;
    unsigned bits = c.u + 0x7FFFFu + ((c.u >> 20) & 1u);
    int e8 = (int)((bits >> 23) & 0xFF) - 120;
    if (e8 <= 0) return (unsigned)(v * 512.0f + 0.5f);
    return ((unsigned)e8 << 3) | ((bits >> 20) & 7u);
}
__device__ inline float fp8dec_sw(unsigned u) {
    unsigned e = (u >> 3) & 15u, m = u & 7u;
    float fn = u2f(((e + 120u) << 23) | (m << 20));
    float fd = (float)m * 0.001953125f;
    return e ? fn : fd;
}
__device__ inline unsigned pack4_fp8(float v0, float v1, float v2, float v3) {
#ifdef HAVE_FP8_CVT
    int r = __builtin_amdgcn_cvt_pk_fp8_f32(v0, v1, 0, false);
    r = __builtin_amdgcn_cvt_pk_fp8_f32(v2, v3, r, true);
    return (unsigned)r;
#else
    return fp8enc_sw(v0) | (fp8enc_sw(v1) << 8) | (fp8enc_sw(v2) << 16) | (fp8enc_sw(v3) << 24);
#endif
}

// ---------- utility fills ----------
__global__ void fill_u32(unsigned* __restrict__ p, unsigned v, int n) {
    int i = blockIdx.x * 256 + threadIdx.x;
    if (i < n) p[i] = v;
}

// ---------- bucketed CSR build ----------
__global__ __launch_bounds__(256) void hist_kernel(const int* __restrict__ dst,
                                                   int* __restrict__ hist) {
    __shared__ int h[NBKT];
    const int c = blockIdx.x, tid = threadIdx.x;
    for (int t = tid; t < NBKT; t += 256) h[t] = 0;
    __syncthreads();
    const int e0 = c * CHSZ;
    for (int e = e0 + tid; e < e0 + CHSZ; e += 256) atomicAdd(&h[dst[e] >> 8], 1);
    __syncthreads();
    for (int t = tid; t < NBKT; t += 256) hist[c * NBKT + t] = h[t];
}

__global__ __launch_bounds__(512) void col_scan(int* __restrict__ hist,
                                                int* __restrict__ colsum) {
    __shared__ int sm[512];
    const int b = blockIdx.x, t = threadIdx.x;
    int v = (t < NCH) ? hist[t * NBKT + b] : 0;
    sm[t] = v;
    __syncthreads();
    for (int off = 1; off < 512; off <<= 1) {
        int u = (t >= off) ? sm[t - off] : 0;
        __syncthreads();
        sm[t] += u;
        __syncthreads();
    }
    if (t < NCH) hist[t * NBKT + b] = sm[t] - v;
    if (t == 511) colsum[b] = sm[511];
}

__global__ __launch_bounds__(512) void bucket_base_scan(const int* __restrict__ colsum,
                                                        int* __restrict__ base) {
    __shared__ int sm[512];
    const int t = threadIdx.x;
    int v = (t < NBKT) ? colsum[t] : 0;
    sm[t] = v;
    __syncthreads();
    for (int off = 1; off < 512; off <<= 1) {
        int u = (t >= off) ? sm[t - off] : 0;
        __syncthreads();
        sm[t] += u;
        __syncthreads();
    }
    if (t <= NBKT) base[t] = sm[t] - v;
}

__global__ __launch_bounds__(256) void bucket_scatter(const int* __restrict__ src,
                                                      const int* __restrict__ dst,
                                                      const int* __restrict__ chpre,
                                                      const int* __restrict__ base,
                                                      int2* __restrict__ pairs) {
    __shared__ int cur[NBKT];
    __shared__ int o2[NBKT];
    const int c = blockIdx.x, tid = threadIdx.x;
    for (int t = tid; t < NBKT; t += 256) {
        cur[t] = 0;
        o2[t] = base[t] + chpre[c * NBKT + t];
    }
    __syncthreads();
    const int e0 = c * CHSZ;
    for (int e = e0 + tid; e < e0 + CHSZ; e += 256) {
        int s = src[e], d = dst[e];
        int b = d >> 8;
        int p = atomicAdd(&cur[b], 1);
        pairs[o2[b] + p] = make_int2(s, d);
    }
}

// degrees + row_ofs + inv (buckets are contiguous node ranges)
__global__ __launch_bounds__(256) void bucket_deg(const int2* __restrict__ pairs,
                                                  const int* __restrict__ base,
                                                  int* __restrict__ row_ofs,
                                                  float* __restrict__ invc) {
    __shared__ int h[256];
    __shared__ int sc[256];
    const int b = blockIdx.x, tid = threadIdx.x;
    h[tid] = 0;
    __syncthreads();
    for (int i = base[b] + tid; i < base[b + 1]; i += 256)
        atomicAdd(&h[pairs[i].y & 255], 1);
    __syncthreads();
    int v = h[tid];
    sc[tid] = v;
    __syncthreads();
    for (int off = 1; off < 256; off <<= 1) {
        int t = (tid >= off) ? sc[tid - off] : 0;
        __syncthreads();
        sc[tid] += t;
        __syncthreads();
    }
    int node = b * 256 + tid;
    if (node < N_NODESC) {
        row_ofs[node] = base[b] + sc[tid] - v;
        invc[node] = 1.0f / (float)max(v, 1);
    }
    if (node == N_NODESC) row_ofs[N_NODESC] = N_EDGESC;
}

__global__ __launch_bounds__(256) void bucket_csrfill(const int2* __restrict__ pairs,
                                                      const int* __restrict__ base,
                                                      const int* __restrict__ row_ofs,
                                                      int* __restrict__ csr) {
    __shared__ int cur[256];
    __shared__ int ob[256];
    const int b = blockIdx.x, tid = threadIdx.x;
    int node = b * 256 + tid;
    ob[tid] = (node < N_NODESC) ? row_ofs[node] : 0;
    cur[tid] = 0;
    __syncthreads();
    for (int i = base[b] + tid; i < base[b + 1]; i += 256) {
        int2 pr = pairs[i];
        int loc = pr.y & 255;
        int p = atomicAdd(&cur[loc], 1);
        csr[ob[loc] + p] = pr.x;
    }
}

// ---------- graph ranges (batch sorted; writes every present graph) ----------
__global__ void ranges_bounds(const int* __restrict__ batch, int* __restrict__ gstart,
                              int* __restrict__ gend, int n) {
    int i = blockIdx.x * 256 + threadIdx.x;
    if (i >= n) return;
    int g = batch[i];
    if (i == 0 || batch[i - 1] != g) gstart[g] = i;
    if (i == n - 1 || batch[i + 1] != g) gend[g] = i + 1;
}

// ---------- all weight transposes in one kernel ----------
// z=0: W2lT (perm), z=1: W2rT, z=2: W3lT (perm), z=3: W3rT, z=4: BT1 [256 n][64 k]
__global__ void wtrans_all(const float* __restrict__ W1l, const float* __restrict__ W1r,
                           const float* __restrict__ W2l, const float* __restrict__ W2r,
                           const float* __restrict__ W3l, const float* __restrict__ W3r,
                           unsigned short* __restrict__ W2lT, unsigned short* __restrict__ W2rT,
                           unsigned short* __restrict__ W3lT, unsigned short* __restrict__ W3rT,
                           unsigned short* __restrict__ BT1) {
    int z = blockIdx.z;
    int tx = threadIdx.x & 15, ty = threadIdx.x >> 4;
    int n = blockIdx.y * 16 + ty;
    int p = blockIdx.x * 16 + tx;
    if (z == 4) {
        if (blockIdx.x >= 4) return;  // k < 64
        float v = 0.0f;
        if (p < IN_DIMC) v = W1l[(size_t)p * HIDC + n];
        else if (p >= 32 && p < 32 + IN_DIMC) v = W1r[(size_t)(p - 32) * HIDC + n];
        BT1[(size_t)n * 64 + p] = f2bf(v);
        return;
    }
    const float* W = (z == 0) ? W2l : (z == 1) ? W2r : (z == 2) ? W3l : W3r;
    unsigned short* WT = (z == 0) ? W2lT : (z == 1) ? W2rT : (z == 2) ? W3lT : W3rT;
    int c = (z == 0 || z == 2) ? ((p & 0xC0) + ((p & 3) << 4) + ((p >> 2) & 15)) : p;
    WT[(size_t)n * HIDC + p] = f2bf(W[(size_t)c * HIDC + n]);
}

// ---------- layer-1 mean gather + x copy (fused): wave/node, half-wave/edge ----------
__global__ void gather25(const float* __restrict__ x, const int* __restrict__ ofs,
                         const int* __restrict__ csr, const float* __restrict__ inv,
                         unsigned short* __restrict__ Acat) {
    long long gtid = (long long)blockIdx.x * 256 + threadIdx.x;
    int node = (int)(gtid >> 6);
    if (node >= N_NODESC) return;
    const int lane = threadIdx.x & 63;
    const int half = lane >> 5;
    const int c = lane & 31;
    const bool act = c < IN_DIMC;
    const int s = ofs[node], e = ofs[node + 1];
    float acc = 0.0f;
    int j = s + half;
    for (; j + 6 < e; j += 8) {
        int sn0 = csr[j], sn1 = csr[j + 2], sn2 = csr[j + 4], sn3 = csr[j + 6];
        float v0 = act ? x[(size_t)sn0 * IN_DIMC + c] : 0.0f;
        float v1 = act ? x[(size_t)sn1 * IN_DIMC + c] : 0.0f;
        float v2 = act ? x[(size_t)sn2 * IN_DIMC + c] : 0.0f;
        float v3 = act ? x[(size_t)sn3 * IN_DIMC + c] : 0.0f;
        acc += (v0 + v1) + (v2 + v3);
    }
    for (; j < e; j += 2) {
        int sn = csr[j];
        acc += act ? x[(size_t)sn * IN_DIMC + c] : 0.0f;
    }
    acc += __shfl_xor(acc, 32, 64);
    if (half == 0) {
        Acat[(size_t)node * 64 + c] = f2bf(acc * inv[node]);
    } else {
        Acat[(size_t)node * 64 + 32 + c] =
            act ? f2bf(x[(size_t)node * IN_DIMC + c]) : (unsigned short)0;
    }
}

// ---------- hidden mean gather over fp8 rows (packed f32x2 accumulation) ----------
__global__ void gather256_fp8(const unsigned char* __restrict__ hq, const int* __restrict__ ofs,
                              const int* __restrict__ csr, const float* __restrict__ inv,
                              unsigned short* __restrict__ agg) {
    long long gtid = (long long)blockIdx.x * 256 + threadIdx.x;
    int node = (int)(gtid >> 6);
    if (node >= N_NODESC) return;
    const int lane = threadIdx.x & 63;
    const int half = lane >> 5;
    const int l = lane & 31;
    const int s = ofs[node], e = ofs[node + 1];

    f32x2 A01 = {0.0f, 0.0f}, A23 = {0.0f, 0.0f}, A45 = {0.0f, 0.0f}, A67 = {0.0f, 0.0f};
    const size_t boff = (size_t)l * 8;

#ifdef HAVE_FP8_CVT
#define DEC8(q)                                                          \
    {                                                                    \
        A01 += __builtin_amdgcn_cvt_pk_f32_fp8((int)(q).x, false);       \
        A23 += __builtin_amdgcn_cvt_pk_f32_fp8((int)(q).x, true);        \
        A45 += __builtin_amdgcn_cvt_pk_f32_fp8((int)(q).y, false);       \
        A67 += __builtin_amdgcn_cvt_pk_f32_fp8((int)(q).y, true);        \
    }
#else
#define DEC8(q)                                                          \
    {                                                                    \
        unsigned lo = (unsigned)(q).x, hi = (unsigned)(q).y;             \
        A01.x += fp8dec_sw(lo & 255); A01.y += fp8dec_sw((lo >> 8) & 255);   \
        A23.x += fp8dec_sw((lo >> 16) & 255); A23.y += fp8dec_sw(lo >> 24); \
        A45.x += fp8dec_sw(hi & 255); A45.y += fp8dec_sw((hi >> 8) & 255);   \
        A67.x += fp8dec_sw((hi >> 16) & 255); A67.y += fp8dec_sw(hi >> 24); \
    }
#endif

    int j = s + half;
    for (; j + 6 < e; j += 8) {
        int sn0 = csr[j];
        int sn1 = csr[j + 2];
        int sn2 = csr[j + 4];
        int sn3 = csr[j + 6];
        uint2 q0 = *reinterpret_cast<const uint2*>(hq + (size_t)sn0 * 256 + boff);
        uint2 q1 = *reinterpret_cast<const uint2*>(hq + (size_t)sn1 * 256 + boff);
        uint2 q2 = *reinterpret_cast<const uint2*>(hq + (size_t)sn2 * 256 + boff);
        uint2 q3 = *reinterpret_cast<const uint2*>(hq + (size_t)sn3 * 256 + boff);
        DEC8(q0) DEC8(q1) DEC8(q2) DEC8(q3)
    }
    for (; j < e; j += 2) {
        int sn0 = csr[j];
        uint2 q0 = *reinterpret_cast<const uint2*>(hq + (size_t)sn0 * 256 + boff);
        DEC8(q0)
    }
#undef DEC8

    float a0 = A01.x, a1 = A01.y, a2 = A23.x, a3 = A23.y;
    float a4 = A45.x, a5 = A45.y, a6 = A67.x, a7 = A67.y;
    a0 += __shfl_xor(a0, 32, 64); a1 += __shfl_xor(a1, 32, 64);
    a2 += __shfl_xor(a2, 32, 64); a3 += __shfl_xor(a3, 32, 64);
    a4 += __shfl_xor(a4, 32, 64); a5 += __shfl_xor(a5, 32, 64);
    a6 += __shfl_xor(a6, 32, 64); a7 += __shfl_xor(a7, 32, 64);

    if (half == 0) {
        float sc = inv[node];
        int4 p;
        p.x = (int)((unsigned)f2bf(a0 * sc) | ((unsigned)f2bf(a1 * sc) << 16));
        p.y = (int)((unsigned)f2bf(a2 * sc) | ((unsigned)f2bf(a3 * sc) << 16));
        p.z = (int)((unsigned)f2bf(a4 * sc) | ((unsigned)f2bf(a5 * sc) << 16));
        p.w = (int)((unsigned)f2bf(a6 * sc) | ((unsigned)f2bf(a7 * sc) << 16));
        *reinterpret_cast<int4*>(agg + (size_t)node * HIDC + (size_t)l * 8) = p;
    }
}

// ---------- MFMA bf16 SAGE GEMM, m97-style 64-row tile, templated K-depth ----------
template <int KD, bool TWOPASS>
__global__ __launch_bounds__(256) void sage_gemm_mfma(
    const unsigned short* __restrict__ A0, const unsigned short* __restrict__ A1,
    const unsigned short* __restrict__ B0T, const unsigned short* __restrict__ B1T,
    const float* __restrict__ bias, unsigned short* __restrict__ out,
    unsigned char* __restrict__ outq, int M) {
    __shared__ unsigned short sA[64 * 64];   // 8KB
    __shared__ unsigned short sB[256 * 64];  // 32KB
    const int rowbase = blockIdx.x * 64;
    const int tid = threadIdx.x;
    const int lane = tid & 63;
    const int w = tid >> 6;
    const int fr = lane & 15;
    const int kq8 = (lane >> 4) << 3;

    const int srow = lane >> 3;
    const int schunk = (lane & 7) ^ srow;

    f32x4 acc[4][4] = {};

#pragma unroll
    for (int pass = 0; pass < (TWOPASS ? 2 : 1); ++pass) {
        const unsigned short* __restrict__ A = (TWOPASS && pass) ? A1 : A0;
        const unsigned short* __restrict__ BT = (TWOPASS && pass) ? B1T : B0T;
#pragma unroll
        for (int ks = 0; ks < KD / 64; ++ks) {
            const int kb = ks * 64;
            __syncthreads();
#pragma unroll
            for (int c = 0; c < 2; ++c) {
                int ar = w * 16 + c * 8 + srow;
                const unsigned short* g = A + (size_t)(rowbase + ar) * KD + kb + (schunk << 3);
                __builtin_amdgcn_global_load_lds(
                    (const __attribute__((address_space(1))) void*)g,
                    (__attribute__((address_space(3))) void*)(sA + (w * 16 + c * 8) * 64),
                    16, 0, 0);
            }
#pragma unroll
            for (int c = 0; c < 8; ++c) {
                int br = w * 64 + c * 8 + srow;
                const unsigned short* g = BT + (size_t)br * KD + kb + (schunk << 3);
                __builtin_amdgcn_global_load_lds(
                    (const __attribute__((address_space(1))) void*)g,
                    (__attribute__((address_space(3))) void*)(sB + (w * 64 + c * 8) * 64),
                    16, 0, 0);
            }
            __syncthreads();
#pragma unroll
            for (int kg = 0; kg < 2; ++kg) {
                bf16x8 af[4], bfr[4];
#pragma unroll
                for (int t = 0; t < 4; ++t) {
                    int ra = t * 16 + fr;
                    int ba = ra * 128 + ((kg * 64 + kq8 * 2) ^ ((ra & 7) << 4));
                    af[t] = *reinterpret_cast<const bf16x8*>(
                        reinterpret_cast<const char*>(sA) + ba);
                    int rb = w * 64 + t * 16 + fr;
                    int bb2 = rb * 128 + ((kg * 64 + kq8 * 2) ^ ((rb & 7) << 4));
                    bfr[t] = *reinterpret_cast<const bf16x8*>(
                        reinterpret_cast<const char*>(sB) + bb2);
                }
#pragma unroll
                for (int i = 0; i < 4; ++i)
#pragma unroll
                    for (int j = 0; j < 4; ++j)
                        acc[i][j] = __builtin_amdgcn_mfma_f32_16x16x32_bf16(
                            af[i], bfr[j], acc[i][j], 0, 0, 0);
            }
        }
    }

    const int crow0 = (lane >> 4) << 2;
    float bb[4];
#pragma unroll
    for (int j = 0; j < 4; ++j) bb[j] = bias[w * 64 + j * 16 + fr];
#pragma unroll
    for (int i = 0; i < 4; ++i) {
#pragma unroll
        for (int r = 0; r < 4; ++r) {
            int row = rowbase + i * 16 + crow0 + r;
            if (row >= M) continue;
            float v[4];
#pragma unroll
            for (int j = 0; j < 4; ++j) {
                v[j] = fmaxf(acc[i][j][r] + bb[j], 0.0f);
                out[(size_t)row * HIDC + w * 64 + j * 16 + fr] = f2bf(v[j]);
            }
            if (outq)
                *reinterpret_cast<unsigned*>(outq + (size_t)row * 256 + w * 64 + fr * 4) =
                    pack4_fp8(v[0], v[1], v[2], v[3]);
        }
    }
}

// ---------- segment-max pool ----------
__global__ void pool_max(const unsigned short* __restrict__ h, const int* __restrict__ gstart,
                         const int* __restrict__ gend, float* __restrict__ xc, int col_off) {
    int g = blockIdx.x;
    int chunk = blockIdx.y;
    int c = threadIdx.x;
    int s = gstart[g], e = gend[g];
    int len = e - s;
    if (len <= 0) return;
    int per = (len + 7) >> 3;
    int cs = s + chunk * per;
    int ce = min(cs + per, e);
    if (cs >= ce) return;
    float m = 0.0f;
    for (int i = cs; i < ce; ++i) m = fmaxf(m, bf2f(h[(size_t)i * HIDC + c]));
    atomicMax(reinterpret_cast<int*>(&xc[(size_t)g * (3 * HIDC) + col_off + c]),
              __float_as_int(m));
}

// ---------- head MLPs ----------
__global__ void mlp1(const float* __restrict__ xc, const float* __restrict__ W,
                     const float* __restrict__ b, float* __restrict__ hmid) {
    __shared__ float row[3 * HIDC];
    int g = blockIdx.x;
    for (int i = threadIdx.x; i < 3 * HIDC; i += 256) row[i] = xc[(size_t)g * (3 * HIDC) + i];
    __syncthreads();
    float acc = b[threadIdx.x];
    for (int k = 0; k < 3 * HIDC; ++k) acc += row[k] * W[(size_t)k * HIDC + threadIdx.x];
    hmid[(size_t)g * HIDC + threadIdx.x] = fmaxf(acc, 0.0f);
}

__global__ void mlp2(const float* __restrict__ hmid, const float* __restrict__ W,
                     const float* __restrict__ b, float* __restrict__ out) {
    __shared__ float row[HIDC];
    int g = blockIdx.x;
    for (int i = threadIdx.x; i < HIDC; i += 128) row[i] = hmid[(size_t)g * HIDC + i];
    __syncthreads();
    float acc = b[threadIdx.x];
    for (int k = 0; k < HIDC; ++k) acc += row[k] * W[(size_t)k * OUT_DIMC + threadIdx.x];
    out[(size_t)g * OUT_DIMC + threadIdx.x] = acc;
}

static inline char* align_up(char* p, size_t a) {
    return (char*)(((uintptr_t)p + a - 1) & ~(uintptr_t)(a - 1));
}

extern "C" void kernel_launch(void* const* d_in, const int* in_sizes, int n_in,
                              void* d_out, int out_size, void* d_ws, size_t ws_size,
                              hipStream_t stream) {
    const float* x = (const float*)d_in[0];
    const int* edge_index = (const int*)d_in[1];
    const int* batch = (const int*)d_in[2];
    const float* W1l = (const float*)d_in[3];
    const float* W1r = (const float*)d_in[4];
    const float* b1 = (const float*)d_in[5];
    const float* W2l = (const float*)d_in[6];
    const float* W2r = (const float*)d_in[7];
    const float* b2 = (const float*)d_in[8];
    const float* W3l = (const float*)d_in[9];
    const float* W3r = (const float*)d_in[10];
    const float* b3 = (const float*)d_in[11];
    const float* Wlin1 = (const float*)d_in[12];
    const float* blin1 = (const float*)d_in[13];
    const float* Wlin2 = (const float*)d_in[14];
    const float* blin2 = (const float*)d_in[15];
    float* out = (float*)d_out;

    const int N = N_NODESC, E = N_EDGESC;
    const int* src = edge_index;
    const int* dst = edge_index + E;

    // ---- workspace carve-up ----
    char* w0 = (char*)d_ws;
    char* w = w0;
    float* invc = (float*)w;   w = align_up(w + (size_t)N * 4, 256);
    int* row_ofs = (int*)w;    w = align_up(w + (size_t)(N + 1) * 4, 256);
    int* bbase = (int*)w;      w = align_up(w + (size_t)(NBKT + 1) * 4, 256);
    int* colsum = (int*)w;     w = align_up(w + (size_t)NBKT * 4, 256);
    int* csr = (int*)w;        w = align_up(w + (size_t)E * 4, 256);
    int* gstart = (int*)w;     w = align_up(w + (size_t)N_GRAPHSC * 4, 256);
    int* gend = (int*)w;       w = align_up(w + (size_t)N_GRAPHSC * 4, 256);
    float* xc = (float*)w;     w = align_up(w + (size_t)N_GRAPHSC * 3 * HIDC * 4, 256);
    float* hmid = (float*)w;   w = align_up(w + (size_t)N_GRAPHSC * HIDC * 4, 256);
    unsigned short* W2lT = (unsigned short*)w; w = align_up(w + (size_t)HIDC * HIDC * 2, 256);
    unsigned short* W2rT = (unsigned short*)w; w = align_up(w + (size_t)HIDC * HIDC * 2, 256);
    unsigned short* W3lT = (unsigned short*)w; w = align_up(w + (size_t)HIDC * HIDC * 2, 256);
    unsigned short* W3rT = (unsigned short*)w; w = align_up(w + (size_t)HIDC * HIDC * 2, 256);
    unsigned short* BT1 = (unsigned short*)w;  w = align_up(w + (size_t)HIDC * 64 * 2, 256);
    char* aggU = w;            w = align_up(w + (size_t)N * HIDC * 2, 256);
    unsigned short* h1 = (unsigned short*)w;  w = align_up(w + (size_t)N * HIDC * 2, 256);
    unsigned short* h2 = (unsigned short*)w;  w = align_up(w + (size_t)N * HIDC * 2 + 65536, 256);
    unsigned char* hq = (unsigned char*)w;    w = align_up(w + (size_t)N * 256, 256);
    size_t required = (size_t)(w - w0);
    if (ws_size < required) return;

    unsigned short* aggH = (unsigned short*)aggU;
    // transient aliases:
    int* hist = (int*)aggU;                        // dead after bucket_scatter
    unsigned short* Acat = (unsigned short*)aggU;  // [N][64] bf16; after hist dead
    int2* pairs = (int2*)h2;                       // dead after bucket_csrfill

    const int nbN = (N + 255) / 256;
    const dim3 pgrid(N_GRAPHSC, 8);

    // weight transposes (single kernel)
    wtrans_all<<<dim3(16, 16, 5), 256, 0, stream>>>(W1l, W1r, W2l, W2r, W3l, W3r, W2lT, W2rT,
                                                    W3lT, W3rT, BT1);

    // ---- bucketed CSR build ----
    hist_kernel<<<NCH, 256, 0, stream>>>(dst, hist);
    col_scan<<<NBKT, 512, 0, stream>>>(hist, colsum);
    bucket_base_scan<<<1, 512, 0, stream>>>(colsum, bbase);
    bucket_scatter<<<NCH, 256, 0, stream>>>(src, dst, hist, bbase, pairs);
    bucket_deg<<<NBKT, 256, 0, stream>>>(pairs, bbase, row_ofs, invc);
    bucket_csrfill<<<NBKT, 256, 0, stream>>>(pairs, bbase, row_ofs, csr);

    // graph ranges (no pre-fill needed: every graph present gets written) + zero xc
    ranges_bounds<<<nbN, 256, 0, stream>>>(batch, gstart, gend, N);
    fill_u32<<<(N_GRAPHSC * 3 * HIDC + 255) / 256, 256, 0, stream>>>((unsigned*)xc, 0u,
                                                                     N_GRAPHSC * 3 * HIDC);

    // ---- layer 1 (MFMA KD=64 on [agg25|x]) -> h1 bf16 + hq fp8 (perm layout) ----
    gather25<<<(N * 64 + 255) / 256, 256, 0, stream>>>(x, row_ofs, csr, invc, Acat);
    sage_gemm_mfma<64, false><<<NRB64, 256, 0, stream>>>(Acat, nullptr, BT1, nullptr, b1, h1,
                                                         hq, N);
    pool_max<<<pgrid, 256, 0, stream>>>(h1, gstart, gend, xc, 0);

    // ---- layer 2: fp8 gather (perm) + MFMA with perm'd W2lT -> h2 + hq fp8 (perm) ----
    gather256_fp8<<<(N * 64 + 255) / 256, 256, 0, stream>>>(hq, row_ofs, csr, invc, aggH);
    sage_gemm_mfma<256, true><<<NRB64, 256, 0, stream>>>(aggH, h1, W2lT, W2rT, b2, h2, hq, N);
    pool_max<<<pgrid, 256, 0, stream>>>(h2, gstart, gend, xc, HIDC);

    // ---- layer 3: fp8 gather (perm) + MFMA with perm'd W3lT -> h1 ----
    gather256_fp8<<<(N * 64 + 255) / 256, 256, 0, stream>>>(hq, row_ofs, csr, invc, aggH);
    sage_gemm_mfma<256, true><<<NRB64, 256, 0, stream>>>(aggH, h2, W3lT, W3rT, b3, h1, nullptr,
                                                         N);
    pool_max<<<pgrid, 256, 0, stream>>>(h1, gstart, gend, xc, 2 * HIDC);

    // ---- head ----
    mlp1<<<N_GRAPHSC, 256, 0, stream>>>(xc, Wlin1, blin1, hmid);
    mlp2<<<N_GRAPHSC, 128, 0, stream>>>(hmid, Wlin2, blin2, out);
}

// Round 19
// 432.371 us; speedup vs baseline: 1.5510x; 1.0264x over previous
//
#include <hip/hip_runtime.h>
#include <hip/hip_bf16.h>

#define N_NODESC 100000
#define N_EDGESC 1600000
#define N_GRAPHSC 200
#define IN_DIMC 25
#define HIDC 256
#define OUT_DIMC 128
#define NRB64 ((N_NODESC + 63) / 64)   // 1563 row-blocks
#define NBKT ((N_NODESC + 255) / 256)  // 391 dst-buckets (256 nodes each)
#define NCH 400                        // edge chunks
#define CHSZ (N_EDGESC / NCH)          // 4000 edges/chunk (exact)

typedef __attribute__((ext_vector_type(8))) short bf16x8;
typedef __attribute__((ext_vector_type(4))) float f32x4;
typedef __attribute__((ext_vector_type(2))) float f32x2;

#if defined(__has_builtin)
#if __has_builtin(__builtin_amdgcn_cvt_pk_f32_fp8) && __has_builtin(__builtin_amdgcn_cvt_pk_fp8_f32)
#define HAVE_FP8_CVT 1
#endif
#endif

// ---------- bf16 helpers ----------
__device__ inline float bf2f(unsigned short u) {
    union { float f; unsigned u32; } c;
    c.u32 = ((unsigned)u) << 16;
    return c.f;
}
__device__ inline unsigned short f2bf(float f) {
    union { float f; unsigned u; } c;
    c.f = f;
    unsigned r = (c.u + 0x7FFFu + ((c.u >> 16) & 1u)) >> 16;  // RNE
    return (unsigned short)r;
}
__device__ inline float u2f(unsigned u) {
    union { unsigned u; float f; } c;
    c.u = u;
    return c.f;
}

// ---------- fp8 e4m3 helpers (values >= 0 only) ----------
__device__ inline unsigned fp8enc_sw(float v) {
    v = fminf(v, 448.0f);
    union { float f; unsigned u; } c;
    c.f = v;
    unsigned bits = c.u + 0x7FFFFu + ((c.u >> 20) & 1u);
    int e8 = (int)((bits >> 23) & 0xFF) - 120;
    if (e8 <= 0) return (unsigned)(v * 512.0f + 0.5f);
    return ((unsigned)e8 << 3) | ((bits >> 20) & 7u);
}
__device__ inline float fp8dec_sw(unsigned u) {
    unsigned e = (u >> 3) & 15u, m = u & 7u;
    float fn = u2f(((e + 120u) << 23) | (m << 20));
    float fd = (float)m * 0.001953125f;
    return e ? fn : fd;
}
__device__ inline unsigned pack4_fp8(float v0, float v1, float v2, float v3) {
#ifdef HAVE_FP8_CVT
    int r = __builtin_amdgcn_cvt_pk_fp8_f32(v0, v1, 0, false);
    r = __builtin_amdgcn_cvt_pk_fp8_f32(v2, v3, r, true);
    return (unsigned)r;
#else
    return fp8enc_sw(v0) | (fp8enc_sw(v1) << 8) | (fp8enc_sw(v2) << 16) | (fp8enc_sw(v3) << 24);
#endif
}

// ---------- utility fills ----------
__global__ void fill_u32(unsigned* __restrict__ p, unsigned v, int n) {
    int i = blockIdx.x * 256 + threadIdx.x;
    if (i < n) p[i] = v;
}

// ---------- x -> bf16 table [N][32] (64B rows, line-aligned) ----------
__global__ void xtab_kernel(const float* __restrict__ x, unsigned short* __restrict__ xt) {
    int i = blockIdx.x * 256 + threadIdx.x;
    int node = i >> 5, c = i & 31;
    if (node >= N_NODESC) return;
    xt[i] = (c < IN_DIMC) ? f2bf(x[(size_t)node * IN_DIMC + c]) : (unsigned short)0;
}

// ---------- bucketed CSR build ----------
__global__ __launch_bounds__(256) void hist_kernel(const int* __restrict__ dst,
                                                   int* __restrict__ hist) {
    __shared__ int h[NBKT];
    const int c = blockIdx.x, tid = threadIdx.x;
    for (int t = tid; t < NBKT; t += 256) h[t] = 0;
    __syncthreads();
    const int e0 = c * CHSZ;
    for (int e = e0 + tid; e < e0 + CHSZ; e += 256) atomicAdd(&h[dst[e] >> 8], 1);
    __syncthreads();
    for (int t = tid; t < NBKT; t += 256) hist[c * NBKT + t] = h[t];
}

__global__ __launch_bounds__(512) void col_scan(int* __restrict__ hist,
                                                int* __restrict__ colsum) {
    __shared__ int sm[512];
    const int b = blockIdx.x, t = threadIdx.x;
    int v = (t < NCH) ? hist[t * NBKT + b] : 0;
    sm[t] = v;
    __syncthreads();
    for (int off = 1; off < 512; off <<= 1) {
        int u = (t >= off) ? sm[t - off] : 0;
        __syncthreads();
        sm[t] += u;
        __syncthreads();
    }
    if (t < NCH) hist[t * NBKT + b] = sm[t] - v;
    if (t == 511) colsum[b] = sm[511];
}

__global__ __launch_bounds__(512) void bucket_base_scan(const int* __restrict__ colsum,
                                                        int* __restrict__ base) {
    __shared__ int sm[512];
    const int t = threadIdx.x;
    int v = (t < NBKT) ? colsum[t] : 0;
    sm[t] = v;
    __syncthreads();
    for (int off = 1; off < 512; off <<= 1) {
        int u = (t >= off) ? sm[t - off] : 0;
        __syncthreads();
        sm[t] += u;
        __syncthreads();
    }
    if (t <= NBKT) base[t] = sm[t] - v;
}

__global__ __launch_bounds__(256) void bucket_scatter(const int* __restrict__ src,
                                                      const int* __restrict__ dst,
                                                      const int* __restrict__ chpre,
                                                      const int* __restrict__ base,
                                                      int2* __restrict__ pairs) {
    __shared__ int cur[NBKT];
    __shared__ int o2[NBKT];
    const int c = blockIdx.x, tid = threadIdx.x;
    for (int t = tid; t < NBKT; t += 256) {
        cur[t] = 0;
        o2[t] = base[t] + chpre[c * NBKT + t];
    }
    __syncthreads();
    const int e0 = c * CHSZ;
    for (int e = e0 + tid; e < e0 + CHSZ; e += 256) {
        int s = src[e], d = dst[e];
        int b = d >> 8;
        int p = atomicAdd(&cur[b], 1);
        pairs[o2[b] + p] = make_int2(s, d);
    }
}

// degrees + row_ofs + inv (buckets are contiguous node ranges)
__global__ __launch_bounds__(256) void bucket_deg(const int2* __restrict__ pairs,
                                                  const int* __restrict__ base,
                                                  int* __restrict__ row_ofs,
                                                  float* __restrict__ invc) {
    __shared__ int h[256];
    __shared__ int sc[256];
    const int b = blockIdx.x, tid = threadIdx.x;
    h[tid] = 0;
    __syncthreads();
    for (int i = base[b] + tid; i < base[b + 1]; i += 256)
        atomicAdd(&h[pairs[i].y & 255], 1);
    __syncthreads();
    int v = h[tid];
    sc[tid] = v;
    __syncthreads();
    for (int off = 1; off < 256; off <<= 1) {
        int t = (tid >= off) ? sc[tid - off] : 0;
        __syncthreads();
        sc[tid] += t;
        __syncthreads();
    }
    int node = b * 256 + tid;
    if (node < N_NODESC) {
        row_ofs[node] = base[b] + sc[tid] - v;
        invc[node] = 1.0f / (float)max(v, 1);
    }
    if (node == N_NODESC) row_ofs[N_NODESC] = N_EDGESC;
}

__global__ __launch_bounds__(256) void bucket_csrfill(const int2* __restrict__ pairs,
                                                      const int* __restrict__ base,
                                                      const int* __restrict__ row_ofs,
                                                      int* __restrict__ csr) {
    __shared__ int cur[256];
    __shared__ int ob[256];
    const int b = blockIdx.x, tid = threadIdx.x;
    int node = b * 256 + tid;
    ob[tid] = (node < N_NODESC) ? row_ofs[node] : 0;
    cur[tid] = 0;
    __syncthreads();
    for (int i = base[b] + tid; i < base[b + 1]; i += 256) {
        int2 pr = pairs[i];
        int loc = pr.y & 255;
        int p = atomicAdd(&cur[loc], 1);
        csr[ob[loc] + p] = pr.x;
    }
}

// ---------- graph ranges (batch sorted) ----------
__global__ void ranges_bounds(const int* __restrict__ batch, int* __restrict__ gstart,
                              int* __restrict__ gend, int n) {
    int i = blockIdx.x * 256 + threadIdx.x;
    if (i >= n) return;
    int g = batch[i];
    if (i == 0 || batch[i - 1] != g) gstart[g] = i;
    if (i == n - 1 || batch[i + 1] != g) gend[g] = i + 1;
}

// ---------- all weight transposes in one kernel ----------
// z=0: W2lT (perm), z=1: W2rT, z=2: W3lT (perm), z=3: W3rT, z=4: BT1 [256 n][64 k]
__global__ void wtrans_all(const float* __restrict__ W1l, const float* __restrict__ W1r,
                           const float* __restrict__ W2l, const float* __restrict__ W2r,
                           const float* __restrict__ W3l, const float* __restrict__ W3r,
                           unsigned short* __restrict__ W2lT, unsigned short* __restrict__ W2rT,
                           unsigned short* __restrict__ W3lT, unsigned short* __restrict__ W3rT,
                           unsigned short* __restrict__ BT1) {
    int z = blockIdx.z;
    int tx = threadIdx.x & 15, ty = threadIdx.x >> 4;
    int n = blockIdx.y * 16 + ty;
    int p = blockIdx.x * 16 + tx;
    if (z == 4) {
        if (blockIdx.x >= 4) return;  // k < 64
        float v = 0.0f;
        if (p < IN_DIMC) v = W1l[(size_t)p * HIDC + n];
        else if (p >= 32 && p < 32 + IN_DIMC) v = W1r[(size_t)(p - 32) * HIDC + n];
        BT1[(size_t)n * 64 + p] = f2bf(v);
        return;
    }
    const float* W = (z == 0) ? W2l : (z == 1) ? W2r : (z == 2) ? W3l : W3r;
    unsigned short* WT = (z == 0) ? W2lT : (z == 1) ? W2rT : (z == 2) ? W3lT : W3rT;
    int c = (z == 0 || z == 2) ? ((p & 0xC0) + ((p & 3) << 4) + ((p >> 2) & 15)) : p;
    WT[(size_t)n * HIDC + p] = f2bf(W[(size_t)c * HIDC + n]);
}

// ---------- layer-1 mean gather over bf16 x-table + x copy (fused) ----------
__global__ void gather25(const unsigned short* __restrict__ xt, const int* __restrict__ ofs,
                         const int* __restrict__ csr, const float* __restrict__ inv,
                         unsigned short* __restrict__ Acat) {
    long long gtid = (long long)blockIdx.x * 256 + threadIdx.x;
    int node = (int)(gtid >> 6);
    if (node >= N_NODESC) return;
    const int lane = threadIdx.x & 63;
    const int half = lane >> 5;
    const int c = lane & 31;
    const int s = ofs[node], e = ofs[node + 1];
    float acc = 0.0f;
    int j = s + half;
    for (; j + 6 < e; j += 8) {
        int sn0 = csr[j], sn1 = csr[j + 2], sn2 = csr[j + 4], sn3 = csr[j + 6];
        float v0 = bf2f(xt[(size_t)sn0 * 32 + c]);
        float v1 = bf2f(xt[(size_t)sn1 * 32 + c]);
        float v2 = bf2f(xt[(size_t)sn2 * 32 + c]);
        float v3 = bf2f(xt[(size_t)sn3 * 32 + c]);
        acc += (v0 + v1) + (v2 + v3);
    }
    for (; j < e; j += 2) {
        int sn = csr[j];
        acc += bf2f(xt[(size_t)sn * 32 + c]);
    }
    acc += __shfl_xor(acc, 32, 64);
    if (half == 0) {
        Acat[(size_t)node * 64 + c] = f2bf(acc * inv[node]);
    } else {
        Acat[(size_t)node * 64 + 32 + c] = xt[(size_t)node * 32 + c];
    }
}

// ---------- hidden mean gather over fp8 rows (packed f32x2 accumulation) ----------
__global__ void gather256_fp8(const unsigned char* __restrict__ hq, const int* __restrict__ ofs,
                              const int* __restrict__ csr, const float* __restrict__ inv,
                              unsigned short* __restrict__ agg) {
    long long gtid = (long long)blockIdx.x * 256 + threadIdx.x;
    int node = (int)(gtid >> 6);
    if (node >= N_NODESC) return;
    const int lane = threadIdx.x & 63;
    const int half = lane >> 5;
    const int l = lane & 31;
    const int s = ofs[node], e = ofs[node + 1];

    f32x2 A01 = {0.0f, 0.0f}, A23 = {0.0f, 0.0f}, A45 = {0.0f, 0.0f}, A67 = {0.0f, 0.0f};
    const size_t boff = (size_t)l * 8;

#ifdef HAVE_FP8_CVT
#define DEC8(q)                                                          \
    {                                                                    \
        A01 += __builtin_amdgcn_cvt_pk_f32_fp8((int)(q).x, false);       \
        A23 += __builtin_amdgcn_cvt_pk_f32_fp8((int)(q).x, true);        \
        A45 += __builtin_amdgcn_cvt_pk_f32_fp8((int)(q).y, false);       \
        A67 += __builtin_amdgcn_cvt_pk_f32_fp8((int)(q).y, true);        \
    }
#else
#define DEC8(q)                                                          \
    {                                                                    \
        unsigned lo = (unsigned)(q).x, hi = (unsigned)(q).y;             \
        A01.x += fp8dec_sw(lo & 255); A01.y += fp8dec_sw((lo >> 8) & 255);   \
        A23.x += fp8dec_sw((lo >> 16) & 255); A23.y += fp8dec_sw(lo >> 24); \
        A45.x += fp8dec_sw(hi & 255); A45.y += fp8dec_sw((hi >> 8) & 255);   \
        A67.x += fp8dec_sw((hi >> 16) & 255); A67.y += fp8dec_sw(hi >> 24); \
    }
#endif

    int j = s + half;
    for (; j + 6 < e; j += 8) {
        int sn0 = csr[j];
        int sn1 = csr[j + 2];
        int sn2 = csr[j + 4];
        int sn3 = csr[j + 6];
        uint2 q0 = *reinterpret_cast<const uint2*>(hq + (size_t)sn0 * 256 + boff);
        uint2 q1 = *reinterpret_cast<const uint2*>(hq + (size_t)sn1 * 256 + boff);
        uint2 q2 = *reinterpret_cast<const uint2*>(hq + (size_t)sn2 * 256 + boff);
        uint2 q3 = *reinterpret_cast<const uint2*>(hq + (size_t)sn3 * 256 + boff);
        DEC8(q0) DEC8(q1) DEC8(q2) DEC8(q3)
    }
    for (; j < e; j += 2) {
        int sn0 = csr[j];
        uint2 q0 = *reinterpret_cast<const uint2*>(hq + (size_t)sn0 * 256 + boff);
        DEC8(q0)
    }
#undef DEC8

    float a0 = A01.x, a1 = A01.y, a2 = A23.x, a3 = A23.y;
    float a4 = A45.x, a5 = A45.y, a6 = A67.x, a7 = A67.y;
    a0 += __shfl_xor(a0, 32, 64); a1 += __shfl_xor(a1, 32, 64);
    a2 += __shfl_xor(a2, 32, 64); a3 += __shfl_xor(a3, 32, 64);
    a4 += __shfl_xor(a4, 32, 64); a5 += __shfl_xor(a5, 32, 64);
    a6 += __shfl_xor(a6, 32, 64); a7 += __shfl_xor(a7, 32, 64);

    if (half == 0) {
        float sc = inv[node];
        int4 p;
        p.x = (int)((unsigned)f2bf(a0 * sc) | ((unsigned)f2bf(a1 * sc) << 16));
        p.y = (int)((unsigned)f2bf(a2 * sc) | ((unsigned)f2bf(a3 * sc) << 16));
        p.z = (int)((unsigned)f2bf(a4 * sc) | ((unsigned)f2bf(a5 * sc) << 16));
        p.w = (int)((unsigned)f2bf(a6 * sc) | ((unsigned)f2bf(a7 * sc) << 16));
        *reinterpret_cast<int4*>(agg + (size_t)node * HIDC + (size_t)l * 8) = p;
    }
}

// ---------- MFMA bf16 SAGE GEMM, m97-style 64-row tile, templated K-depth ----------
template <int KD, bool TWOPASS>
__global__ __launch_bounds__(256) void sage_gemm_mfma(
    const unsigned short* __restrict__ A0, const unsigned short* __restrict__ A1,
    const unsigned short* __restrict__ B0T, const unsigned short* __restrict__ B1T,
    const float* __restrict__ bias, unsigned short* __restrict__ out,
    unsigned char* __restrict__ outq, int M) {
    __shared__ unsigned short sA[64 * 64];   // 8KB
    __shared__ unsigned short sB[256 * 64];  // 32KB
    const int rowbase = blockIdx.x * 64;
    const int tid = threadIdx.x;
    const int lane = tid & 63;
    const int w = tid >> 6;
    const int fr = lane & 15;
    const int kq8 = (lane >> 4) << 3;

    const int srow = lane >> 3;
    const int schunk = (lane & 7) ^ srow;

    f32x4 acc[4][4] = {};

#pragma unroll
    for (int pass = 0; pass < (TWOPASS ? 2 : 1); ++pass) {
        const unsigned short* __restrict__ A = (TWOPASS && pass) ? A1 : A0;
        const unsigned short* __restrict__ BT = (TWOPASS && pass) ? B1T : B0T;
#pragma unroll
        for (int ks = 0; ks < KD / 64; ++ks) {
            const int kb = ks * 64;
            __syncthreads();
#pragma unroll
            for (int c = 0; c < 2; ++c) {
                int ar = w * 16 + c * 8 + srow;
                const unsigned short* g = A + (size_t)(rowbase + ar) * KD + kb + (schunk << 3);
                __builtin_amdgcn_global_load_lds(
                    (const __attribute__((address_space(1))) void*)g,
                    (__attribute__((address_space(3))) void*)(sA + (w * 16 + c * 8) * 64),
                    16, 0, 0);
            }
#pragma unroll
            for (int c = 0; c < 8; ++c) {
                int br = w * 64 + c * 8 + srow;
                const unsigned short* g = BT + (size_t)br * KD + kb + (schunk << 3);
                __builtin_amdgcn_global_load_lds(
                    (const __attribute__((address_space(1))) void*)g,
                    (__attribute__((address_space(3))) void*)(sB + (w * 64 + c * 8) * 64),
                    16, 0, 0);
            }
            __syncthreads();
#pragma unroll
            for (int kg = 0; kg < 2; ++kg) {
                bf16x8 af[4], bfr[4];
#pragma unroll
                for (int t = 0; t < 4; ++t) {
                    int ra = t * 16 + fr;
                    int ba = ra * 128 + ((kg * 64 + kq8 * 2) ^ ((ra & 7) << 4));
                    af[t] = *reinterpret_cast<const bf16x8*>(
                        reinterpret_cast<const char*>(sA) + ba);
                    int rb = w * 64 + t * 16 + fr;
                    int bb2 = rb * 128 + ((kg * 64 + kq8 * 2) ^ ((rb & 7) << 4));
                    bfr[t] = *reinterpret_cast<const bf16x8*>(
                        reinterpret_cast<const char*>(sB) + bb2);
                }
#pragma unroll
                for (int i = 0; i < 4; ++i)
#pragma unroll
                    for (int j = 0; j < 4; ++j)
                        acc[i][j] = __builtin_amdgcn_mfma_f32_16x16x32_bf16(
                            af[i], bfr[j], acc[i][j], 0, 0, 0);
            }
        }
    }

    const int crow0 = (lane >> 4) << 2;
    float bb[4];
#pragma unroll
    for (int j = 0; j < 4; ++j) bb[j] = bias[w * 64 + j * 16 + fr];
#pragma unroll
    for (int i = 0; i < 4; ++i) {
#pragma unroll
        for (int r = 0; r < 4; ++r) {
            int row = rowbase + i * 16 + crow0 + r;
            if (row >= M) continue;
            float v[4];
#pragma unroll
            for (int j = 0; j < 4; ++j) {
                v[j] = fmaxf(acc[i][j][r] + bb[j], 0.0f);
                out[(size_t)row * HIDC + w * 64 + j * 16 + fr] = f2bf(v[j]);
            }
            if (outq)
                *reinterpret_cast<unsigned*>(outq + (size_t)row * 256 + w * 64 + fr * 4) =
                    pack4_fp8(v[0], v[1], v[2], v[3]);
        }
    }
}

// ---------- segment-max pool ----------
__global__ void pool_max(const unsigned short* __restrict__ h, const int* __restrict__ gstart,
                         const int* __restrict__ gend, float* __restrict__ xc, int col_off) {
    int g = blockIdx.x;
    int chunk = blockIdx.y;
    int c = threadIdx.x;
    int s = gstart[g], e = gend[g];
    int len = e - s;
    if (len <= 0) return;
    int per = (len + 7) >> 3;
    int cs = s + chunk * per;
    int ce = min(cs + per, e);
    if (cs >= ce) return;
    float m = 0.0f;
    for (int i = cs; i < ce; ++i) m = fmaxf(m, bf2f(h[(size_t)i * HIDC + c]));
    atomicMax(reinterpret_cast<int*>(&xc[(size_t)g * (3 * HIDC) + col_off + c]),
              __float_as_int(m));
}

// ---------- head MLPs ----------
__global__ void mlp1(const float* __restrict__ xc, const float* __restrict__ W,
                     const float* __restrict__ b, float* __restrict__ hmid) {
    __shared__ float row[3 * HIDC];
    int g = blockIdx.x;
    for (int i = threadIdx.x; i < 3 * HIDC; i += 256) row[i] = xc[(size_t)g * (3 * HIDC) + i];
    __syncthreads();
    float acc = b[threadIdx.x];
    for (int k = 0; k < 3 * HIDC; ++k) acc += row[k] * W[(size_t)k * HIDC + threadIdx.x];
    hmid[(size_t)g * HIDC + threadIdx.x] = fmaxf(acc, 0.0f);
}

__global__ void mlp2(const float* __restrict__ hmid, const float* __restrict__ W,
                     const float* __restrict__ b, float* __restrict__ out) {
    __shared__ float row[HIDC];
    int g = blockIdx.x;
    for (int i = threadIdx.x; i < HIDC; i += 128) row[i] = hmid[(size_t)g * HIDC + i];
    __syncthreads();
    float acc = b[threadIdx.x];
    for (int k = 0; k < HIDC; ++k) acc += row[k] * W[(size_t)k * OUT_DIMC + threadIdx.x];
    out[(size_t)g * OUT_DIMC + threadIdx.x] = acc;
}

static inline char* align_up(char* p, size_t a) {
    return (char*)(((uintptr_t)p + a - 1) & ~(uintptr_t)(a - 1));
}

extern "C" void kernel_launch(void* const* d_in, const int* in_sizes, int n_in,
                              void* d_out, int out_size, void* d_ws, size_t ws_size,
                              hipStream_t stream) {
    const float* x = (const float*)d_in[0];
    const int* edge_index = (const int*)d_in[1];
    const int* batch = (const int*)d_in[2];
    const float* W1l = (const float*)d_in[3];
    const float* W1r = (const float*)d_in[4];
    const float* b1 = (const float*)d_in[5];
    const float* W2l = (const float*)d_in[6];
    const float* W2r = (const float*)d_in[7];
    const float* b2 = (const float*)d_in[8];
    const float* W3l = (const float*)d_in[9];
    const float* W3r = (const float*)d_in[10];
    const float* b3 = (const float*)d_in[11];
    const float* Wlin1 = (const float*)d_in[12];
    const float* blin1 = (const float*)d_in[13];
    const float* Wlin2 = (const float*)d_in[14];
    const float* blin2 = (const float*)d_in[15];
    float* out = (float*)d_out;

    const int N = N_NODESC, E = N_EDGESC;
    const int* src = edge_index;
    const int* dst = edge_index + E;

    // ---- workspace carve-up ----
    char* w0 = (char*)d_ws;
    char* w = w0;
    float* invc = (float*)w;   w = align_up(w + (size_t)N * 4, 256);
    int* row_ofs = (int*)w;    w = align_up(w + (size_t)(N + 1) * 4, 256);
    int* bbase = (int*)w;      w = align_up(w + (size_t)(NBKT + 1) * 4, 256);
    int* colsum = (int*)w;     w = align_up(w + (size_t)NBKT * 4, 256);
    int* csr = (int*)w;        w = align_up(w + (size_t)E * 4, 256);
    int* gstart = (int*)w;     w = align_up(w + (size_t)N_GRAPHSC * 4, 256);
    int* gend = (int*)w;       w = align_up(w + (size_t)N_GRAPHSC * 4, 256);
    float* xc = (float*)w;     w = align_up(w + (size_t)N_GRAPHSC * 3 * HIDC * 4, 256);
    float* hmid = (float*)w;   w = align_up(w + (size_t)N_GRAPHSC * HIDC * 4, 256);
    unsigned short* W2lT = (unsigned short*)w; w = align_up(w + (size_t)HIDC * HIDC * 2, 256);
    unsigned short* W2rT = (unsigned short*)w; w = align_up(w + (size_t)HIDC * HIDC * 2, 256);
    unsigned short* W3lT = (unsigned short*)w; w = align_up(w + (size_t)HIDC * HIDC * 2, 256);
    unsigned short* W3rT = (unsigned short*)w; w = align_up(w + (size_t)HIDC * HIDC * 2, 256);
    unsigned short* BT1 = (unsigned short*)w;  w = align_up(w + (size_t)HIDC * 64 * 2, 256);
    unsigned short* xt = (unsigned short*)w;   w = align_up(w + (size_t)N * 32 * 2, 256);
    char* aggU = w;            w = align_up(w + (size_t)N * HIDC * 2, 256);
    unsigned short* h1 = (unsigned short*)w;  w = align_up(w + (size_t)N * HIDC * 2, 256);
    unsigned short* h2 = (unsigned short*)w;  w = align_up(w + (size_t)N * HIDC * 2 + 65536, 256);
    unsigned char* hq = (unsigned char*)w;    w = align_up(w + (size_t)N * 256, 256);
    size_t required = (size_t)(w - w0);
    if (ws_size < required) return;

    unsigned short* aggH = (unsigned short*)aggU;
    // transient aliases:
    int* hist = (int*)aggU;                        // dead after bucket_scatter
    unsigned short* Acat = (unsigned short*)aggU;  // [N][64] bf16; after hist dead
    int2* pairs = (int2*)h2;                       // dead after bucket_csrfill

    const int nbN = (N + 255) / 256;
    const dim3 pgrid(N_GRAPHSC, 8);

    // weight transposes (single kernel) + x bf16 table
    wtrans_all<<<dim3(16, 16, 5), 256, 0, stream>>>(W1l, W1r, W2l, W2r, W3l, W3r, W2lT, W2rT,
                                                    W3lT, W3rT, BT1);
    xtab_kernel<<<(N * 32 + 255) / 256, 256, 0, stream>>>(x, xt);

    // ---- bucketed CSR build ----
    hist_kernel<<<NCH, 256, 0, stream>>>(dst, hist);
    col_scan<<<NBKT, 512, 0, stream>>>(hist, colsum);
    bucket_base_scan<<<1, 512, 0, stream>>>(colsum, bbase);
    bucket_scatter<<<NCH, 256, 0, stream>>>(src, dst, hist, bbase, pairs);
    bucket_deg<<<NBKT, 256, 0, stream>>>(pairs, bbase, row_ofs, invc);
    bucket_csrfill<<<NBKT, 256, 0, stream>>>(pairs, bbase, row_ofs, csr);

    // graph ranges + zero xc
    ranges_bounds<<<nbN, 256, 0, stream>>>(batch, gstart, gend, N);
    fill_u32<<<(N_GRAPHSC * 3 * HIDC + 255) / 256, 256, 0, stream>>>((unsigned*)xc, 0u,
                                                                     N_GRAPHSC * 3 * HIDC);

    // ---- layer 1 (MFMA KD=64 on [agg25|x]) -> h1 bf16 + hq fp8 (perm layout) ----
    gather25<<<(N * 64 + 255) / 256, 256, 0, stream>>>(xt, row_ofs, csr, invc, Acat);
    sage_gemm_mfma<64, false><<<NRB64, 256, 0, stream>>>(Acat, nullptr, BT1, nullptr, b1, h1,
                                                         hq, N);
    pool_max<<<pgrid, 256, 0, stream>>>(h1, gstart, gend, xc, 0);

    // ---- layer 2: fp8 gather (perm) + MFMA with perm'd W2lT -> h2 + hq fp8 (perm) ----
    gather256_fp8<<<(N * 64 + 255) / 256, 256, 0, stream>>>(hq, row_ofs, csr, invc, aggH);
    sage_gemm_mfma<256, true><<<NRB64, 256, 0, stream>>>(aggH, h1, W2lT, W2rT, b2, h2, hq, N);
    pool_max<<<pgrid, 256, 0, stream>>>(h2, gstart, gend, xc, HIDC);

    // ---- layer 3: fp8 gather (perm) + MFMA with perm'd W3lT -> h1 ----
    gather256_fp8<<<(N * 64 + 255) / 256, 256, 0, stream>>>(hq, row_ofs, csr, invc, aggH);
    sage_gemm_mfma<256, true><<<NRB64, 256, 0, stream>>>(aggH, h2, W3lT, W3rT, b3, h1, nullptr,
                                                         N);
    pool_max<<<pgrid, 256, 0, stream>>>(h1, gstart, gend, xc, 2 * HIDC);

    // ---- head ----
    mlp1<<<N_GRAPHSC, 256, 0, stream>>>(xc, Wlin1, blin1, hmid);
    mlp2<<<N_GRAPHSC, 128, 0, stream>>>(hmid, Wlin2, blin2, out);
}

// Round 20
// 430.086 us; speedup vs baseline: 1.5593x; 1.0053x over previous
//
#include <hip/hip_runtime.h>
#include <hip/hip_bf16.h>

#define N_NODESC 100000
#define N_EDGESC 1600000
#define N_GRAPHSC 200
#define IN_DIMC 25
#define HIDC 256
#define OUT_DIMC 128
#define NRB64 ((N_NODESC + 63) / 64)   // 1563 row-blocks
#define NBKT ((N_NODESC + 255) / 256)  // 391 dst-buckets (256 nodes each)
#define NCH 400                        // edge chunks
#define CHSZ (N_EDGESC / NCH)          // 4000 edges/chunk (exact)

typedef __attribute__((ext_vector_type(8))) short bf16x8;
typedef __attribute__((ext_vector_type(4))) float f32x4;
typedef __attribute__((ext_vector_type(2))) float f32x2;

#if defined(__has_builtin)
#if __has_builtin(__builtin_amdgcn_cvt_pk_f32_fp8) && __has_builtin(__builtin_amdgcn_cvt_pk_fp8_f32)
#define HAVE_FP8_CVT 1
#endif
#endif

// ---------- bf16 helpers ----------
__device__ inline float bf2f(unsigned short u) {
    union { float f; unsigned u32; } c;
    c.u32 = ((unsigned)u) << 16;
    return c.f;
}
__device__ inline unsigned short f2bf(float f) {
    union { float f; unsigned u; } c;
    c.f = f;
    unsigned r = (c.u + 0x7FFFu + ((c.u >> 16) & 1u)) >> 16;  // RNE
    return (unsigned short)r;
}
__device__ inline float u2f(unsigned u) {
    union { unsigned u; float f; } c;
    c.u = u;
    return c.f;
}

// ---------- fp8 e4m3 helpers (values >= 0 only) ----------
__device__ inline unsigned fp8enc_sw(float v) {
    v = fminf(v, 448.0f);
    union { float f; unsigned u; } c;
    c.f = v;
    unsigned bits = c.u + 0x7FFFFu + ((c.u >> 20) & 1u);
    int e8 = (int)((bits >> 23) & 0xFF) - 120;
    if (e8 <= 0) return (unsigned)(v * 512.0f + 0.5f);
    return ((unsigned)e8 << 3) | ((bits >> 20) & 7u);
}
__device__ inline float fp8dec_sw(unsigned u) {
    unsigned e = (u >> 3) & 15u, m = u & 7u;
    float fn = u2f(((e + 120u) << 23) | (m << 20));
    float fd = (float)m * 0.001953125f;
    return e ? fn : fd;
}
__device__ inline unsigned pack4_fp8(float v0, float v1, float v2, float v3) {
#ifdef HAVE_FP8_CVT
    int r = __builtin_amdgcn_cvt_pk_fp8_f32(v0, v1, 0, false);
    r = __builtin_amdgcn_cvt_pk_fp8_f32(v2, v3, r, true);
    return (unsigned)r;
#else
    return fp8enc_sw(v0) | (fp8enc_sw(v1) << 8) | (fp8enc_sw(v2) << 16) | (fp8enc_sw(v3) << 24);
#endif
}

// ---------- utility fills ----------
__global__ void fill_u32(unsigned* __restrict__ p, unsigned v, int n) {
    int i = blockIdx.x * 256 + threadIdx.x;
    if (i < n) p[i] = v;
}

// ---------- x -> bf16 table [N][32] (64B rows, line-aligned) ----------
__global__ void xtab_kernel(const float* __restrict__ x, unsigned short* __restrict__ xt) {
    int i = blockIdx.x * 256 + threadIdx.x;
    int node = i >> 5, c = i & 31;
    if (node >= N_NODESC) return;
    xt[i] = (c < IN_DIMC) ? f2bf(x[(size_t)node * IN_DIMC + c]) : (unsigned short)0;
}

// ---------- bucketed CSR build ----------
__global__ __launch_bounds__(256) void hist_kernel(const int* __restrict__ dst,
                                                   int* __restrict__ hist) {
    __shared__ int h[NBKT];
    const int c = blockIdx.x, tid = threadIdx.x;
    for (int t = tid; t < NBKT; t += 256) h[t] = 0;
    __syncthreads();
    const int e0 = c * CHSZ;
    for (int e = e0 + tid; e < e0 + CHSZ; e += 256) atomicAdd(&h[dst[e] >> 8], 1);
    __syncthreads();
    for (int t = tid; t < NBKT; t += 256) hist[c * NBKT + t] = h[t];
}

__global__ __launch_bounds__(512) void col_scan(int* __restrict__ hist,
                                                int* __restrict__ colsum) {
    __shared__ int sm[512];
    const int b = blockIdx.x, t = threadIdx.x;
    int v = (t < NCH) ? hist[t * NBKT + b] : 0;
    sm[t] = v;
    __syncthreads();
    for (int off = 1; off < 512; off <<= 1) {
        int u = (t >= off) ? sm[t - off] : 0;
        __syncthreads();
        sm[t] += u;
        __syncthreads();
    }
    if (t < NCH) hist[t * NBKT + b] = sm[t] - v;
    if (t == 511) colsum[b] = sm[511];
}

__global__ __launch_bounds__(512) void bucket_base_scan(const int* __restrict__ colsum,
                                                        int* __restrict__ base) {
    __shared__ int sm[512];
    const int t = threadIdx.x;
    int v = (t < NBKT) ? colsum[t] : 0;
    sm[t] = v;
    __syncthreads();
    for (int off = 1; off < 512; off <<= 1) {
        int u = (t >= off) ? sm[t - off] : 0;
        __syncthreads();
        sm[t] += u;
        __syncthreads();
    }
    if (t <= NBKT) base[t] = sm[t] - v;
}

__global__ __launch_bounds__(256) void bucket_scatter(const int* __restrict__ src,
                                                      const int* __restrict__ dst,
                                                      const int* __restrict__ chpre,
                                                      const int* __restrict__ base,
                                                      int2* __restrict__ pairs) {
    __shared__ int cur[NBKT];
    __shared__ int o2[NBKT];
    const int c = blockIdx.x, tid = threadIdx.x;
    for (int t = tid; t < NBKT; t += 256) {
        cur[t] = 0;
        o2[t] = base[t] + chpre[c * NBKT + t];
    }
    __syncthreads();
    const int e0 = c * CHSZ;
    for (int e = e0 + tid; e < e0 + CHSZ; e += 256) {
        int s = src[e], d = dst[e];
        int b = d >> 8;
        int p = atomicAdd(&cur[b], 1);
        pairs[o2[b] + p] = make_int2(s, d);
    }
}

// degrees + row_ofs + inv (buckets are contiguous node ranges)
__global__ __launch_bounds__(256) void bucket_deg(const int2* __restrict__ pairs,
                                                  const int* __restrict__ base,
                                                  int* __restrict__ row_ofs,
                                                  float* __restrict__ invc) {
    __shared__ int h[256];
    __shared__ int sc[256];
    const int b = blockIdx.x, tid = threadIdx.x;
    h[tid] = 0;
    __syncthreads();
    for (int i = base[b] + tid; i < base[b + 1]; i += 256)
        atomicAdd(&h[pairs[i].y & 255], 1);
    __syncthreads();
    int v = h[tid];
    sc[tid] = v;
    __syncthreads();
    for (int off = 1; off < 256; off <<= 1) {
        int t = (tid >= off) ? sc[tid - off] : 0;
        __syncthreads();
        sc[tid] += t;
        __syncthreads();
    }
    int node = b * 256 + tid;
    if (node < N_NODESC) {
        row_ofs[node] = base[b] + sc[tid] - v;
        invc[node] = 1.0f / (float)max(v, 1);
    }
    if (node == N_NODESC) row_ofs[N_NODESC] = N_EDGESC;
}

__global__ __launch_bounds__(256) void bucket_csrfill(const int2* __restrict__ pairs,
                                                      const int* __restrict__ base,
                                                      const int* __restrict__ row_ofs,
                                                      int* __restrict__ csr) {
    __shared__ int cur[256];
    __shared__ int ob[256];
    const int b = blockIdx.x, tid = threadIdx.x;
    int node = b * 256 + tid;
    ob[tid] = (node < N_NODESC) ? row_ofs[node] : 0;
    cur[tid] = 0;
    __syncthreads();
    for (int i = base[b] + tid; i < base[b + 1]; i += 256) {
        int2 pr = pairs[i];
        int loc = pr.y & 255;
        int p = atomicAdd(&cur[loc], 1);
        csr[ob[loc] + p] = pr.x;
    }
}

// ---------- graph ranges (batch sorted) ----------
__global__ void ranges_bounds(const int* __restrict__ batch, int* __restrict__ gstart,
                              int* __restrict__ gend, int n) {
    int i = blockIdx.x * 256 + threadIdx.x;
    if (i >= n) return;
    int g = batch[i];
    if (i == 0 || batch[i - 1] != g) gstart[g] = i;
    if (i == n - 1 || batch[i + 1] != g) gend[g] = i + 1;
}

// ---------- all weight transposes in one kernel ----------
// z=0: W2lT (perm), z=1: W2rT, z=2: W3lT (perm), z=3: W3rT, z=4: BT1 [256 n][64 k]
__global__ void wtrans_all(const float* __restrict__ W1l, const float* __restrict__ W1r,
                           const float* __restrict__ W2l, const float* __restrict__ W2r,
                           const float* __restrict__ W3l, const float* __restrict__ W3r,
                           unsigned short* __restrict__ W2lT, unsigned short* __restrict__ W2rT,
                           unsigned short* __restrict__ W3lT, unsigned short* __restrict__ W3rT,
                           unsigned short* __restrict__ BT1) {
    int z = blockIdx.z;
    int tx = threadIdx.x & 15, ty = threadIdx.x >> 4;
    int n = blockIdx.y * 16 + ty;
    int p = blockIdx.x * 16 + tx;
    if (z == 4) {
        if (blockIdx.x >= 4) return;  // k < 64
        float v = 0.0f;
        if (p < IN_DIMC) v = W1l[(size_t)p * HIDC + n];
        else if (p >= 32 && p < 32 + IN_DIMC) v = W1r[(size_t)(p - 32) * HIDC + n];
        BT1[(size_t)n * 64 + p] = f2bf(v);
        return;
    }
    const float* W = (z == 0) ? W2l : (z == 1) ? W2r : (z == 2) ? W3l : W3r;
    unsigned short* WT = (z == 0) ? W2lT : (z == 1) ? W2rT : (z == 2) ? W3lT : W3rT;
    int c = (z == 0 || z == 2) ? ((p & 0xC0) + ((p & 3) << 4) + ((p >> 2) & 15)) : p;
    WT[(size_t)n * HIDC + p] = f2bf(W[(size_t)c * HIDC + n]);
}

// ---------- layer-1 mean gather over bf16 x-table + x copy (fused) ----------
__global__ void gather25(const unsigned short* __restrict__ xt, const int* __restrict__ ofs,
                         const int* __restrict__ csr, const float* __restrict__ inv,
                         unsigned short* __restrict__ Acat) {
    long long gtid = (long long)blockIdx.x * 256 + threadIdx.x;
    int node = (int)(gtid >> 6);
    if (node >= N_NODESC) return;
    const int lane = threadIdx.x & 63;
    const int half = lane >> 5;
    const int c = lane & 31;
    const int s = ofs[node], e = ofs[node + 1];
    float acc = 0.0f;
    int j = s + half;
    for (; j + 6 < e; j += 8) {
        int sn0 = csr[j], sn1 = csr[j + 2], sn2 = csr[j + 4], sn3 = csr[j + 6];
        float v0 = bf2f(xt[(size_t)sn0 * 32 + c]);
        float v1 = bf2f(xt[(size_t)sn1 * 32 + c]);
        float v2 = bf2f(xt[(size_t)sn2 * 32 + c]);
        float v3 = bf2f(xt[(size_t)sn3 * 32 + c]);
        acc += (v0 + v1) + (v2 + v3);
    }
    for (; j < e; j += 2) {
        int sn = csr[j];
        acc += bf2f(xt[(size_t)sn * 32 + c]);
    }
    acc += __shfl_xor(acc, 32, 64);
    if (half == 0) {
        Acat[(size_t)node * 64 + c] = f2bf(acc * inv[node]);
    } else {
        Acat[(size_t)node * 64 + 32 + c] = xt[(size_t)node * 32 + c];
    }
}

// ---------- hidden mean gather over fp8 rows: 16 rows in flight ----------
__global__ void gather256_fp8(const unsigned char* __restrict__ hq, const int* __restrict__ ofs,
                              const int* __restrict__ csr, const float* __restrict__ inv,
                              unsigned short* __restrict__ agg) {
    long long gtid = (long long)blockIdx.x * 256 + threadIdx.x;
    int node = (int)(gtid >> 6);
    if (node >= N_NODESC) return;
    const int lane = threadIdx.x & 63;
    const int half = lane >> 5;
    const int l = lane & 31;
    const int s = ofs[node], e = ofs[node + 1];

    f32x2 A01 = {0.0f, 0.0f}, A23 = {0.0f, 0.0f}, A45 = {0.0f, 0.0f}, A67 = {0.0f, 0.0f};
    const size_t boff = (size_t)l * 8;

#ifdef HAVE_FP8_CVT
#define DEC8(q)                                                          \
    {                                                                    \
        A01 += __builtin_amdgcn_cvt_pk_f32_fp8((int)(q).x, false);       \
        A23 += __builtin_amdgcn_cvt_pk_f32_fp8((int)(q).x, true);        \
        A45 += __builtin_amdgcn_cvt_pk_f32_fp8((int)(q).y, false);       \
        A67 += __builtin_amdgcn_cvt_pk_f32_fp8((int)(q).y, true);        \
    }
#else
#define DEC8(q)                                                          \
    {                                                                    \
        unsigned lo = (unsigned)(q).x, hi = (unsigned)(q).y;             \
        A01.x += fp8dec_sw(lo & 255); A01.y += fp8dec_sw((lo >> 8) & 255);   \
        A23.x += fp8dec_sw((lo >> 16) & 255); A23.y += fp8dec_sw(lo >> 24); \
        A45.x += fp8dec_sw(hi & 255); A45.y += fp8dec_sw((hi >> 8) & 255);   \
        A67.x += fp8dec_sw((hi >> 16) & 255); A67.y += fp8dec_sw(hi >> 24); \
    }
#endif

    int j = s + half;
    // 8x unroll per half-wave -> up to 16 rows (256B each) in flight per wave
    for (; j + 14 < e; j += 16) {
        int sn0 = csr[j], sn1 = csr[j + 2], sn2 = csr[j + 4], sn3 = csr[j + 6];
        int sn4 = csr[j + 8], sn5 = csr[j + 10], sn6 = csr[j + 12], sn7 = csr[j + 14];
        uint2 q0 = *reinterpret_cast<const uint2*>(hq + (size_t)sn0 * 256 + boff);
        uint2 q1 = *reinterpret_cast<const uint2*>(hq + (size_t)sn1 * 256 + boff);
        uint2 q2 = *reinterpret_cast<const uint2*>(hq + (size_t)sn2 * 256 + boff);
        uint2 q3 = *reinterpret_cast<const uint2*>(hq + (size_t)sn3 * 256 + boff);
        uint2 q4 = *reinterpret_cast<const uint2*>(hq + (size_t)sn4 * 256 + boff);
        uint2 q5 = *reinterpret_cast<const uint2*>(hq + (size_t)sn5 * 256 + boff);
        uint2 q6 = *reinterpret_cast<const uint2*>(hq + (size_t)sn6 * 256 + boff);
        uint2 q7 = *reinterpret_cast<const uint2*>(hq + (size_t)sn7 * 256 + boff);
        DEC8(q0) DEC8(q1) DEC8(q2) DEC8(q3) DEC8(q4) DEC8(q5) DEC8(q6) DEC8(q7)
    }
    for (; j + 6 < e; j += 8) {
        int sn0 = csr[j], sn1 = csr[j + 2], sn2 = csr[j + 4], sn3 = csr[j + 6];
        uint2 q0 = *reinterpret_cast<const uint2*>(hq + (size_t)sn0 * 256 + boff);
        uint2 q1 = *reinterpret_cast<const uint2*>(hq + (size_t)sn1 * 256 + boff);
        uint2 q2 = *reinterpret_cast<const uint2*>(hq + (size_t)sn2 * 256 + boff);
        uint2 q3 = *reinterpret_cast<const uint2*>(hq + (size_t)sn3 * 256 + boff);
        DEC8(q0) DEC8(q1) DEC8(q2) DEC8(q3)
    }
    for (; j < e; j += 2) {
        int sn0 = csr[j];
        uint2 q0 = *reinterpret_cast<const uint2*>(hq + (size_t)sn0 * 256 + boff);
        DEC8(q0)
    }
#undef DEC8

    float a0 = A01.x, a1 = A01.y, a2 = A23.x, a3 = A23.y;
    float a4 = A45.x, a5 = A45.y, a6 = A67.x, a7 = A67.y;
    a0 += __shfl_xor(a0, 32, 64); a1 += __shfl_xor(a1, 32, 64);
    a2 += __shfl_xor(a2, 32, 64); a3 += __shfl_xor(a3, 32, 64);
    a4 += __shfl_xor(a4, 32, 64); a5 += __shfl_xor(a5, 32, 64);
    a6 += __shfl_xor(a6, 32, 64); a7 += __shfl_xor(a7, 32, 64);

    if (half == 0) {
        float sc = inv[node];
        int4 p;
        p.x = (int)((unsigned)f2bf(a0 * sc) | ((unsigned)f2bf(a1 * sc) << 16));
        p.y = (int)((unsigned)f2bf(a2 * sc) | ((unsigned)f2bf(a3 * sc) << 16));
        p.z = (int)((unsigned)f2bf(a4 * sc) | ((unsigned)f2bf(a5 * sc) << 16));
        p.w = (int)((unsigned)f2bf(a6 * sc) | ((unsigned)f2bf(a7 * sc) << 16));
        *reinterpret_cast<int4*>(agg + (size_t)node * HIDC + (size_t)l * 8) = p;
    }
}

// ---------- MFMA bf16 SAGE GEMM, m97-style 64-row tile, templated K-depth ----------
template <int KD, bool TWOPASS>
__global__ __launch_bounds__(256) void sage_gemm_mfma(
    const unsigned short* __restrict__ A0, const unsigned short* __restrict__ A1,
    const unsigned short* __restrict__ B0T, const unsigned short* __restrict__ B1T,
    const float* __restrict__ bias, unsigned short* __restrict__ out,
    unsigned char* __restrict__ outq, int M) {
    __shared__ unsigned short sA[64 * 64];   // 8KB
    __shared__ unsigned short sB[256 * 64];  // 32KB
    const int rowbase = blockIdx.x * 64;
    const int tid = threadIdx.x;
    const int lane = tid & 63;
    const int w = tid >> 6;
    const int fr = lane & 15;
    const int kq8 = (lane >> 4) << 3;

    const int srow = lane >> 3;
    const int schunk = (lane & 7) ^ srow;

    f32x4 acc[4][4] = {};

#pragma unroll
    for (int pass = 0; pass < (TWOPASS ? 2 : 1); ++pass) {
        const unsigned short* __restrict__ A = (TWOPASS && pass) ? A1 : A0;
        const unsigned short* __restrict__ BT = (TWOPASS && pass) ? B1T : B0T;
#pragma unroll
        for (int ks = 0; ks < KD / 64; ++ks) {
            const int kb = ks * 64;
            __syncthreads();
#pragma unroll
            for (int c = 0; c < 2; ++c) {
                int ar = w * 16 + c * 8 + srow;
                const unsigned short* g = A + (size_t)(rowbase + ar) * KD + kb + (schunk << 3);
                __builtin_amdgcn_global_load_lds(
                    (const __attribute__((address_space(1))) void*)g,
                    (__attribute__((address_space(3))) void*)(sA + (w * 16 + c * 8) * 64),
                    16, 0, 0);
            }
#pragma unroll
            for (int c = 0; c < 8; ++c) {
                int br = w * 64 + c * 8 + srow;
                const unsigned short* g = BT + (size_t)br * KD + kb + (schunk << 3);
                __builtin_amdgcn_global_load_lds(
                    (const __attribute__((address_space(1))) void*)g,
                    (__attribute__((address_space(3))) void*)(sB + (w * 64 + c * 8) * 64),
                    16, 0, 0);
            }
            __syncthreads();
#pragma unroll
            for (int kg = 0; kg < 2; ++kg) {
                bf16x8 af[4], bfr[4];
#pragma unroll
                for (int t = 0; t < 4; ++t) {
                    int ra = t * 16 + fr;
                    int ba = ra * 128 + ((kg * 64 + kq8 * 2) ^ ((ra & 7) << 4));
                    af[t] = *reinterpret_cast<const bf16x8*>(
                        reinterpret_cast<const char*>(sA) + ba);
                    int rb = w * 64 + t * 16 + fr;
                    int bb2 = rb * 128 + ((kg * 64 + kq8 * 2) ^ ((rb & 7) << 4));
                    bfr[t] = *reinterpret_cast<const bf16x8*>(
                        reinterpret_cast<const char*>(sB) + bb2);
                }
#pragma unroll
                for (int i = 0; i < 4; ++i)
#pragma unroll
                    for (int j = 0; j < 4; ++j)
                        acc[i][j] = __builtin_amdgcn_mfma_f32_16x16x32_bf16(
                            af[i], bfr[j], acc[i][j], 0, 0, 0);
            }
        }
    }

    const int crow0 = (lane >> 4) << 2;
    float bb[4];
#pragma unroll
    for (int j = 0; j < 4; ++j) bb[j] = bias[w * 64 + j * 16 + fr];
#pragma unroll
    for (int i = 0; i < 4; ++i) {
#pragma unroll
        for (int r = 0; r < 4; ++r) {
            int row = rowbase + i * 16 + crow0 + r;
            if (row >= M) continue;
            float v[4];
#pragma unroll
            for (int j = 0; j < 4; ++j) {
                v[j] = fmaxf(acc[i][j][r] + bb[j], 0.0f);
                out[(size_t)row * HIDC + w * 64 + j * 16 + fr] = f2bf(v[j]);
            }
            if (outq)
                *reinterpret_cast<unsigned*>(outq + (size_t)row * 256 + w * 64 + fr * 4) =
                    pack4_fp8(v[0], v[1], v[2], v[3]);
        }
    }
}

// ---------- segment-max pool ----------
__global__ void pool_max(const unsigned short* __restrict__ h, const int* __restrict__ gstart,
                         const int* __restrict__ gend, float* __restrict__ xc, int col_off) {
    int g = blockIdx.x;
    int chunk = blockIdx.y;
    int c = threadIdx.x;
    int s = gstart[g], e = gend[g];
    int len = e - s;
    if (len <= 0) return;
    int per = (len + 7) >> 3;
    int cs = s + chunk * per;
    int ce = min(cs + per, e);
    if (cs >= ce) return;
    float m = 0.0f;
    for (int i = cs; i < ce; ++i) m = fmaxf(m, bf2f(h[(size_t)i * HIDC + c]));
    atomicMax(reinterpret_cast<int*>(&xc[(size_t)g * (3 * HIDC) + col_off + c]),
              __float_as_int(m));
}

// ---------- head MLPs ----------
__global__ void mlp1(const float* __restrict__ xc, const float* __restrict__ W,
                     const float* __restrict__ b, float* __restrict__ hmid) {
    __shared__ float row[3 * HIDC];
    int g = blockIdx.x;
    for (int i = threadIdx.x; i < 3 * HIDC; i += 256) row[i] = xc[(size_t)g * (3 * HIDC) + i];
    __syncthreads();
    float acc = b[threadIdx.x];
    for (int k = 0; k < 3 * HIDC; ++k) acc += row[k] * W[(size_t)k * HIDC + threadIdx.x];
    hmid[(size_t)g * HIDC + threadIdx.x] = fmaxf(acc, 0.0f);
}

__global__ void mlp2(const float* __restrict__ hmid, const float* __restrict__ W,
                     const float* __restrict__ b, float* __restrict__ out) {
    __shared__ float row[HIDC];
    int g = blockIdx.x;
    for (int i = threadIdx.x; i < HIDC; i += 128) row[i] = hmid[(size_t)g * HIDC + i];
    __syncthreads();
    float acc = b[threadIdx.x];
    for (int k = 0; k < HIDC; ++k) acc += row[k] * W[(size_t)k * OUT_DIMC + threadIdx.x];
    out[(size_t)g * OUT_DIMC + threadIdx.x] = acc;
}

static inline char* align_up(char* p, size_t a) {
    return (char*)(((uintptr_t)p + a - 1) & ~(uintptr_t)(a - 1));
}

extern "C" void kernel_launch(void* const* d_in, const int* in_sizes, int n_in,
                              void* d_out, int out_size, void* d_ws, size_t ws_size,
                              hipStream_t stream) {
    const float* x = (const float*)d_in[0];
    const int* edge_index = (const int*)d_in[1];
    const int* batch = (const int*)d_in[2];
    const float* W1l = (const float*)d_in[3];
    const float* W1r = (const float*)d_in[4];
    const float* b1 = (const float*)d_in[5];
    const float* W2l = (const float*)d_in[6];
    const float* W2r = (const float*)d_in[7];
    const float* b2 = (const float*)d_in[8];
    const float* W3l = (const float*)d_in[9];
    const float* W3r = (const float*)d_in[10];
    const float* b3 = (const float*)d_in[11];
    const float* Wlin1 = (const float*)d_in[12];
    const float* blin1 = (const float*)d_in[13];
    const float* Wlin2 = (const float*)d_in[14];
    const float* blin2 = (const float*)d_in[15];
    float* out = (float*)d_out;

    const int N = N_NODESC, E = N_EDGESC;
    const int* src = edge_index;
    const int* dst = edge_index + E;

    // ---- workspace carve-up ----
    char* w0 = (char*)d_ws;
    char* w = w0;
    float* invc = (float*)w;   w = align_up(w + (size_t)N * 4, 256);
    int* row_ofs = (int*)w;    w = align_up(w + (size_t)(N + 1) * 4, 256);
    int* bbase = (int*)w;      w = align_up(w + (size_t)(NBKT + 1) * 4, 256);
    int* colsum = (int*)w;     w = align_up(w + (size_t)NBKT * 4, 256);
    int* csr = (int*)w;        w = align_up(w + (size_t)E * 4, 256);
    int* gstart = (int*)w;     w = align_up(w + (size_t)N_GRAPHSC * 4, 256);
    int* gend = (int*)w;       w = align_up(w + (size_t)N_GRAPHSC * 4, 256);
    float* xc = (float*)w;     w = align_up(w + (size_t)N_GRAPHSC * 3 * HIDC * 4, 256);
    float* hmid = (float*)w;   w = align_up(w + (size_t)N_GRAPHSC * HIDC * 4, 256);
    unsigned short* W2lT = (unsigned short*)w; w = align_up(w + (size_t)HIDC * HIDC * 2, 256);
    unsigned short* W2rT = (unsigned short*)w; w = align_up(w + (size_t)HIDC * HIDC * 2, 256);
    unsigned short* W3lT = (unsigned short*)w; w = align_up(w + (size_t)HIDC * HIDC * 2, 256);
    unsigned short* W3rT = (unsigned short*)w; w = align_up(w + (size_t)HIDC * HIDC * 2, 256);
    unsigned short* BT1 = (unsigned short*)w;  w = align_up(w + (size_t)HIDC * 64 * 2, 256);
    unsigned short* xt = (unsigned short*)w;   w = align_up(w + (size_t)N * 32 * 2, 256);
    char* aggU = w;            w = align_up(w + (size_t)N * HIDC * 2, 256);
    unsigned short* h1 = (unsigned short*)w;  w = align_up(w + (size_t)N * HIDC * 2, 256);
    unsigned short* h2 = (unsigned short*)w;  w = align_up(w + (size_t)N * HIDC * 2 + 65536, 256);
    unsigned char* hq = (unsigned char*)w;    w = align_up(w + (size_t)N * 256, 256);
    size_t required = (size_t)(w - w0);
    if (ws_size < required) return;

    unsigned short* aggH = (unsigned short*)aggU;
    // transient aliases:
    int* hist = (int*)aggU;                        // dead after bucket_scatter
    unsigned short* Acat = (unsigned short*)aggU;  // [N][64] bf16; after hist dead
    int2* pairs = (int2*)h2;                       // dead after bucket_csrfill

    const int nbN = (N + 255) / 256;
    const dim3 pgrid(N_GRAPHSC, 8);

    // weight transposes (single kernel) + x bf16 table
    wtrans_all<<<dim3(16, 16, 5), 256, 0, stream>>>(W1l, W1r, W2l, W2r, W3l, W3r, W2lT, W2rT,
                                                    W3lT, W3rT, BT1);
    xtab_kernel<<<(N * 32 + 255) / 256, 256, 0, stream>>>(x, xt);

    // ---- bucketed CSR build ----
    hist_kernel<<<NCH, 256, 0, stream>>>(dst, hist);
    col_scan<<<NBKT, 512, 0, stream>>>(hist, colsum);
    bucket_base_scan<<<1, 512, 0, stream>>>(colsum, bbase);
    bucket_scatter<<<NCH, 256, 0, stream>>>(src, dst, hist, bbase, pairs);
    bucket_deg<<<NBKT, 256, 0, stream>>>(pairs, bbase, row_ofs, invc);
    bucket_csrfill<<<NBKT, 256, 0, stream>>>(pairs, bbase, row_ofs, csr);

    // graph ranges + zero xc
    ranges_bounds<<<nbN, 256, 0, stream>>>(batch, gstart, gend, N);
    fill_u32<<<(N_GRAPHSC * 3 * HIDC + 255) / 256, 256, 0, stream>>>((unsigned*)xc, 0u,
                                                                     N_GRAPHSC * 3 * HIDC);

    // ---- layer 1 (MFMA KD=64 on [agg25|x]) -> h1 bf16 + hq fp8 (perm layout) ----
    gather25<<<(N * 64 + 255) / 256, 256, 0, stream>>>(xt, row_ofs, csr, invc, Acat);
    sage_gemm_mfma<64, false><<<NRB64, 256, 0, stream>>>(Acat, nullptr, BT1, nullptr, b1, h1,
                                                         hq, N);
    pool_max<<<pgrid, 256, 0, stream>>>(h1, gstart, gend, xc, 0);

    // ---- layer 2: fp8 gather (perm) + MFMA with perm'd W2lT -> h2 + hq fp8 (perm) ----
    gather256_fp8<<<(N * 64 + 255) / 256, 256, 0, stream>>>(hq, row_ofs, csr, invc, aggH);
    sage_gemm_mfma<256, true><<<NRB64, 256, 0, stream>>>(aggH, h1, W2lT, W2rT, b2, h2, hq, N);
    pool_max<<<pgrid, 256, 0, stream>>>(h2, gstart, gend, xc, HIDC);

    // ---- layer 3: fp8 gather (perm) + MFMA with perm'd W3lT -> h1 ----
    gather256_fp8<<<(N * 64 + 255) / 256, 256, 0, stream>>>(hq, row_ofs, csr, invc, aggH);
    sage_gemm_mfma<256, true><<<NRB64, 256, 0, stream>>>(aggH, h2, W3lT, W3rT, b3, h1, nullptr,
                                                         N);
    pool_max<<<pgrid, 256, 0, stream>>>(h1, gstart, gend, xc, 2 * HIDC);

    // ---- head ----
    mlp1<<<N_GRAPHSC, 256, 0, stream>>>(xc, Wlin1, blin1, hmid);
    mlp2<<<N_GRAPHSC, 128, 0, stream>>>(hmid, Wlin2, blin2, out);
}